// Round 1
// baseline (1112.858 us; speedup 1.0000x reference)
//
#include <hip/hip_runtime.h>
#include <hip/hip_bf16.h>

typedef unsigned short u16;
typedef unsigned int u32;
typedef __attribute__((ext_vector_type(8))) short short8;   // 8 bf16 (4 VGPRs)
typedef __attribute__((ext_vector_type(4))) float f32x4;    // MFMA C/D

#define MFMA_BF16(A, B, C) __builtin_amdgcn_mfma_f32_16x16x32_bf16(A, B, C, 0, 0, 0)

#define SCALE2 0.08838834764831845f
#define LNEPS 1e-5f

__device__ __forceinline__ float b2f(u16 u) {
  return __uint_as_float(((u32)u) << 16);
}
__device__ __forceinline__ u16 f2b(float f) {
  u32 x = __float_as_uint(f);
  return (u16)((x + 0x7fffu + ((x >> 16) & 1u)) >> 16);  // RNE
}
__device__ __forceinline__ float ldf(const float* p) { return *p; }
__device__ __forceinline__ float ldf(const u16* p) { return b2f(*p); }
__device__ __forceinline__ void stf(float* p, float v) { *p = v; }
__device__ __forceinline__ void stf(u16* p, float v) { *p = f2b(v); }

// ---------------- MFMA GEMM: out[m][n] = sum_k X[m][k]*W[n][k] + bias[n]
// K=384, N=384. Block 128Mx128N, 4 waves (2x2 of 64x64). SPLIT: hi/lo bf16
// 3-product f32-precision (X must be float).
template <int SPLIT, typename TX, typename TO>
__global__ __launch_bounds__(256) void gemm_mfma(
    const TX* __restrict__ X, const float* __restrict__ W,
    const float* __restrict__ bias, TO* __restrict__ out) {
  __shared__ __align__(16) u16 AH[128 * 40];
  __shared__ __align__(16) u16 BH[128 * 40];
  __shared__ __align__(16) u16 AL[SPLIT ? 128 * 40 : 8];
  __shared__ __align__(16) u16 BL[SPLIT ? 128 * 40 : 8];
  const int tid = threadIdx.x;
  const int w = tid >> 6, lane = tid & 63;
  const int t = lane & 15, qd = lane >> 4;
  const int wm = w & 1, wn = w >> 1;
  const int m0 = blockIdx.y * 128, n0 = blockIdx.x * 128;
  f32x4 acc[4][4];
#pragma unroll
  for (int i = 0; i < 4; ++i)
#pragma unroll
    for (int j = 0; j < 4; ++j) acc[i][j] = (f32x4){0.f, 0.f, 0.f, 0.f};
  for (int kt = 0; kt < 384; kt += 32) {
    // stage A (128x32) and B (128x32) with f32->bf16 convert
#pragma unroll
    for (int rep = 0; rep < 4; ++rep) {
      int e = tid + rep * 256;
      int m = e >> 3, k4 = (e & 7) * 4;
      if constexpr (sizeof(TX) == 4) {
        float4 v = *(const float4*)(X + (size_t)(m0 + m) * 384 + kt + k4);
        u16 h0 = f2b(v.x), h1 = f2b(v.y), h2 = f2b(v.z), h3 = f2b(v.w);
        u32 hp0 = (u32)h0 | ((u32)h1 << 16), hp1 = (u32)h2 | ((u32)h3 << 16);
        *(uint2*)&AH[m * 40 + k4] = make_uint2(hp0, hp1);
        if (SPLIT) {
          u16 l0 = f2b(v.x - b2f(h0)), l1 = f2b(v.y - b2f(h1));
          u16 l2 = f2b(v.z - b2f(h2)), l3 = f2b(v.w - b2f(h3));
          *(uint2*)&AL[m * 40 + k4] =
              make_uint2((u32)l0 | ((u32)l1 << 16), (u32)l2 | ((u32)l3 << 16));
        }
      } else {
        uint2 raw = *(const uint2*)(X + (size_t)(m0 + m) * 384 + kt + k4);
        *(uint2*)&AH[m * 40 + k4] = raw;
      }
      float4 wv = *(const float4*)(W + (size_t)(n0 + m) * 384 + kt + k4);
      u16 wh0 = f2b(wv.x), wh1 = f2b(wv.y), wh2 = f2b(wv.z), wh3 = f2b(wv.w);
      *(uint2*)&BH[m * 40 + k4] =
          make_uint2((u32)wh0 | ((u32)wh1 << 16), (u32)wh2 | ((u32)wh3 << 16));
      if (SPLIT) {
        u16 wl0 = f2b(wv.x - b2f(wh0)), wl1 = f2b(wv.y - b2f(wh1));
        u16 wl2 = f2b(wv.z - b2f(wh2)), wl3 = f2b(wv.w - b2f(wh3));
        *(uint2*)&BL[m * 40 + k4] =
            make_uint2((u32)wl0 | ((u32)wl1 << 16), (u32)wl2 | ((u32)wl3 << 16));
      }
    }
    __syncthreads();
    short8 af[4], bf[4], al[4], bl[4];
#pragma unroll
    for (int mi = 0; mi < 4; ++mi) {
      af[mi] = *(const short8*)&AH[(wm * 64 + mi * 16 + t) * 40 + qd * 8];
      bf[mi] = *(const short8*)&BH[(wn * 64 + mi * 16 + t) * 40 + qd * 8];
      if (SPLIT) {
        al[mi] = *(const short8*)&AL[(wm * 64 + mi * 16 + t) * 40 + qd * 8];
        bl[mi] = *(const short8*)&BL[(wn * 64 + mi * 16 + t) * 40 + qd * 8];
      }
    }
#pragma unroll
    for (int mi = 0; mi < 4; ++mi)
#pragma unroll
      for (int ni = 0; ni < 4; ++ni) {
        acc[mi][ni] = MFMA_BF16(af[mi], bf[ni], acc[mi][ni]);
        if (SPLIT) {
          acc[mi][ni] = MFMA_BF16(al[mi], bf[ni], acc[mi][ni]);
          acc[mi][ni] = MFMA_BF16(af[mi], bl[ni], acc[mi][ni]);
        }
      }
    __syncthreads();
  }
#pragma unroll
  for (int ni = 0; ni < 4; ++ni) {
    int n = n0 + wn * 64 + ni * 16 + t;
    float bv = bias[n];
#pragma unroll
    for (int mi = 0; mi < 4; ++mi)
#pragma unroll
      for (int r = 0; r < 4; ++r) {
        int m = m0 + wm * 64 + mi * 16 + qd * 4 + r;
        stf(&out[(size_t)m * 384 + n], acc[mi][ni][r] + bv);
      }
  }
}

// ---------------- row LayerNorm, in place (templated storage)
template <typename T>
__global__ __launch_bounds__(256) void ln_inplace(
    T* __restrict__ Tb, const float* __restrict__ w, const float* __restrict__ b, int N) {
  const int row = blockIdx.x, tid = threadIdx.x;
  T* Tr = Tb + (size_t)row * N;
  float vals[3];
  float s = 0.f, ss = 0.f;
  int nv = 0;
  for (int i = tid; i < N; i += 256) {
    float v = ldf(&Tr[i]);
    vals[nv++] = v;
    s += v; ss += v * v;
  }
#pragma unroll
  for (int mk = 32; mk; mk >>= 1) { s += __shfl_xor(s, mk); ss += __shfl_xor(ss, mk); }
  __shared__ float red[8];
  if ((tid & 63) == 0) { red[tid >> 6] = s; red[4 + (tid >> 6)] = ss; }
  __syncthreads();
  s = red[0] + red[1] + red[2] + red[3];
  ss = red[4] + red[5] + red[6] + red[7];
  float inv = 1.f / (float)N;
  float mean = s * inv;
  float var = fmaxf(ss * inv - mean * mean, 0.f);
  float rstd = rsqrtf(var + LNEPS);
  nv = 0;
  for (int i = tid; i < N; i += 256) {
    float v = (vals[nv++] - mean) * rstd * w[i] + b[i];
    stf(&Tr[i], v);
  }
}

// ---------------- LN over split storage: lo = f32 chans 0..383, hi = bf16 chans 384..767
__global__ __launch_bounds__(256) void ln_wf_split(
    float* __restrict__ lo, u16* __restrict__ hi,
    const float* __restrict__ w, const float* __restrict__ b) {
  const int row = blockIdx.x, tid = threadIdx.x;
  float* L = lo + (size_t)row * 384;
  u16* H = hi + (size_t)row * 384;
  float vals[3];
  float s = 0.f, ss = 0.f;
  int nv = 0;
  for (int i = tid; i < 768; i += 256) {
    float v = (i < 384) ? L[i] : b2f(H[i - 384]);
    vals[nv++] = v;
    s += v; ss += v * v;
  }
#pragma unroll
  for (int mk = 32; mk; mk >>= 1) { s += __shfl_xor(s, mk); ss += __shfl_xor(ss, mk); }
  __shared__ float red[8];
  if ((tid & 63) == 0) { red[tid >> 6] = s; red[4 + (tid >> 6)] = ss; }
  __syncthreads();
  s = red[0] + red[1] + red[2] + red[3];
  ss = red[4] + red[5] + red[6] + red[7];
  float mean = s * (1.f / 768.f);
  float var = fmaxf(ss * (1.f / 768.f) - mean * mean, 0.f);
  float rstd = rsqrtf(var + LNEPS);
  nv = 0;
  for (int i = tid; i < 768; i += 256) {
    float v = (vals[nv++] - mean) * rstd * w[i] + b[i];
    if (i < 384) L[i] = v; else H[i - 384] = f2b(v);
  }
}

// ---------------- DWT sf: t_sf f32 -> q1 split-bf16 (hi+lo), q2 bf16 (3 heads)
__global__ __launch_bounds__(256) void dwt_sf(
    const float* __restrict__ T, u16* __restrict__ q1h, u16* __restrict__ q1l,
    u16* __restrict__ q2) {
  const int blk = blockIdx.x;
  const int b = blk >> 10, pos = blk & 1023;
  const int i = pos >> 5, j = pos & 31;
  const int p00 = (i * 2) * 64 + j * 2;
  const float* base = T + (size_t)b * 4096 * 384;
  for (int ch = threadIdx.x; ch < 384; ch += 256) {
    float a  = base[(size_t)p00 * 384 + ch];
    float cc = base[(size_t)(p00 + 1) * 384 + ch];
    float bb = base[(size_t)(p00 + 64) * 384 + ch];
    float dd = base[(size_t)(p00 + 65) * 384 + ch];
    float s0 = 0.5f * ( a + bb + cc + dd);
    float s1 = 0.5f * (-a - bb + cc + dd);
    float s2 = 0.5f * (-a + bb - cc + dd);
    float s3 = 0.5f * ( a - bb - cc + dd);
    size_t po = (size_t)(b * 1024 + pos) * 384 + ch;
    u16 h = f2b(s0);
    q1h[po] = h;
    q1l[po] = f2b(s0 - b2f(h));
    q2[(size_t)((b * 3 + 0) * 1024 + pos) * 384 + ch] = f2b(s1);
    q2[(size_t)((b * 3 + 1) * 1024 + pos) * 384 + ch] = f2b(s2);
    q2[(size_t)((b * 3 + 2) * 1024 + pos) * 384 + ch] = f2b(s3);
  }
}

// ---------------- DWT wf (split input): lo f32, hi bf16 -> k1 split-bf16, v1, k2, v2
__global__ __launch_bounds__(256) void dwt_wf_split(
    const float* __restrict__ lo, const u16* __restrict__ hi,
    u16* __restrict__ k1h, u16* __restrict__ k1l, u16* __restrict__ v1,
    u16* __restrict__ k2, u16* __restrict__ v2) {
  const int blk = blockIdx.x;
  const int b = blk >> 10, pos = blk & 1023;
  const int i = pos >> 5, j = pos & 31;
  const int p00 = (i * 2) * 64 + j * 2;
  for (int ch = threadIdx.x; ch < 768; ch += 256) {
    float a, bb, cc, dd;
    if (ch < 384) {
      const float* base = lo + (size_t)b * 4096 * 384;
      a  = base[(size_t)p00 * 384 + ch];
      cc = base[(size_t)(p00 + 1) * 384 + ch];
      bb = base[(size_t)(p00 + 64) * 384 + ch];
      dd = base[(size_t)(p00 + 65) * 384 + ch];
    } else {
      const u16* base = hi + (size_t)b * 4096 * 384;
      int c = ch - 384;
      a  = b2f(base[(size_t)p00 * 384 + c]);
      cc = b2f(base[(size_t)(p00 + 1) * 384 + c]);
      bb = b2f(base[(size_t)(p00 + 64) * 384 + c]);
      dd = b2f(base[(size_t)(p00 + 65) * 384 + c]);
    }
    float s0 = 0.5f * ( a + bb + cc + dd);
    float s1 = 0.5f * (-a - bb + cc + dd);
    float s2 = 0.5f * (-a + bb - cc + dd);
    float s3 = 0.5f * ( a - bb - cc + dd);
    if (ch < 384) {
      size_t po = (size_t)(b * 1024 + pos) * 384 + ch;
      u16 h = f2b(s0);
      k1h[po] = h;
      k1l[po] = f2b(s0 - b2f(h));
      v1[po] = f2b(s2);
      k2[(size_t)((b * 3 + 1) * 1024 + pos) * 384 + ch] = f2b(s1);
      v2[(size_t)((b * 3 + 1) * 1024 + pos) * 384 + ch] = f2b(s3);
    } else {
      int c = ch - 384;
      k2[(size_t)((b * 3 + 0) * 1024 + pos) * 384 + c] = f2b(s0);
      k2[(size_t)((b * 3 + 2) * 1024 + pos) * 384 + c] = f2b(s1);
      v2[(size_t)((b * 3 + 0) * 1024 + pos) * 384 + c] = f2b(s2);
      v2[(size_t)((b * 3 + 2) * 1024 + pos) * 384 + c] = f2b(s3);
    }
  }
}

// ---------------- transpose [bh][1024][384] -> [bh][384][1024]
__global__ __launch_bounds__(256) void transpose_rm(
    const u16* __restrict__ in, u16* __restrict__ out) {
  __shared__ u16 T[64][65];
  const int tid = threadIdx.x;
  const int bh = blockIdx.z, r0 = blockIdx.y * 64, c0 = blockIdx.x * 64;
  const u16* ip = in + ((size_t)bh * 1024 + r0) * 384 + c0;
  for (int i = tid; i < 2048; i += 256) {
    int r = i >> 5, c2 = i & 31;
    u32 v = *(const u32*)(ip + (size_t)r * 384 + c2 * 2);
    T[c2 * 2][r] = (u16)v;
    T[c2 * 2 + 1][r] = (u16)(v >> 16);
  }
  __syncthreads();
  u16* op = out + ((size_t)bh * 384 + c0) * 1024 + r0;
  for (int i = tid; i < 2048; i += 256) {
    int c = i >> 5, r2 = i & 31;
    u32 v = (u32)T[c][r2 * 2] | ((u32)T[c][r2 * 2 + 1] << 16);
    *(u32*)(op + (size_t)c * 1024 + r2 * 2) = v;
  }
}

// ---------------- att2 stats (plain bf16): per query row m/l over all keys.
// Block: 16 own rows; per iter 64 stream rows (16 per wave). Stream fragments
// are loaded DIRECTLY to registers (each lane consumes exactly the bytes it
// would have staged: row w*16+t, chans qd*8+ks*32) — no LDS, no vmcnt drain,
// no barriers in the loop.
__global__ __launch_bounds__(256) void att2_stats(
    const u16* __restrict__ q, const u16* __restrict__ k,
    float2* __restrict__ stats, float scale) {
  __shared__ float2 comb[4][16];
  const int tid = threadIdx.x, w = tid >> 6, lane = tid & 63;
  const int t = lane & 15, qd = lane >> 4;
  const int bh = blockIdx.y, o0 = blockIdx.x * 16;
  short8 Ah[12];
  {
    const u16* qp = q + ((size_t)bh * 1024 + o0 + t) * 384 + qd * 8;
#pragma unroll
    for (int ks = 0; ks < 12; ++ks) Ah[ks] = *(const short8*)(qp + ks * 32);
  }
  float m[4] = {-1e30f, -1e30f, -1e30f, -1e30f}, l[4] = {0.f, 0.f, 0.f, 0.f};
  for (int st = 0; st < 16; ++st) {
    const u16* kp = k + ((size_t)bh * 1024 + st * 64 + w * 16 + t) * 384 + qd * 8;
    f32x4 S0 = {0.f, 0.f, 0.f, 0.f}, S1 = {0.f, 0.f, 0.f, 0.f};
#pragma unroll
    for (int ks = 0; ks < 12; ks += 2) {
      short8 B0 = *(const short8*)(kp + ks * 32);
      short8 B1 = *(const short8*)(kp + (ks + 1) * 32);
      S0 = MFMA_BF16(Ah[ks], B0, S0);
      S1 = MFMA_BF16(Ah[ks + 1], B1, S1);
    }
#pragma unroll
    for (int r = 0; r < 4; ++r) {
      float s = (S0[r] + S1[r]) * scale;
      float mx = s;
#pragma unroll
      for (int mk = 1; mk < 16; mk <<= 1) mx = fmaxf(mx, __shfl_xor(mx, mk));
      float nm = fmaxf(m[r], mx);
      float e = __expf(s - nm);
#pragma unroll
      for (int mk = 1; mk < 16; mk <<= 1) e += __shfl_xor(e, mk);
      l[r] = l[r] * __expf(m[r] - nm) + e;
      m[r] = nm;
    }
  }
  if (t == 0) {
#pragma unroll
    for (int r = 0; r < 4; ++r) comb[w][qd * 4 + r] = make_float2(m[r], l[r]);
  }
  __syncthreads();
  if (tid < 16) {
    float nm = comb[0][tid].x;
#pragma unroll
    for (int ww = 1; ww < 4; ++ww) nm = fmaxf(nm, comb[ww][tid].x);
    float ll = 0.f;
#pragma unroll
    for (int ww = 0; ww < 4; ++ww) ll += comb[ww][tid].y * __expf(comb[ww][tid].x - nm);
    stats[(size_t)bh * 1024 + o0 + tid] = make_float2(nm, 1.f / ll);
  }
}

// ---------------- att2 accumulate (transposed gather): own=keys, stream=queries,
// stats indexed by stream rows. Stream fragments direct-to-register (no LDS
// staging, no vmcnt drain); P double-buffered; one barrier/iter.
__global__ __launch_bounds__(256) void att2_accum(
    const u16* __restrict__ own, const u16* __restrict__ str,
    const u16* __restrict__ vt, const float2* __restrict__ stats,
    u16* __restrict__ xall, float scale) {
  __shared__ __align__(16) u16 P[2][16 * 72];  // double-buffered 4.5 KB
  const int tid = threadIdx.x, w = tid >> 6, lane = tid & 63;
  const int t = lane & 15, qd = lane >> 4;
  const int bh = blockIdx.y, o0 = blockIdx.x * 16;
  short8 Ah[12];
  {
    const u16* op = own + ((size_t)bh * 1024 + o0 + t) * 384 + qd * 8;
#pragma unroll
    for (int ks = 0; ks < 12; ++ks) Ah[ks] = *(const short8*)(op + ks * 32);
  }
  f32x4 acc[6];
#pragma unroll
  for (int i = 0; i < 6; ++i) acc[i] = (f32x4){0.f, 0.f, 0.f, 0.f};
  const u16* vbase = vt + ((size_t)bh * 384 + w * 96 + t) * 1024;
  for (int st = 0; st < 16; ++st) {
    const int pb = st & 1;
    const u16* sp = str + ((size_t)bh * 1024 + st * 64 + w * 16 + t) * 384 + qd * 8;
    short8 Vr[12];
#pragma unroll
    for (int nj = 0; nj < 6; ++nj) {
      Vr[nj * 2]     = *(const short8*)(vbase + (size_t)nj * 16 * 1024 + st * 64 + qd * 8);
      Vr[nj * 2 + 1] = *(const short8*)(vbase + (size_t)nj * 16 * 1024 + st * 64 + 32 + qd * 8);
    }
    float2 cs = stats[(size_t)bh * 1024 + st * 64 + w * 16 + t];
    f32x4 S0 = {0.f, 0.f, 0.f, 0.f}, S1 = {0.f, 0.f, 0.f, 0.f};
#pragma unroll
    for (int ks = 0; ks < 12; ks += 2) {
      short8 B0 = *(const short8*)(sp + ks * 32);
      short8 B1 = *(const short8*)(sp + (ks + 1) * 32);
      S0 = MFMA_BF16(Ah[ks], B0, S0);
      S1 = MFMA_BF16(Ah[ks + 1], B1, S1);
    }
#pragma unroll
    for (int r = 0; r < 4; ++r) {
      float p = __expf((S0[r] + S1[r]) * scale - cs.x) * cs.y;
      P[pb][(qd * 4 + r) * 72 + w * 16 + t] = f2b(p);
    }
    __syncthreads();
    short8 Pa0 = *(const short8*)&P[pb][t * 72 + qd * 8];
    short8 Pa1 = *(const short8*)&P[pb][t * 72 + 32 + qd * 8];
#pragma unroll
    for (int nj = 0; nj < 6; ++nj) {
      acc[nj] = MFMA_BF16(Pa0, Vr[nj * 2], acc[nj]);
      acc[nj] = MFMA_BF16(Pa1, Vr[nj * 2 + 1], acc[nj]);
    }
  }
  const int b_out = bh / 3, off = (1 + bh % 3) * 384;
#pragma unroll
  for (int nj = 0; nj < 6; ++nj)
#pragma unroll
    for (int r = 0; r < 4; ++r) {
      int row = o0 + qd * 4 + r;
      int d = w * 96 + nj * 16 + t;
      xall[((size_t)b_out * 1024 + row) * 1536 + off + d] = f2b(acc[nj][r]);
    }
}

// ---------------- att1 stats (split hi/lo, f32-precision scores, scale=1).
// Per iter 32 stream rows. Waves 0,1: hh+lh chains + softmax state for sub w.
// Waves 2,3: hl chain (str-lo in regs) -> partial to LDS. K fragments direct
// to registers; Sp double-buffered -> ONE barrier/iter.
__global__ __launch_bounds__(256) void att1_stats(
    const u16* __restrict__ qh, const u16* __restrict__ ql,
    const u16* __restrict__ kh, const u16* __restrict__ kl,
    float2* __restrict__ stats) {
  __shared__ float Sp[2][2][16][17];
  __shared__ float2 comb[2][16];
  const int tid = threadIdx.x, w = tid >> 6, lane = tid & 63;
  const int t = lane & 15, qd = lane >> 4;
  const int bh = blockIdx.y, o0 = blockIdx.x * 16;
  const int ss = w & 1;
  const bool scorer = (w < 2);
  short8 Ah[12], R2[12];  // R2: q-lo (scorers, persistent) / str-lo (w23, per-iter)
  {
    const u16* qp = qh + ((size_t)bh * 1024 + o0 + t) * 384 + qd * 8;
#pragma unroll
    for (int ks = 0; ks < 12; ++ks) Ah[ks] = *(const short8*)(qp + ks * 32);
    if (scorer) {
      const u16* qp2 = ql + ((size_t)bh * 1024 + o0 + t) * 384 + qd * 8;
#pragma unroll
      for (int ks = 0; ks < 12; ++ks) R2[ks] = *(const short8*)(qp2 + ks * 32);
    }
  }
  float m[4] = {-1e30f, -1e30f, -1e30f, -1e30f}, l[4] = {0.f, 0.f, 0.f, 0.f};
  for (int st = 0; st < 32; ++st) {
    const int pb = st & 1;
    f32x4 S0 = {0.f, 0.f, 0.f, 0.f}, S1 = {0.f, 0.f, 0.f, 0.f};
    if (scorer) {
      const u16* kp = kh + ((size_t)bh * 1024 + st * 32 + w * 16 + t) * 384 + qd * 8;
#pragma unroll
      for (int ks = 0; ks < 12; ++ks) {
        short8 Bh = *(const short8*)(kp + ks * 32);
        S0 = MFMA_BF16(Ah[ks], Bh, S0);
        S1 = MFMA_BF16(R2[ks], Bh, S1);
      }
    } else {
      const u16* kp = kl + ((size_t)bh * 1024 + st * 32 + ss * 16 + t) * 384 + qd * 8;
#pragma unroll
      for (int ks = 0; ks < 12; ++ks) R2[ks] = *(const short8*)(kp + ks * 32);
#pragma unroll
      for (int ks = 0; ks < 12; ks += 2) {
        S0 = MFMA_BF16(Ah[ks], R2[ks], S0);
        S1 = MFMA_BF16(Ah[ks + 1], R2[ks + 1], S1);
      }
#pragma unroll
      for (int r = 0; r < 4; ++r) Sp[pb][ss][qd * 4 + r][t] = S0[r] + S1[r];
    }
    __syncthreads();  // Sp[pb] ready
    if (scorer) {
#pragma unroll
      for (int r = 0; r < 4; ++r) {
        float s = S0[r] + S1[r] + Sp[pb][w][qd * 4 + r][t];
        float mx = s;
#pragma unroll
        for (int mk = 1; mk < 16; mk <<= 1) mx = fmaxf(mx, __shfl_xor(mx, mk));
        float nm = fmaxf(m[r], mx);
        float e = __expf(s - nm);
#pragma unroll
        for (int mk = 1; mk < 16; mk <<= 1) e += __shfl_xor(e, mk);
        l[r] = l[r] * __expf(m[r] - nm) + e;
        m[r] = nm;
      }
    }
  }
  if (scorer && t == 0) {
#pragma unroll
    for (int r = 0; r < 4; ++r) comb[w][qd * 4 + r] = make_float2(m[r], l[r]);
  }
  __syncthreads();
  if (tid < 16) {
    float2 a = comb[0][tid], b = comb[1][tid];
    float nm = fmaxf(a.x, b.x);
    float ll = a.y * __expf(a.x - nm) + b.y * __expf(b.x - nm);
    stats[(size_t)bh * 1024 + o0 + tid] = make_float2(nm, 1.f / ll);
  }
}

// ---------------- att1 accumulate (split scores, standard attn direction).
// K fragments direct to registers; Sp and P double-buffered -> two barriers/iter.
__global__ __launch_bounds__(256) void att1_accum(
    const u16* __restrict__ qh, const u16* __restrict__ ql,
    const u16* __restrict__ kh, const u16* __restrict__ kl,
    const u16* __restrict__ vt, const float2* __restrict__ stats,
    u16* __restrict__ xall) {
  __shared__ float Sp[2][2][16][17];
  __shared__ __align__(16) u16 P[2][16 * 40];
  const int tid = threadIdx.x, w = tid >> 6, lane = tid & 63;
  const int t = lane & 15, qd = lane >> 4;
  const int bh = blockIdx.y, o0 = blockIdx.x * 16;
  const int ss = w & 1;
  const bool scorer = (w < 2);
  short8 Ah[12], R2[12];
  float sm[4], sr[4];
  {
    const u16* qp = qh + ((size_t)bh * 1024 + o0 + t) * 384 + qd * 8;
#pragma unroll
    for (int ks = 0; ks < 12; ++ks) Ah[ks] = *(const short8*)(qp + ks * 32);
    if (scorer) {
      const u16* qp2 = ql + ((size_t)bh * 1024 + o0 + t) * 384 + qd * 8;
#pragma unroll
      for (int ks = 0; ks < 12; ++ks) R2[ks] = *(const short8*)(qp2 + ks * 32);
#pragma unroll
      for (int r = 0; r < 4; ++r) {
        float2 s2 = stats[(size_t)bh * 1024 + o0 + qd * 4 + r];
        sm[r] = s2.x; sr[r] = s2.y;
      }
    }
  }
  f32x4 acc[6];
#pragma unroll
  for (int i = 0; i < 6; ++i) acc[i] = (f32x4){0.f, 0.f, 0.f, 0.f};
  const u16* vbase = vt + ((size_t)bh * 384 + w * 96 + t) * 1024;
  for (int st = 0; st < 32; ++st) {
    const int pb = st & 1;
    f32x4 S0 = {0.f, 0.f, 0.f, 0.f}, S1 = {0.f, 0.f, 0.f, 0.f};
    if (scorer) {
      const u16* kp = kh + ((size_t)bh * 1024 + st * 32 + w * 16 + t) * 384 + qd * 8;
#pragma unroll
      for (int ks = 0; ks < 12; ++ks) {
        short8 Bh = *(const short8*)(kp + ks * 32);
        S0 = MFMA_BF16(Ah[ks], Bh, S0);
        S1 = MFMA_BF16(R2[ks], Bh, S1);
      }
    } else {
      const u16* kp = kl + ((size_t)bh * 1024 + st * 32 + ss * 16 + t) * 384 + qd * 8;
#pragma unroll
      for (int ks = 0; ks < 12; ++ks) R2[ks] = *(const short8*)(kp + ks * 32);
#pragma unroll
      for (int ks = 0; ks < 12; ks += 2) {
        S0 = MFMA_BF16(Ah[ks], R2[ks], S0);
        S1 = MFMA_BF16(Ah[ks + 1], R2[ks + 1], S1);
      }
#pragma unroll
      for (int r = 0; r < 4; ++r) Sp[pb][ss][qd * 4 + r][t] = S0[r] + S1[r];
    }
    short8 Vr[6];
#pragma unroll
    for (int nj = 0; nj < 6; ++nj)
      Vr[nj] = *(const short8*)(vbase + (size_t)nj * 16 * 1024 + st * 32 + qd * 8);
    __syncthreads();  // #1: Sp[pb] ready
    if (scorer) {
#pragma unroll
      for (int r = 0; r < 4; ++r) {
        float s = S0[r] + S1[r] + Sp[pb][w][qd * 4 + r][t];
        float p = __expf(s - sm[r]) * sr[r];
        P[pb][(qd * 4 + r) * 40 + w * 16 + t] = f2b(p);
      }
    }
    __syncthreads();  // #2: P[pb] ready
    short8 Pa = *(const short8*)&P[pb][t * 40 + qd * 8];
#pragma unroll
    for (int nj = 0; nj < 6; ++nj) acc[nj] = MFMA_BF16(Pa, Vr[nj], acc[nj]);
  }
#pragma unroll
  for (int nj = 0; nj < 6; ++nj)
#pragma unroll
    for (int r = 0; r < 4; ++r) {
      int row = o0 + qd * 4 + r;
      int d = w * 96 + nj * 16 + t;
      xall[((size_t)bh * 1024 + row) * 1536 + d] = f2b(acc[nj][r]);
    }
}

// ---------------- IWT: xall (B,1024,1536) -> y (B,4096,384)
__global__ __launch_bounds__(256) void iwt_y(const u16* __restrict__ xall, u16* __restrict__ y) {
  const int blk = blockIdx.x;
  const int b = blk >> 10, pos = blk & 1023;
  const int i = pos >> 5, j = pos & 31;
  const u16* xr = xall + (size_t)(b * 1024 + pos) * 1536;
  u16* yb = y + (size_t)b * 4096 * 384;
  const int p00 = (i * 2) * 64 + j * 2;
  for (int c = threadIdx.x; c < 384; c += 256) {
    float g1 = 0.5f * b2f(xr[c]);
    float g2 = 0.5f * b2f(xr[c + 384]);
    float g3 = 0.5f * b2f(xr[c + 768]);
    float g4 = 0.5f * b2f(xr[c + 1152]);
    yb[(size_t)p00 * 384 + c]        = f2b(g1 - g2 - g3 + g4);
    yb[(size_t)(p00 + 64) * 384 + c] = f2b(g1 - g2 + g3 - g4);
    yb[(size_t)(p00 + 1) * 384 + c]  = f2b(g1 + g2 - g3 - g4);
    yb[(size_t)(p00 + 65) * 384 + c] = f2b(g1 + g2 + g3 + g4);
  }
}

extern "C" void kernel_launch(void* const* d_in, const int* in_sizes, int n_in,
                              void* d_out, int out_size, void* d_ws, size_t ws_size,
                              hipStream_t stream) {
  (void)in_sizes; (void)n_in; (void)out_size; (void)ws_size;
  const float* sf      = (const float*)d_in[0];
  const float* wf      = (const float*)d_in[1];
  const float* q_w     = (const float*)d_in[2];
  const float* q_b     = (const float*)d_in[3];
  const float* q_ln_w  = (const float*)d_in[4];
  const float* q_ln_b  = (const float*)d_in[5];
  const float* kv_w    = (const float*)d_in[6];
  const float* kv_b    = (const float*)d_in[7];
  const float* kv_ln_w = (const float*)d_in[8];
  const float* kv_ln_b = (const float*)d_in[9];
  const float* out_w   = (const float*)d_in[10];
  const float* out_b   = (const float*)d_in[11];
  float* out = (float*)d_out;

  // ---- workspace layout, ~168 MiB peak with phase aliasing ----
  char* p = (char*)d_ws;
  float* A  = (float*)p; p += 50331648;   // t_sf f32; later k1h|k1l|v1|k2|v1t
  float* B1 = (float*)p; p += 50331648;   // t_wf lo f32; later xall
  u16*   B2 = (u16*)p;   p += 25165824;   // t_wf hi bf16; later v2t; later y
  u16* q1h = (u16*)p; p += 6291456;       // (8,1024,384) bf16 hi
  u16* q1l = (u16*)p; p += 6291456;       // lo
  u16* q2  = (u16*)p; p += 18874368;      // (24,1024,384) bf16
  u16* v2  = (u16*)p; p += 18874368;      // (24,1024,384) bf16 row-major
  float2* stats1 = (float2*)p; p += 65536;    // 8192 float2
  float2* stats2 = (float2*)p;                // 24576 float2
  // aliases inside A (t_sf dead after dwt_sf):
  u16* k1h = (u16*)A;
  u16* k1l = k1h + 3145728;
  u16* v1  = k1l + 3145728;
  u16* k2  = v1 + 3145728;
  u16* v1t = k2 + 9437184;            // (8,384,1024)
  u16* xall = (u16*)B1;               // (8,1024,1536)
  u16* v2t = B2;                      // (24,384,1024)
  u16* y   = B2;                      // (8,4096,384)

  // projections (MFMA) + LN; att1 score chain stays f32-precision via split
  gemm_mfma<1, float, float><<<dim3(3, 256), 256, 0, stream>>>(sf, q_w, q_b, A);
  ln_inplace<float><<<32768, 256, 0, stream>>>(A, q_ln_w, q_ln_b, 384);
  gemm_mfma<1, float, float><<<dim3(3, 256), 256, 0, stream>>>(wf, kv_w, kv_b, B1);
  gemm_mfma<0, float, u16><<<dim3(3, 256), 256, 0, stream>>>(wf, kv_w + 384 * 384, kv_b + 384, B2);
  ln_wf_split<<<32768, 256, 0, stream>>>(B1, B2, kv_ln_w, kv_ln_b);

  // DWT (dwt_sf must read A before k1/v1/k2/v1t overwrite it)
  dwt_sf<<<8192, 256, 0, stream>>>(A, q1h, q1l, q2);
  dwt_wf_split<<<8192, 256, 0, stream>>>(B1, B2, k1h, k1l, v1, k2, v2);

  // V transposes for MFMA B-operand layout
  transpose_rm<<<dim3(6, 16, 8), 256, 0, stream>>>(v1, v1t);
  transpose_rm<<<dim3(6, 16, 24), 256, 0, stream>>>(v2, v2t);  // overwrites dead t_wf-hi

  // attention
  att1_stats<<<dim3(64, 8), 256, 0, stream>>>(q1h, q1l, k1h, k1l, stats1);
  att2_stats<<<dim3(64, 24), 256, 0, stream>>>(q2, k2, stats2, SCALE2);
  att1_accum<<<dim3(64, 8), 256, 0, stream>>>(q1h, q1l, k1h, k1l, v1t, stats1, xall);
  att2_accum<<<dim3(64, 24), 256, 0, stream>>>(k2, q2, v2t, stats2, xall, SCALE2);

  // IWT + output projection (MFMA)
  iwt_y<<<8192, 256, 0, stream>>>(xall, y);
  gemm_mfma<0, u16, float><<<dim3(3, 256), 256, 0, stream>>>(y, out_w, out_b, out);
}

// Round 2
// 1098.162 us; speedup vs baseline: 1.0134x; 1.0134x over previous
//
#include <hip/hip_runtime.h>
#include <hip/hip_bf16.h>

typedef unsigned short u16;
typedef unsigned int u32;
typedef __attribute__((ext_vector_type(8))) short short8;   // 8 bf16 (4 VGPRs)
typedef __attribute__((ext_vector_type(4))) float f32x4;    // MFMA C/D

#define MFMA_BF16(A, B, C) __builtin_amdgcn_mfma_f32_16x16x32_bf16(A, B, C, 0, 0, 0)

#define SCALE2 0.08838834764831845f
#define LNEPS 1e-5f

__device__ __forceinline__ float b2f(u16 u) {
  return __uint_as_float(((u32)u) << 16);
}
__device__ __forceinline__ u16 f2b(float f) {
  u32 x = __float_as_uint(f);
  return (u16)((x + 0x7fffu + ((x >> 16) & 1u)) >> 16);  // RNE
}
__device__ __forceinline__ float ldf(const float* p) { return *p; }
__device__ __forceinline__ float ldf(const u16* p) { return b2f(*p); }
__device__ __forceinline__ void stf(float* p, float v) { *p = v; }
__device__ __forceinline__ void stf(u16* p, float v) { *p = f2b(v); }

// ---------------- MFMA GEMM: out[m][n] = sum_k X[m][k]*W[n][k] + bias[n]
// K=384, N=384. Block 128Mx128N, 4 waves (2x2 of 64x64). SPLIT: hi/lo bf16
// 3-product f32-precision (X must be float).
template <int SPLIT, typename TX, typename TO>
__global__ __launch_bounds__(256) void gemm_mfma(
    const TX* __restrict__ X, const float* __restrict__ W,
    const float* __restrict__ bias, TO* __restrict__ out) {
  __shared__ __align__(16) u16 AH[128 * 40];
  __shared__ __align__(16) u16 BH[128 * 40];
  __shared__ __align__(16) u16 AL[SPLIT ? 128 * 40 : 8];
  __shared__ __align__(16) u16 BL[SPLIT ? 128 * 40 : 8];
  const int tid = threadIdx.x;
  const int w = tid >> 6, lane = tid & 63;
  const int t = lane & 15, qd = lane >> 4;
  const int wm = w & 1, wn = w >> 1;
  const int m0 = blockIdx.y * 128, n0 = blockIdx.x * 128;
  f32x4 acc[4][4];
#pragma unroll
  for (int i = 0; i < 4; ++i)
#pragma unroll
    for (int j = 0; j < 4; ++j) acc[i][j] = (f32x4){0.f, 0.f, 0.f, 0.f};
  for (int kt = 0; kt < 384; kt += 32) {
    // stage A (128x32) and B (128x32) with f32->bf16 convert
#pragma unroll
    for (int rep = 0; rep < 4; ++rep) {
      int e = tid + rep * 256;
      int m = e >> 3, k4 = (e & 7) * 4;
      if constexpr (sizeof(TX) == 4) {
        float4 v = *(const float4*)(X + (size_t)(m0 + m) * 384 + kt + k4);
        u16 h0 = f2b(v.x), h1 = f2b(v.y), h2 = f2b(v.z), h3 = f2b(v.w);
        u32 hp0 = (u32)h0 | ((u32)h1 << 16), hp1 = (u32)h2 | ((u32)h3 << 16);
        *(uint2*)&AH[m * 40 + k4] = make_uint2(hp0, hp1);
        if (SPLIT) {
          u16 l0 = f2b(v.x - b2f(h0)), l1 = f2b(v.y - b2f(h1));
          u16 l2 = f2b(v.z - b2f(h2)), l3 = f2b(v.w - b2f(h3));
          *(uint2*)&AL[m * 40 + k4] =
              make_uint2((u32)l0 | ((u32)l1 << 16), (u32)l2 | ((u32)l3 << 16));
        }
      } else {
        uint2 raw = *(const uint2*)(X + (size_t)(m0 + m) * 384 + kt + k4);
        *(uint2*)&AH[m * 40 + k4] = raw;
      }
      float4 wv = *(const float4*)(W + (size_t)(n0 + m) * 384 + kt + k4);
      u16 wh0 = f2b(wv.x), wh1 = f2b(wv.y), wh2 = f2b(wv.z), wh3 = f2b(wv.w);
      *(uint2*)&BH[m * 40 + k4] =
          make_uint2((u32)wh0 | ((u32)wh1 << 16), (u32)wh2 | ((u32)wh3 << 16));
      if (SPLIT) {
        u16 wl0 = f2b(wv.x - b2f(wh0)), wl1 = f2b(wv.y - b2f(wh1));
        u16 wl2 = f2b(wv.z - b2f(wh2)), wl3 = f2b(wv.w - b2f(wh3));
        *(uint2*)&BL[m * 40 + k4] =
            make_uint2((u32)wl0 | ((u32)wl1 << 16), (u32)wl2 | ((u32)wl3 << 16));
      }
    }
    __syncthreads();
    short8 af[4], bf[4], al[4], bl[4];
#pragma unroll
    for (int mi = 0; mi < 4; ++mi) {
      af[mi] = *(const short8*)&AH[(wm * 64 + mi * 16 + t) * 40 + qd * 8];
      bf[mi] = *(const short8*)&BH[(wn * 64 + mi * 16 + t) * 40 + qd * 8];
      if (SPLIT) {
        al[mi] = *(const short8*)&AL[(wm * 64 + mi * 16 + t) * 40 + qd * 8];
        bl[mi] = *(const short8*)&BL[(wn * 64 + mi * 16 + t) * 40 + qd * 8];
      }
    }
#pragma unroll
    for (int mi = 0; mi < 4; ++mi)
#pragma unroll
      for (int ni = 0; ni < 4; ++ni) {
        acc[mi][ni] = MFMA_BF16(af[mi], bf[ni], acc[mi][ni]);
        if (SPLIT) {
          acc[mi][ni] = MFMA_BF16(al[mi], bf[ni], acc[mi][ni]);
          acc[mi][ni] = MFMA_BF16(af[mi], bl[ni], acc[mi][ni]);
        }
      }
    __syncthreads();
  }
#pragma unroll
  for (int ni = 0; ni < 4; ++ni) {
    int n = n0 + wn * 64 + ni * 16 + t;
    float bv = bias[n];
#pragma unroll
    for (int mi = 0; mi < 4; ++mi)
#pragma unroll
      for (int r = 0; r < 4; ++r) {
        int m = m0 + wm * 64 + mi * 16 + qd * 4 + r;
        stf(&out[(size_t)m * 384 + n], acc[mi][ni][r] + bv);
      }
  }
}

// ---------------- row LayerNorm, in place (templated storage)
template <typename T>
__global__ __launch_bounds__(256) void ln_inplace(
    T* __restrict__ Tb, const float* __restrict__ w, const float* __restrict__ b, int N) {
  const int row = blockIdx.x, tid = threadIdx.x;
  T* Tr = Tb + (size_t)row * N;
  float vals[3];
  float s = 0.f, ss = 0.f;
  int nv = 0;
  for (int i = tid; i < N; i += 256) {
    float v = ldf(&Tr[i]);
    vals[nv++] = v;
    s += v; ss += v * v;
  }
#pragma unroll
  for (int mk = 32; mk; mk >>= 1) { s += __shfl_xor(s, mk); ss += __shfl_xor(ss, mk); }
  __shared__ float red[8];
  if ((tid & 63) == 0) { red[tid >> 6] = s; red[4 + (tid >> 6)] = ss; }
  __syncthreads();
  s = red[0] + red[1] + red[2] + red[3];
  ss = red[4] + red[5] + red[6] + red[7];
  float inv = 1.f / (float)N;
  float mean = s * inv;
  float var = fmaxf(ss * inv - mean * mean, 0.f);
  float rstd = rsqrtf(var + LNEPS);
  nv = 0;
  for (int i = tid; i < N; i += 256) {
    float v = (vals[nv++] - mean) * rstd * w[i] + b[i];
    stf(&Tr[i], v);
  }
}

// ---------------- LN over split storage: lo = f32 chans 0..383, hi = bf16 chans 384..767
__global__ __launch_bounds__(256) void ln_wf_split(
    float* __restrict__ lo, u16* __restrict__ hi,
    const float* __restrict__ w, const float* __restrict__ b) {
  const int row = blockIdx.x, tid = threadIdx.x;
  float* L = lo + (size_t)row * 384;
  u16* H = hi + (size_t)row * 384;
  float vals[3];
  float s = 0.f, ss = 0.f;
  int nv = 0;
  for (int i = tid; i < 768; i += 256) {
    float v = (i < 384) ? L[i] : b2f(H[i - 384]);
    vals[nv++] = v;
    s += v; ss += v * v;
  }
#pragma unroll
  for (int mk = 32; mk; mk >>= 1) { s += __shfl_xor(s, mk); ss += __shfl_xor(ss, mk); }
  __shared__ float red[8];
  if ((tid & 63) == 0) { red[tid >> 6] = s; red[4 + (tid >> 6)] = ss; }
  __syncthreads();
  s = red[0] + red[1] + red[2] + red[3];
  ss = red[4] + red[5] + red[6] + red[7];
  float mean = s * (1.f / 768.f);
  float var = fmaxf(ss * (1.f / 768.f) - mean * mean, 0.f);
  float rstd = rsqrtf(var + LNEPS);
  nv = 0;
  for (int i = tid; i < 768; i += 256) {
    float v = (vals[nv++] - mean) * rstd * w[i] + b[i];
    if (i < 384) L[i] = v; else H[i - 384] = f2b(v);
  }
}

// ---------------- DWT sf: t_sf f32 -> q1 split-bf16 (hi+lo), q2 bf16 (3 heads)
__global__ __launch_bounds__(256) void dwt_sf(
    const float* __restrict__ T, u16* __restrict__ q1h, u16* __restrict__ q1l,
    u16* __restrict__ q2) {
  const int blk = blockIdx.x;
  const int b = blk >> 10, pos = blk & 1023;
  const int i = pos >> 5, j = pos & 31;
  const int p00 = (i * 2) * 64 + j * 2;
  const float* base = T + (size_t)b * 4096 * 384;
  for (int ch = threadIdx.x; ch < 384; ch += 256) {
    float a  = base[(size_t)p00 * 384 + ch];
    float cc = base[(size_t)(p00 + 1) * 384 + ch];
    float bb = base[(size_t)(p00 + 64) * 384 + ch];
    float dd = base[(size_t)(p00 + 65) * 384 + ch];
    float s0 = 0.5f * ( a + bb + cc + dd);
    float s1 = 0.5f * (-a - bb + cc + dd);
    float s2 = 0.5f * (-a + bb - cc + dd);
    float s3 = 0.5f * ( a - bb - cc + dd);
    size_t po = (size_t)(b * 1024 + pos) * 384 + ch;
    u16 h = f2b(s0);
    q1h[po] = h;
    q1l[po] = f2b(s0 - b2f(h));
    q2[(size_t)((b * 3 + 0) * 1024 + pos) * 384 + ch] = f2b(s1);
    q2[(size_t)((b * 3 + 1) * 1024 + pos) * 384 + ch] = f2b(s2);
    q2[(size_t)((b * 3 + 2) * 1024 + pos) * 384 + ch] = f2b(s3);
  }
}

// ---------------- DWT wf (split input): lo f32, hi bf16 -> k1 split-bf16, v1, k2, v2
__global__ __launch_bounds__(256) void dwt_wf_split(
    const float* __restrict__ lo, const u16* __restrict__ hi,
    u16* __restrict__ k1h, u16* __restrict__ k1l, u16* __restrict__ v1,
    u16* __restrict__ k2, u16* __restrict__ v2) {
  const int blk = blockIdx.x;
  const int b = blk >> 10, pos = blk & 1023;
  const int i = pos >> 5, j = pos & 31;
  const int p00 = (i * 2) * 64 + j * 2;
  for (int ch = threadIdx.x; ch < 768; ch += 256) {
    float a, bb, cc, dd;
    if (ch < 384) {
      const float* base = lo + (size_t)b * 4096 * 384;
      a  = base[(size_t)p00 * 384 + ch];
      cc = base[(size_t)(p00 + 1) * 384 + ch];
      bb = base[(size_t)(p00 + 64) * 384 + ch];
      dd = base[(size_t)(p00 + 65) * 384 + ch];
    } else {
      const u16* base = hi + (size_t)b * 4096 * 384;
      int c = ch - 384;
      a  = b2f(base[(size_t)p00 * 384 + c]);
      cc = b2f(base[(size_t)(p00 + 1) * 384 + c]);
      bb = b2f(base[(size_t)(p00 + 64) * 384 + c]);
      dd = b2f(base[(size_t)(p00 + 65) * 384 + c]);
    }
    float s0 = 0.5f * ( a + bb + cc + dd);
    float s1 = 0.5f * (-a - bb + cc + dd);
    float s2 = 0.5f * (-a + bb - cc + dd);
    float s3 = 0.5f * ( a - bb - cc + dd);
    if (ch < 384) {
      size_t po = (size_t)(b * 1024 + pos) * 384 + ch;
      u16 h = f2b(s0);
      k1h[po] = h;
      k1l[po] = f2b(s0 - b2f(h));
      v1[po] = f2b(s2);
      k2[(size_t)((b * 3 + 1) * 1024 + pos) * 384 + ch] = f2b(s1);
      v2[(size_t)((b * 3 + 1) * 1024 + pos) * 384 + ch] = f2b(s3);
    } else {
      int c = ch - 384;
      k2[(size_t)((b * 3 + 0) * 1024 + pos) * 384 + c] = f2b(s0);
      k2[(size_t)((b * 3 + 2) * 1024 + pos) * 384 + c] = f2b(s1);
      v2[(size_t)((b * 3 + 0) * 1024 + pos) * 384 + c] = f2b(s2);
      v2[(size_t)((b * 3 + 2) * 1024 + pos) * 384 + c] = f2b(s3);
    }
  }
}

// ---------------- transpose [bh][1024][384] -> [bh][384][1024]
__global__ __launch_bounds__(256) void transpose_rm(
    const u16* __restrict__ in, u16* __restrict__ out) {
  __shared__ u16 T[64][65];
  const int tid = threadIdx.x;
  const int bh = blockIdx.z, r0 = blockIdx.y * 64, c0 = blockIdx.x * 64;
  const u16* ip = in + ((size_t)bh * 1024 + r0) * 384 + c0;
  for (int i = tid; i < 2048; i += 256) {
    int r = i >> 5, c2 = i & 31;
    u32 v = *(const u32*)(ip + (size_t)r * 384 + c2 * 2);
    T[c2 * 2][r] = (u16)v;
    T[c2 * 2 + 1][r] = (u16)(v >> 16);
  }
  __syncthreads();
  u16* op = out + ((size_t)bh * 384 + c0) * 1024 + r0;
  for (int i = tid; i < 2048; i += 256) {
    int c = i >> 5, r2 = i & 31;
    u32 v = (u32)T[c][r2 * 2] | ((u32)T[c][r2 * 2 + 1] << 16);
    *(u32*)(op + (size_t)c * 1024 + r2 * 2) = v;
  }
}

// XCD-aware decode: hardware assigns workgroup L to XCD L%8. Group all blocks
// of one head on one XCD so its 2-3 MB working set stays L2-resident.
__device__ __forceinline__ void xcd24(int L, int& bh, int& o0) {
  int s = L >> 3;
  bh = ((s >> 6) << 3) | (L & 7);
  o0 = (s & 63) * 16;
}
__device__ __forceinline__ void xcd8(int L, int& bh, int& o0) {
  bh = L & 7;
  o0 = (L >> 3) * 16;
}

// ---------------- att2 stats: per query row m/l over all keys. 16 own rows;
// per iter 64 stream rows (16/wave), direct-to-register; XCD-swizzled.
__global__ __launch_bounds__(256) void att2_stats(
    const u16* __restrict__ q, const u16* __restrict__ k,
    float2* __restrict__ stats, float scale) {
  __shared__ float2 comb[4][16];
  const int tid = threadIdx.x, w = tid >> 6, lane = tid & 63;
  const int t = lane & 15, qd = lane >> 4;
  int bh, o0;
  xcd24(blockIdx.x, bh, o0);
  short8 Ah[12];
  {
    const u16* qp = q + ((size_t)bh * 1024 + o0 + t) * 384 + qd * 8;
#pragma unroll
    for (int ks = 0; ks < 12; ++ks) Ah[ks] = *(const short8*)(qp + ks * 32);
  }
  float m[4] = {-1e30f, -1e30f, -1e30f, -1e30f}, l[4] = {0.f, 0.f, 0.f, 0.f};
  for (int st = 0; st < 16; ++st) {
    const u16* kp = k + ((size_t)bh * 1024 + st * 64 + w * 16 + t) * 384 + qd * 8;
    f32x4 S0 = {0.f, 0.f, 0.f, 0.f}, S1 = {0.f, 0.f, 0.f, 0.f};
#pragma unroll
    for (int ks = 0; ks < 12; ks += 2) {
      short8 B0 = *(const short8*)(kp + ks * 32);
      short8 B1 = *(const short8*)(kp + (ks + 1) * 32);
      S0 = MFMA_BF16(Ah[ks], B0, S0);
      S1 = MFMA_BF16(Ah[ks + 1], B1, S1);
    }
#pragma unroll
    for (int r = 0; r < 4; ++r) {
      float s = (S0[r] + S1[r]) * scale;
      float mx = s;
#pragma unroll
      for (int mk = 1; mk < 16; mk <<= 1) mx = fmaxf(mx, __shfl_xor(mx, mk));
      float nm = fmaxf(m[r], mx);
      float e = __expf(s - nm);
#pragma unroll
      for (int mk = 1; mk < 16; mk <<= 1) e += __shfl_xor(e, mk);
      l[r] = l[r] * __expf(m[r] - nm) + e;
      m[r] = nm;
    }
  }
  if (t == 0) {
#pragma unroll
    for (int r = 0; r < 4; ++r) comb[w][qd * 4 + r] = make_float2(m[r], l[r]);
  }
  __syncthreads();
  if (tid < 16) {
    float nm = comb[0][tid].x;
#pragma unroll
    for (int ww = 1; ww < 4; ++ww) nm = fmaxf(nm, comb[ww][tid].x);
    float ll = 0.f;
#pragma unroll
    for (int ww = 0; ww < 4; ++ww) ll += comb[ww][tid].y * __expf(comb[ww][tid].x - nm);
    stats[(size_t)bh * 1024 + o0 + tid] = make_float2(nm, 1.f / ll);
  }
}

// ---------------- att2 accumulate (transposed gather): own=keys, stream=queries,
// stats indexed by stream rows. Direct-to-register; P double-buffered;
// one barrier/iter. XCD-swizzled.
__global__ __launch_bounds__(256) void att2_accum(
    const u16* __restrict__ own, const u16* __restrict__ str,
    const u16* __restrict__ vt, const float2* __restrict__ stats,
    u16* __restrict__ xall, float scale) {
  __shared__ __align__(16) u16 P[2][16 * 72];  // double-buffered 4.5 KB
  const int tid = threadIdx.x, w = tid >> 6, lane = tid & 63;
  const int t = lane & 15, qd = lane >> 4;
  int bh, o0;
  xcd24(blockIdx.x, bh, o0);
  short8 Ah[12];
  {
    const u16* op = own + ((size_t)bh * 1024 + o0 + t) * 384 + qd * 8;
#pragma unroll
    for (int ks = 0; ks < 12; ++ks) Ah[ks] = *(const short8*)(op + ks * 32);
  }
  f32x4 acc[6];
#pragma unroll
  for (int i = 0; i < 6; ++i) acc[i] = (f32x4){0.f, 0.f, 0.f, 0.f};
  const u16* vbase = vt + ((size_t)bh * 384 + w * 96 + t) * 1024;
  for (int st = 0; st < 16; ++st) {
    const int pb = st & 1;
    const u16* sp = str + ((size_t)bh * 1024 + st * 64 + w * 16 + t) * 384 + qd * 8;
    short8 Vr[12];
#pragma unroll
    for (int nj = 0; nj < 6; ++nj) {
      Vr[nj * 2]     = *(const short8*)(vbase + (size_t)nj * 16 * 1024 + st * 64 + qd * 8);
      Vr[nj * 2 + 1] = *(const short8*)(vbase + (size_t)nj * 16 * 1024 + st * 64 + 32 + qd * 8);
    }
    float2 cs = stats[(size_t)bh * 1024 + st * 64 + w * 16 + t];
    f32x4 S0 = {0.f, 0.f, 0.f, 0.f}, S1 = {0.f, 0.f, 0.f, 0.f};
#pragma unroll
    for (int ks = 0; ks < 12; ks += 2) {
      short8 B0 = *(const short8*)(sp + ks * 32);
      short8 B1 = *(const short8*)(sp + (ks + 1) * 32);
      S0 = MFMA_BF16(Ah[ks], B0, S0);
      S1 = MFMA_BF16(Ah[ks + 1], B1, S1);
    }
#pragma unroll
    for (int r = 0; r < 4; ++r) {
      float p = __expf((S0[r] + S1[r]) * scale - cs.x) * cs.y;
      P[pb][(qd * 4 + r) * 72 + w * 16 + t] = f2b(p);
    }
    __syncthreads();
    short8 Pa0 = *(const short8*)&P[pb][t * 72 + qd * 8];
    short8 Pa1 = *(const short8*)&P[pb][t * 72 + 32 + qd * 8];
#pragma unroll
    for (int nj = 0; nj < 6; ++nj) {
      acc[nj] = MFMA_BF16(Pa0, Vr[nj * 2], acc[nj]);
      acc[nj] = MFMA_BF16(Pa1, Vr[nj * 2 + 1], acc[nj]);
    }
  }
  const int b_out = bh / 3, off = (1 + bh % 3) * 384;
#pragma unroll
  for (int nj = 0; nj < 6; ++nj)
#pragma unroll
    for (int r = 0; r < 4; ++r) {
      int row = o0 + qd * 4 + r;
      int d = w * 96 + nj * 16 + t;
      xall[((size_t)b_out * 1024 + row) * 1536 + off + d] = f2b(acc[nj][r]);
    }
}

// ---------------- att1 stats (split hi/lo, f32-precision scores, scale=1).
// Direct-to-register; Sp double-buffered -> ONE barrier/iter. XCD-swizzled.
__global__ __launch_bounds__(256) void att1_stats(
    const u16* __restrict__ qh, const u16* __restrict__ ql,
    const u16* __restrict__ kh, const u16* __restrict__ kl,
    float2* __restrict__ stats) {
  __shared__ float Sp[2][2][16][17];
  __shared__ float2 comb[2][16];
  const int tid = threadIdx.x, w = tid >> 6, lane = tid & 63;
  const int t = lane & 15, qd = lane >> 4;
  int bh, o0;
  xcd8(blockIdx.x, bh, o0);
  const int ss = w & 1;
  const bool scorer = (w < 2);
  short8 Ah[12], R2[12];  // R2: q-lo (scorers, persistent) / str-lo (w23, per-iter)
  {
    const u16* qp = qh + ((size_t)bh * 1024 + o0 + t) * 384 + qd * 8;
#pragma unroll
    for (int ks = 0; ks < 12; ++ks) Ah[ks] = *(const short8*)(qp + ks * 32);
    if (scorer) {
      const u16* qp2 = ql + ((size_t)bh * 1024 + o0 + t) * 384 + qd * 8;
#pragma unroll
      for (int ks = 0; ks < 12; ++ks) R2[ks] = *(const short8*)(qp2 + ks * 32);
    }
  }
  float m[4] = {-1e30f, -1e30f, -1e30f, -1e30f}, l[4] = {0.f, 0.f, 0.f, 0.f};
  for (int st = 0; st < 32; ++st) {
    const int pb = st & 1;
    f32x4 S0 = {0.f, 0.f, 0.f, 0.f}, S1 = {0.f, 0.f, 0.f, 0.f};
    if (scorer) {
      const u16* kp = kh + ((size_t)bh * 1024 + st * 32 + w * 16 + t) * 384 + qd * 8;
#pragma unroll
      for (int ks = 0; ks < 12; ++ks) {
        short8 Bh = *(const short8*)(kp + ks * 32);
        S0 = MFMA_BF16(Ah[ks], Bh, S0);
        S1 = MFMA_BF16(R2[ks], Bh, S1);
      }
    } else {
      const u16* kp = kl + ((size_t)bh * 1024 + st * 32 + ss * 16 + t) * 384 + qd * 8;
#pragma unroll
      for (int ks = 0; ks < 12; ++ks) R2[ks] = *(const short8*)(kp + ks * 32);
#pragma unroll
      for (int ks = 0; ks < 12; ks += 2) {
        S0 = MFMA_BF16(Ah[ks], R2[ks], S0);
        S1 = MFMA_BF16(Ah[ks + 1], R2[ks + 1], S1);
      }
#pragma unroll
      for (int r = 0; r < 4; ++r) Sp[pb][ss][qd * 4 + r][t] = S0[r] + S1[r];
    }
    __syncthreads();  // Sp[pb] ready
    if (scorer) {
#pragma unroll
      for (int r = 0; r < 4; ++r) {
        float s = S0[r] + S1[r] + Sp[pb][w][qd * 4 + r][t];
        float mx = s;
#pragma unroll
        for (int mk = 1; mk < 16; mk <<= 1) mx = fmaxf(mx, __shfl_xor(mx, mk));
        float nm = fmaxf(m[r], mx);
        float e = __expf(s - nm);
#pragma unroll
        for (int mk = 1; mk < 16; mk <<= 1) e += __shfl_xor(e, mk);
        l[r] = l[r] * __expf(m[r] - nm) + e;
        m[r] = nm;
      }
    }
  }
  if (scorer && t == 0) {
#pragma unroll
    for (int r = 0; r < 4; ++r) comb[w][qd * 4 + r] = make_float2(m[r], l[r]);
  }
  __syncthreads();
  if (tid < 16) {
    float2 a = comb[0][tid], b = comb[1][tid];
    float nm = fmaxf(a.x, b.x);
    float ll = a.y * __expf(a.x - nm) + b.y * __expf(b.x - nm);
    stats[(size_t)bh * 1024 + o0 + tid] = make_float2(nm, 1.f / ll);
  }
}

// ---------------- att1 accumulate (split scores, standard attn direction).
// Direct-to-register; Sp and P double-buffered -> two barriers/iter. XCD-swizzled.
__global__ __launch_bounds__(256) void att1_accum(
    const u16* __restrict__ qh, const u16* __restrict__ ql,
    const u16* __restrict__ kh, const u16* __restrict__ kl,
    const u16* __restrict__ vt, const float2* __restrict__ stats,
    u16* __restrict__ xall) {
  __shared__ float Sp[2][2][16][17];
  __shared__ __align__(16) u16 P[2][16 * 40];
  const int tid = threadIdx.x, w = tid >> 6, lane = tid & 63;
  const int t = lane & 15, qd = lane >> 4;
  int bh, o0;
  xcd8(blockIdx.x, bh, o0);
  const int ss = w & 1;
  const bool scorer = (w < 2);
  short8 Ah[12], R2[12];
  float sm[4], sr[4];
  {
    const u16* qp = qh + ((size_t)bh * 1024 + o0 + t) * 384 + qd * 8;
#pragma unroll
    for (int ks = 0; ks < 12; ++ks) Ah[ks] = *(const short8*)(qp + ks * 32);
    if (scorer) {
      const u16* qp2 = ql + ((size_t)bh * 1024 + o0 + t) * 384 + qd * 8;
#pragma unroll
      for (int ks = 0; ks < 12; ++ks) R2[ks] = *(const short8*)(qp2 + ks * 32);
#pragma unroll
      for (int r = 0; r < 4; ++r) {
        float2 s2 = stats[(size_t)bh * 1024 + o0 + qd * 4 + r];
        sm[r] = s2.x; sr[r] = s2.y;
      }
    }
  }
  f32x4 acc[6];
#pragma unroll
  for (int i = 0; i < 6; ++i) acc[i] = (f32x4){0.f, 0.f, 0.f, 0.f};
  const u16* vbase = vt + ((size_t)bh * 384 + w * 96 + t) * 1024;
  for (int st = 0; st < 32; ++st) {
    const int pb = st & 1;
    f32x4 S0 = {0.f, 0.f, 0.f, 0.f}, S1 = {0.f, 0.f, 0.f, 0.f};
    if (scorer) {
      const u16* kp = kh + ((size_t)bh * 1024 + st * 32 + w * 16 + t) * 384 + qd * 8;
#pragma unroll
      for (int ks = 0; ks < 12; ++ks) {
        short8 Bh = *(const short8*)(kp + ks * 32);
        S0 = MFMA_BF16(Ah[ks], Bh, S0);
        S1 = MFMA_BF16(R2[ks], Bh, S1);
      }
    } else {
      const u16* kp = kl + ((size_t)bh * 1024 + st * 32 + ss * 16 + t) * 384 + qd * 8;
#pragma unroll
      for (int ks = 0; ks < 12; ++ks) R2[ks] = *(const short8*)(kp + ks * 32);
#pragma unroll
      for (int ks = 0; ks < 12; ks += 2) {
        S0 = MFMA_BF16(Ah[ks], R2[ks], S0);
        S1 = MFMA_BF16(Ah[ks + 1], R2[ks + 1], S1);
      }
#pragma unroll
      for (int r = 0; r < 4; ++r) Sp[pb][ss][qd * 4 + r][t] = S0[r] + S1[r];
    }
    short8 Vr[6];
#pragma unroll
    for (int nj = 0; nj < 6; ++nj)
      Vr[nj] = *(const short8*)(vbase + (size_t)nj * 16 * 1024 + st * 32 + qd * 8);
    __syncthreads();  // #1: Sp[pb] ready
    if (scorer) {
#pragma unroll
      for (int r = 0; r < 4; ++r) {
        float s = S0[r] + S1[r] + Sp[pb][w][qd * 4 + r][t];
        float p = __expf(s - sm[r]) * sr[r];
        P[pb][(qd * 4 + r) * 40 + w * 16 + t] = f2b(p);
      }
    }
    __syncthreads();  // #2: P[pb] ready
    short8 Pa = *(const short8*)&P[pb][t * 40 + qd * 8];
#pragma unroll
    for (int nj = 0; nj < 6; ++nj) acc[nj] = MFMA_BF16(Pa, Vr[nj], acc[nj]);
  }
#pragma unroll
  for (int nj = 0; nj < 6; ++nj)
#pragma unroll
    for (int r = 0; r < 4; ++r) {
      int row = o0 + qd * 4 + r;
      int d = w * 96 + nj * 16 + t;
      xall[((size_t)bh * 1024 + row) * 1536 + d] = f2b(acc[nj][r]);
    }
}

// ---------------- IWT: xall (B,1024,1536) -> y (B,4096,384)
__global__ __launch_bounds__(256) void iwt_y(const u16* __restrict__ xall, u16* __restrict__ y) {
  const int blk = blockIdx.x;
  const int b = blk >> 10, pos = blk & 1023;
  const int i = pos >> 5, j = pos & 31;
  const u16* xr = xall + (size_t)(b * 1024 + pos) * 1536;
  u16* yb = y + (size_t)b * 4096 * 384;
  const int p00 = (i * 2) * 64 + j * 2;
  for (int c = threadIdx.x; c < 384; c += 256) {
    float g1 = 0.5f * b2f(xr[c]);
    float g2 = 0.5f * b2f(xr[c + 384]);
    float g3 = 0.5f * b2f(xr[c + 768]);
    float g4 = 0.5f * b2f(xr[c + 1152]);
    yb[(size_t)p00 * 384 + c]        = f2b(g1 - g2 - g3 + g4);
    yb[(size_t)(p00 + 64) * 384 + c] = f2b(g1 - g2 + g3 - g4);
    yb[(size_t)(p00 + 1) * 384 + c]  = f2b(g1 + g2 - g3 - g4);
    yb[(size_t)(p00 + 65) * 384 + c] = f2b(g1 + g2 + g3 + g4);
  }
}

extern "C" void kernel_launch(void* const* d_in, const int* in_sizes, int n_in,
                              void* d_out, int out_size, void* d_ws, size_t ws_size,
                              hipStream_t stream) {
  (void)in_sizes; (void)n_in; (void)out_size; (void)ws_size;
  const float* sf      = (const float*)d_in[0];
  const float* wf      = (const float*)d_in[1];
  const float* q_w     = (const float*)d_in[2];
  const float* q_b     = (const float*)d_in[3];
  const float* q_ln_w  = (const float*)d_in[4];
  const float* q_ln_b  = (const float*)d_in[5];
  const float* kv_w    = (const float*)d_in[6];
  const float* kv_b    = (const float*)d_in[7];
  const float* kv_ln_w = (const float*)d_in[8];
  const float* kv_ln_b = (const float*)d_in[9];
  const float* out_w   = (const float*)d_in[10];
  const float* out_b   = (const float*)d_in[11];
  float* out = (float*)d_out;

  // ---- workspace layout, ~168 MiB peak with phase aliasing ----
  char* p = (char*)d_ws;
  float* A  = (float*)p; p += 50331648;   // t_sf f32; later k1h|k1l|v1|k2|v1t
  float* B1 = (float*)p; p += 50331648;   // t_wf lo f32; later xall
  u16*   B2 = (u16*)p;   p += 25165824;   // t_wf hi bf16; later v2t; later y
  u16* q1h = (u16*)p; p += 6291456;       // (8,1024,384) bf16 hi
  u16* q1l = (u16*)p; p += 6291456;       // lo
  u16* q2  = (u16*)p; p += 18874368;      // (24,1024,384) bf16
  u16* v2  = (u16*)p; p += 18874368;      // (24,1024,384) bf16 row-major
  float2* stats1 = (float2*)p; p += 65536;    // 8192 float2
  float2* stats2 = (float2*)p;                // 24576 float2
  // aliases inside A (t_sf dead after dwt_sf):
  u16* k1h = (u16*)A;
  u16* k1l = k1h + 3145728;
  u16* v1  = k1l + 3145728;
  u16* k2  = v1 + 3145728;
  u16* v1t = k2 + 9437184;            // (8,384,1024)
  u16* xall = (u16*)B1;               // (8,1024,1536)
  u16* v2t = B2;                      // (24,384,1024)
  u16* y   = B2;                      // (8,4096,384)

  // projections (MFMA) + LN; att1 score chain stays f32-precision via split
  gemm_mfma<1, float, float><<<dim3(3, 256), 256, 0, stream>>>(sf, q_w, q_b, A);
  ln_inplace<float><<<32768, 256, 0, stream>>>(A, q_ln_w, q_ln_b, 384);
  gemm_mfma<1, float, float><<<dim3(3, 256), 256, 0, stream>>>(wf, kv_w, kv_b, B1);
  gemm_mfma<0, float, u16><<<dim3(3, 256), 256, 0, stream>>>(wf, kv_w + 384 * 384, kv_b + 384, B2);
  ln_wf_split<<<32768, 256, 0, stream>>>(B1, B2, kv_ln_w, kv_ln_b);

  // DWT (dwt_sf must read A before k1/v1/k2/v1t overwrite it)
  dwt_sf<<<8192, 256, 0, stream>>>(A, q1h, q1l, q2);
  dwt_wf_split<<<8192, 256, 0, stream>>>(B1, B2, k1h, k1l, v1, k2, v2);

  // V transposes for MFMA B-operand layout
  transpose_rm<<<dim3(6, 16, 8), 256, 0, stream>>>(v1, v1t);
  transpose_rm<<<dim3(6, 16, 24), 256, 0, stream>>>(v2, v2t);  // overwrites dead t_wf-hi

  // attention (1D grids, XCD-swizzled inside the kernels)
  att1_stats<<<512, 256, 0, stream>>>(q1h, q1l, k1h, k1l, stats1);
  att2_stats<<<1536, 256, 0, stream>>>(q2, k2, stats2, SCALE2);
  att1_accum<<<512, 256, 0, stream>>>(q1h, q1l, k1h, k1l, v1t, stats1, xall);
  att2_accum<<<1536, 256, 0, stream>>>(k2, q2, v2t, stats2, xall, SCALE2);

  // IWT + output projection (MFMA)
  iwt_y<<<8192, 256, 0, stream>>>(xall, y);
  gemm_mfma<0, u16, float><<<dim3(3, 256), 256, 0, stream>>>(y, out_w, out_b, out);
}

// Round 3
// 860.292 us; speedup vs baseline: 1.2936x; 1.2765x over previous
//
#include <hip/hip_runtime.h>
#include <hip/hip_bf16.h>

typedef unsigned short u16;
typedef unsigned int u32;
typedef __attribute__((ext_vector_type(8))) short short8;   // 8 bf16 (4 VGPRs)
typedef __attribute__((ext_vector_type(4))) float f32x4;    // MFMA C/D

#define MFMA_BF16(A, B, C) __builtin_amdgcn_mfma_f32_16x16x32_bf16(A, B, C, 0, 0, 0)

#define SCALE2 0.08838834764831845f
#define LNEPS 1e-5f

__device__ __forceinline__ float b2f(u16 u) {
  return __uint_as_float(((u32)u) << 16);
}
__device__ __forceinline__ u16 f2b(float f) {
  u32 x = __float_as_uint(f);
  return (u16)((x + 0x7fffu + ((x >> 16) & 1u)) >> 16);  // RNE
}
__device__ __forceinline__ float ldf(const float* p) { return *p; }
__device__ __forceinline__ float ldf(const u16* p) { return b2f(*p); }
__device__ __forceinline__ void stf(float* p, float v) { *p = v; }
__device__ __forceinline__ void stf(u16* p, float v) { *p = f2b(v); }

// ---------------- MFMA GEMM: out[m][n] = sum_k X[m][k]*W[n][k] + bias[n]
// K=384, N=384. Block 128Mx128N, 4 waves (2x2 of 64x64). SPLIT: hi/lo bf16
// 3-product f32-precision (X must be float).
template <int SPLIT, typename TX, typename TO>
__global__ __launch_bounds__(256) void gemm_mfma(
    const TX* __restrict__ X, const float* __restrict__ W,
    const float* __restrict__ bias, TO* __restrict__ out) {
  __shared__ __align__(16) u16 AH[128 * 40];
  __shared__ __align__(16) u16 BH[128 * 40];
  __shared__ __align__(16) u16 AL[SPLIT ? 128 * 40 : 8];
  __shared__ __align__(16) u16 BL[SPLIT ? 128 * 40 : 8];
  const int tid = threadIdx.x;
  const int w = tid >> 6, lane = tid & 63;
  const int t = lane & 15, qd = lane >> 4;
  const int wm = w & 1, wn = w >> 1;
  const int m0 = blockIdx.y * 128, n0 = blockIdx.x * 128;
  f32x4 acc[4][4];
#pragma unroll
  for (int i = 0; i < 4; ++i)
#pragma unroll
    for (int j = 0; j < 4; ++j) acc[i][j] = (f32x4){0.f, 0.f, 0.f, 0.f};
  for (int kt = 0; kt < 384; kt += 32) {
    // stage A (128x32) and B (128x32) with f32->bf16 convert
#pragma unroll
    for (int rep = 0; rep < 4; ++rep) {
      int e = tid + rep * 256;
      int m = e >> 3, k4 = (e & 7) * 4;
      if constexpr (sizeof(TX) == 4) {
        float4 v = *(const float4*)(X + (size_t)(m0 + m) * 384 + kt + k4);
        u16 h0 = f2b(v.x), h1 = f2b(v.y), h2 = f2b(v.z), h3 = f2b(v.w);
        u32 hp0 = (u32)h0 | ((u32)h1 << 16), hp1 = (u32)h2 | ((u32)h3 << 16);
        *(uint2*)&AH[m * 40 + k4] = make_uint2(hp0, hp1);
        if (SPLIT) {
          u16 l0 = f2b(v.x - b2f(h0)), l1 = f2b(v.y - b2f(h1));
          u16 l2 = f2b(v.z - b2f(h2)), l3 = f2b(v.w - b2f(h3));
          *(uint2*)&AL[m * 40 + k4] =
              make_uint2((u32)l0 | ((u32)l1 << 16), (u32)l2 | ((u32)l3 << 16));
        }
      } else {
        uint2 raw = *(const uint2*)(X + (size_t)(m0 + m) * 384 + kt + k4);
        *(uint2*)&AH[m * 40 + k4] = raw;
      }
      float4 wv = *(const float4*)(W + (size_t)(n0 + m) * 384 + kt + k4);
      u16 wh0 = f2b(wv.x), wh1 = f2b(wv.y), wh2 = f2b(wv.z), wh3 = f2b(wv.w);
      *(uint2*)&BH[m * 40 + k4] =
          make_uint2((u32)wh0 | ((u32)wh1 << 16), (u32)wh2 | ((u32)wh3 << 16));
      if (SPLIT) {
        u16 wl0 = f2b(wv.x - b2f(wh0)), wl1 = f2b(wv.y - b2f(wh1));
        u16 wl2 = f2b(wv.z - b2f(wh2)), wl3 = f2b(wv.w - b2f(wh3));
        *(uint2*)&BL[m * 40 + k4] =
            make_uint2((u32)wl0 | ((u32)wl1 << 16), (u32)wl2 | ((u32)wl3 << 16));
      }
    }
    __syncthreads();
    short8 af[4], bf[4], al[4], bl[4];
#pragma unroll
    for (int mi = 0; mi < 4; ++mi) {
      af[mi] = *(const short8*)&AH[(wm * 64 + mi * 16 + t) * 40 + qd * 8];
      bf[mi] = *(const short8*)&BH[(wn * 64 + mi * 16 + t) * 40 + qd * 8];
      if (SPLIT) {
        al[mi] = *(const short8*)&AL[(wm * 64 + mi * 16 + t) * 40 + qd * 8];
        bl[mi] = *(const short8*)&BL[(wn * 64 + mi * 16 + t) * 40 + qd * 8];
      }
    }
#pragma unroll
    for (int mi = 0; mi < 4; ++mi)
#pragma unroll
      for (int ni = 0; ni < 4; ++ni) {
        acc[mi][ni] = MFMA_BF16(af[mi], bf[ni], acc[mi][ni]);
        if (SPLIT) {
          acc[mi][ni] = MFMA_BF16(al[mi], bf[ni], acc[mi][ni]);
          acc[mi][ni] = MFMA_BF16(af[mi], bl[ni], acc[mi][ni]);
        }
      }
    __syncthreads();
  }
#pragma unroll
  for (int ni = 0; ni < 4; ++ni) {
    int n = n0 + wn * 64 + ni * 16 + t;
    float bv = bias[n];
#pragma unroll
    for (int mi = 0; mi < 4; ++mi)
#pragma unroll
      for (int r = 0; r < 4; ++r) {
        int m = m0 + wm * 64 + mi * 16 + qd * 4 + r;
        stf(&out[(size_t)m * 384 + n], acc[mi][ni][r] + bv);
      }
  }
}

// ---------------- row LayerNorm, in place (templated storage)
template <typename T>
__global__ __launch_bounds__(256) void ln_inplace(
    T* __restrict__ Tb, const float* __restrict__ w, const float* __restrict__ b, int N) {
  const int row = blockIdx.x, tid = threadIdx.x;
  T* Tr = Tb + (size_t)row * N;
  float vals[3];
  float s = 0.f, ss = 0.f;
  int nv = 0;
  for (int i = tid; i < N; i += 256) {
    float v = ldf(&Tr[i]);
    vals[nv++] = v;
    s += v; ss += v * v;
  }
#pragma unroll
  for (int mk = 32; mk; mk >>= 1) { s += __shfl_xor(s, mk); ss += __shfl_xor(ss, mk); }
  __shared__ float red[8];
  if ((tid & 63) == 0) { red[tid >> 6] = s; red[4 + (tid >> 6)] = ss; }
  __syncthreads();
  s = red[0] + red[1] + red[2] + red[3];
  ss = red[4] + red[5] + red[6] + red[7];
  float inv = 1.f / (float)N;
  float mean = s * inv;
  float var = fmaxf(ss * inv - mean * mean, 0.f);
  float rstd = rsqrtf(var + LNEPS);
  nv = 0;
  for (int i = tid; i < N; i += 256) {
    float v = (vals[nv++] - mean) * rstd * w[i] + b[i];
    stf(&Tr[i], v);
  }
}

// ---------------- LN over split storage: lo = f32 chans 0..383, hi = bf16 chans 384..767
__global__ __launch_bounds__(256) void ln_wf_split(
    float* __restrict__ lo, u16* __restrict__ hi,
    const float* __restrict__ w, const float* __restrict__ b) {
  const int row = blockIdx.x, tid = threadIdx.x;
  float* L = lo + (size_t)row * 384;
  u16* H = hi + (size_t)row * 384;
  float vals[3];
  float s = 0.f, ss = 0.f;
  int nv = 0;
  for (int i = tid; i < 768; i += 256) {
    float v = (i < 384) ? L[i] : b2f(H[i - 384]);
    vals[nv++] = v;
    s += v; ss += v * v;
  }
#pragma unroll
  for (int mk = 32; mk; mk >>= 1) { s += __shfl_xor(s, mk); ss += __shfl_xor(ss, mk); }
  __shared__ float red[8];
  if ((tid & 63) == 0) { red[tid >> 6] = s; red[4 + (tid >> 6)] = ss; }
  __syncthreads();
  s = red[0] + red[1] + red[2] + red[3];
  ss = red[4] + red[5] + red[6] + red[7];
  float mean = s * (1.f / 768.f);
  float var = fmaxf(ss * (1.f / 768.f) - mean * mean, 0.f);
  float rstd = rsqrtf(var + LNEPS);
  nv = 0;
  for (int i = tid; i < 768; i += 256) {
    float v = (vals[nv++] - mean) * rstd * w[i] + b[i];
    if (i < 384) L[i] = v; else H[i - 384] = f2b(v);
  }
}

// ---------------- DWT sf: t_sf f32 -> q1 split-bf16 (hi+lo), q2 bf16 (3 heads)
__global__ __launch_bounds__(256) void dwt_sf(
    const float* __restrict__ T, u16* __restrict__ q1h, u16* __restrict__ q1l,
    u16* __restrict__ q2) {
  const int blk = blockIdx.x;
  const int b = blk >> 10, pos = blk & 1023;
  const int i = pos >> 5, j = pos & 31;
  const int p00 = (i * 2) * 64 + j * 2;
  const float* base = T + (size_t)b * 4096 * 384;
  for (int ch = threadIdx.x; ch < 384; ch += 256) {
    float a  = base[(size_t)p00 * 384 + ch];
    float cc = base[(size_t)(p00 + 1) * 384 + ch];
    float bb = base[(size_t)(p00 + 64) * 384 + ch];
    float dd = base[(size_t)(p00 + 65) * 384 + ch];
    float s0 = 0.5f * ( a + bb + cc + dd);
    float s1 = 0.5f * (-a - bb + cc + dd);
    float s2 = 0.5f * (-a + bb - cc + dd);
    float s3 = 0.5f * ( a - bb - cc + dd);
    size_t po = (size_t)(b * 1024 + pos) * 384 + ch;
    u16 h = f2b(s0);
    q1h[po] = h;
    q1l[po] = f2b(s0 - b2f(h));
    q2[(size_t)((b * 3 + 0) * 1024 + pos) * 384 + ch] = f2b(s1);
    q2[(size_t)((b * 3 + 1) * 1024 + pos) * 384 + ch] = f2b(s2);
    q2[(size_t)((b * 3 + 2) * 1024 + pos) * 384 + ch] = f2b(s3);
  }
}

// ---------------- DWT wf (split input): lo f32, hi bf16 -> k1 split-bf16, v1, k2, v2
__global__ __launch_bounds__(256) void dwt_wf_split(
    const float* __restrict__ lo, const u16* __restrict__ hi,
    u16* __restrict__ k1h, u16* __restrict__ k1l, u16* __restrict__ v1,
    u16* __restrict__ k2, u16* __restrict__ v2) {
  const int blk = blockIdx.x;
  const int b = blk >> 10, pos = blk & 1023;
  const int i = pos >> 5, j = pos & 31;
  const int p00 = (i * 2) * 64 + j * 2;
  for (int ch = threadIdx.x; ch < 768; ch += 256) {
    float a, bb, cc, dd;
    if (ch < 384) {
      const float* base = lo + (size_t)b * 4096 * 384;
      a  = base[(size_t)p00 * 384 + ch];
      cc = base[(size_t)(p00 + 1) * 384 + ch];
      bb = base[(size_t)(p00 + 64) * 384 + ch];
      dd = base[(size_t)(p00 + 65) * 384 + ch];
    } else {
      const u16* base = hi + (size_t)b * 4096 * 384;
      int c = ch - 384;
      a  = b2f(base[(size_t)p00 * 384 + c]);
      cc = b2f(base[(size_t)(p00 + 1) * 384 + c]);
      bb = b2f(base[(size_t)(p00 + 64) * 384 + c]);
      dd = b2f(base[(size_t)(p00 + 65) * 384 + c]);
    }
    float s0 = 0.5f * ( a + bb + cc + dd);
    float s1 = 0.5f * (-a - bb + cc + dd);
    float s2 = 0.5f * (-a + bb - cc + dd);
    float s3 = 0.5f * ( a - bb - cc + dd);
    if (ch < 384) {
      size_t po = (size_t)(b * 1024 + pos) * 384 + ch;
      u16 h = f2b(s0);
      k1h[po] = h;
      k1l[po] = f2b(s0 - b2f(h));
      v1[po] = f2b(s2);
      k2[(size_t)((b * 3 + 1) * 1024 + pos) * 384 + ch] = f2b(s1);
      v2[(size_t)((b * 3 + 1) * 1024 + pos) * 384 + ch] = f2b(s3);
    } else {
      int c = ch - 384;
      k2[(size_t)((b * 3 + 0) * 1024 + pos) * 384 + c] = f2b(s0);
      k2[(size_t)((b * 3 + 2) * 1024 + pos) * 384 + c] = f2b(s1);
      v2[(size_t)((b * 3 + 0) * 1024 + pos) * 384 + c] = f2b(s2);
      v2[(size_t)((b * 3 + 2) * 1024 + pos) * 384 + c] = f2b(s3);
    }
  }
}

// ---------------- transpose [bh][1024][384] -> [bh][384][1024]
__global__ __launch_bounds__(256) void transpose_rm(
    const u16* __restrict__ in, u16* __restrict__ out) {
  __shared__ u16 T[64][65];
  const int tid = threadIdx.x;
  const int bh = blockIdx.z, r0 = blockIdx.y * 64, c0 = blockIdx.x * 64;
  const u16* ip = in + ((size_t)bh * 1024 + r0) * 384 + c0;
  for (int i = tid; i < 2048; i += 256) {
    int r = i >> 5, c2 = i & 31;
    u32 v = *(const u32*)(ip + (size_t)r * 384 + c2 * 2);
    T[c2 * 2][r] = (u16)v;
    T[c2 * 2 + 1][r] = (u16)(v >> 16);
  }
  __syncthreads();
  u16* op = out + ((size_t)bh * 384 + c0) * 1024 + r0;
  for (int i = tid; i < 2048; i += 256) {
    int c = i >> 5, r2 = i & 31;
    u32 v = (u32)T[c][r2 * 2] | ((u32)T[c][r2 * 2 + 1] << 16);
    *(u32*)(op + (size_t)c * 1024 + r2 * 2) = v;
  }
}

// XCD-aware decode for att1 (8 heads): head h -> XCD h%8.
__device__ __forceinline__ void xcd8(int L, int& bh, int& o0) {
  bh = L & 7;
  o0 = (L >> 3) * 16;
}
// att2 v2 (24 heads x 16 blocks of 64 own rows): XCD x gets heads {x, x+8, x+16}.
__device__ __forceinline__ void xcd24v2(int L, int& bh, int& o0) {
  int s = L >> 3;
  bh = (s >> 4) * 8 + (L & 7);
  o0 = (s & 15) * 64;
}

// ---------------- att2 stats v2: block owns 64 q-rows (wave w -> 16 rows).
// Stream k2 in 32-row tiles staged to LDS ONCE per block (4x cross-wave reuse
// vs direct loads); double-buffered, 1 barrier/iter. Stats complete per wave.
__global__ __launch_bounds__(256) void att2_stats(
    const u16* __restrict__ q, const u16* __restrict__ k,
    float2* __restrict__ stats, float scale) {
  __shared__ __align__(16) u16 S[2][12 * 32 * 40];  // 61440 B, stride-40 pad
  const int tid = threadIdx.x, w = tid >> 6, lane = tid & 63;
  const int t = lane & 15, qd = lane >> 4;
  int bh, o0;
  xcd24v2(blockIdx.x, bh, o0);
  short8 Ah[12];
  {
    const u16* qp = q + ((size_t)bh * 1024 + o0 + w * 16 + t) * 384 + qd * 8;
#pragma unroll
    for (int ks = 0; ks < 12; ++ks) Ah[ks] = *(const short8*)(qp + ks * 32);
  }
  float m[4] = {-1e30f, -1e30f, -1e30f, -1e30f}, l[4] = {0.f, 0.f, 0.f, 0.f};
  const u16* kb = k + (size_t)bh * 1024 * 384;
  int buf = 0;
  for (int st = 0; st < 32; ++st) {
    // stage stream rows st*32..+32: unit = 8 u16; [row][c8] -> S[ks][row][qq*8]
#pragma unroll
    for (int i = 0; i < 6; ++i) {
      int u = tid + i * 256;
      int r = u / 48, c8 = u % 48;
      int ks = c8 >> 2, qq = c8 & 3;
      uint4 v = *(const uint4*)(kb + (size_t)(st * 32 + r) * 384 + c8 * 8);
      *(uint4*)&S[buf][(ks * 32 + r) * 40 + qq * 8] = v;
    }
    __syncthreads();
    f32x4 Sa0 = {0.f,0.f,0.f,0.f}, Sb0 = {0.f,0.f,0.f,0.f};
    f32x4 Sa1 = {0.f,0.f,0.f,0.f}, Sb1 = {0.f,0.f,0.f,0.f};
#pragma unroll
    for (int ks = 0; ks < 12; ks += 2) {
      short8 B00 = *(const short8*)&S[buf][(ks * 32 + t) * 40 + qd * 8];
      short8 B01 = *(const short8*)&S[buf][((ks + 1) * 32 + t) * 40 + qd * 8];
      short8 B10 = *(const short8*)&S[buf][(ks * 32 + 16 + t) * 40 + qd * 8];
      short8 B11 = *(const short8*)&S[buf][((ks + 1) * 32 + 16 + t) * 40 + qd * 8];
      Sa0 = MFMA_BF16(Ah[ks], B00, Sa0);
      Sb0 = MFMA_BF16(Ah[ks + 1], B01, Sb0);
      Sa1 = MFMA_BF16(Ah[ks], B10, Sa1);
      Sb1 = MFMA_BF16(Ah[ks + 1], B11, Sb1);
    }
#pragma unroll
    for (int r = 0; r < 4; ++r) {
      float s0 = (Sa0[r] + Sb0[r]) * scale;
      float s1 = (Sa1[r] + Sb1[r]) * scale;
      float mx = fmaxf(s0, s1);
#pragma unroll
      for (int mk = 1; mk < 16; mk <<= 1) mx = fmaxf(mx, __shfl_xor(mx, mk));
      float nm = fmaxf(m[r], mx);
      float e = __expf(s0 - nm) + __expf(s1 - nm);
#pragma unroll
      for (int mk = 1; mk < 16; mk <<= 1) e += __shfl_xor(e, mk);
      l[r] = l[r] * __expf(m[r] - nm) + e;
      m[r] = nm;
    }
    buf ^= 1;
  }
  if (t == 0) {
#pragma unroll
    for (int r = 0; r < 4; ++r)
      stats[(size_t)bh * 1024 + o0 + w * 16 + qd * 4 + r] =
          make_float2(m[r], 1.f / l[r]);
  }
}

// ---------------- att2 accumulate v2 (transposed gather): block owns 64 k2
// rows (wave w -> 16 output rows x ALL 384 dims, acc[24]). Stream q2 tile (32
// rows) + V tile (384x32) staged to LDS once per block; single-buffer, two
// barriers/iter. P is wave-private LDS (no cross-wave barrier).
__global__ __launch_bounds__(256, 2) void att2_accum(
    const u16* __restrict__ own, const u16* __restrict__ str,
    const u16* __restrict__ vt, const float2* __restrict__ stats,
    u16* __restrict__ xall, float scale) {
  __shared__ __align__(16) u16 SQ[12 * 32 * 40];   // 30720 B
  __shared__ __align__(16) u16 SV[24 * 16 * 40];   // 30720 B
  __shared__ __align__(16) u16 P[4][16 * 40];      // 5120 B, wave-private
  const int tid = threadIdx.x, w = tid >> 6, lane = tid & 63;
  const int t = lane & 15, qd = lane >> 4;
  int bh, o0;
  xcd24v2(blockIdx.x, bh, o0);
  short8 Ah[12];
  {
    const u16* op = own + ((size_t)bh * 1024 + o0 + w * 16 + t) * 384 + qd * 8;
#pragma unroll
    for (int ks = 0; ks < 12; ++ks) Ah[ks] = *(const short8*)(op + ks * 32);
  }
  f32x4 acc[24];
#pragma unroll
  for (int i = 0; i < 24; ++i) acc[i] = (f32x4){0.f, 0.f, 0.f, 0.f};
  const u16* sb = str + (size_t)bh * 1024 * 384;
  const u16* vb = vt + (size_t)bh * 384 * 1024;
  u16* Pw = &P[w][0];
  for (int st = 0; st < 32; ++st) {
    __syncthreads();  // all waves done reading SQ/SV from previous iter
#pragma unroll
    for (int i = 0; i < 6; ++i) {
      int u = tid + i * 256;
      int r = u / 48, c8 = u % 48;
      int ks = c8 >> 2, qq = c8 & 3;
      uint4 v = *(const uint4*)(sb + (size_t)(st * 32 + r) * 384 + c8 * 8);
      *(uint4*)&SQ[(ks * 32 + r) * 40 + qq * 8] = v;
    }
#pragma unroll
    for (int i = 0; i < 6; ++i) {
      int u = tid + i * 256;
      int d = u >> 2, cq = u & 3;
      uint4 v = *(const uint4*)(vb + (size_t)d * 1024 + st * 32 + cq * 8);
      *(uint4*)&SV[d * 40 + cq * 8] = v;
    }
    float2 cs0 = stats[(size_t)bh * 1024 + st * 32 + t];
    float2 cs1 = stats[(size_t)bh * 1024 + st * 32 + 16 + t];
    __syncthreads();  // staging visible
    f32x4 Sa0 = {0.f,0.f,0.f,0.f}, Sb0 = {0.f,0.f,0.f,0.f};
    f32x4 Sa1 = {0.f,0.f,0.f,0.f}, Sb1 = {0.f,0.f,0.f,0.f};
#pragma unroll
    for (int ks = 0; ks < 12; ks += 2) {
      short8 B00 = *(const short8*)&SQ[(ks * 32 + t) * 40 + qd * 8];
      short8 B01 = *(const short8*)&SQ[((ks + 1) * 32 + t) * 40 + qd * 8];
      short8 B10 = *(const short8*)&SQ[(ks * 32 + 16 + t) * 40 + qd * 8];
      short8 B11 = *(const short8*)&SQ[((ks + 1) * 32 + 16 + t) * 40 + qd * 8];
      Sa0 = MFMA_BF16(Ah[ks], B00, Sa0);
      Sb0 = MFMA_BF16(Ah[ks + 1], B01, Sb0);
      Sa1 = MFMA_BF16(Ah[ks], B10, Sa1);
      Sb1 = MFMA_BF16(Ah[ks + 1], B11, Sb1);
    }
#pragma unroll
    for (int r = 0; r < 4; ++r) {
      float p0 = __expf((Sa0[r] + Sb0[r]) * scale - cs0.x) * cs0.y;
      float p1 = __expf((Sa1[r] + Sb1[r]) * scale - cs1.x) * cs1.y;
      Pw[(qd * 4 + r) * 40 + t] = f2b(p0);
      Pw[(qd * 4 + r) * 40 + 16 + t] = f2b(p1);
    }
    // wave-private P: compiler inserts lgkmcnt wait before the read
    short8 Pa = *(const short8*)&Pw[t * 40 + qd * 8];
#pragma unroll
    for (int nj = 0; nj < 24; ++nj) {
      short8 Vf = *(const short8*)&SV[(nj * 16 + t) * 40 + qd * 8];
      acc[nj] = MFMA_BF16(Pa, Vf, acc[nj]);
    }
  }
  const int b_out = bh / 3, off = (1 + bh % 3) * 384;
#pragma unroll
  for (int nj = 0; nj < 24; ++nj)
#pragma unroll
    for (int r = 0; r < 4; ++r) {
      int row = o0 + w * 16 + qd * 4 + r;
      int d = nj * 16 + t;
      xall[((size_t)b_out * 1024 + row) * 1536 + off + d] = f2b(acc[nj][r]);
    }
}

// ---------------- att1 stats (split hi/lo, f32-precision scores, scale=1).
// Direct-to-register; Sp double-buffered -> ONE barrier/iter. XCD-swizzled.
__global__ __launch_bounds__(256) void att1_stats(
    const u16* __restrict__ qh, const u16* __restrict__ ql,
    const u16* __restrict__ kh, const u16* __restrict__ kl,
    float2* __restrict__ stats) {
  __shared__ float Sp[2][2][16][17];
  __shared__ float2 comb[2][16];
  const int tid = threadIdx.x, w = tid >> 6, lane = tid & 63;
  const int t = lane & 15, qd = lane >> 4;
  int bh, o0;
  xcd8(blockIdx.x, bh, o0);
  const int ss = w & 1;
  const bool scorer = (w < 2);
  short8 Ah[12], R2[12];  // R2: q-lo (scorers, persistent) / str-lo (w23, per-iter)
  {
    const u16* qp = qh + ((size_t)bh * 1024 + o0 + t) * 384 + qd * 8;
#pragma unroll
    for (int ks = 0; ks < 12; ++ks) Ah[ks] = *(const short8*)(qp + ks * 32);
    if (scorer) {
      const u16* qp2 = ql + ((size_t)bh * 1024 + o0 + t) * 384 + qd * 8;
#pragma unroll
      for (int ks = 0; ks < 12; ++ks) R2[ks] = *(const short8*)(qp2 + ks * 32);
    }
  }
  float m[4] = {-1e30f, -1e30f, -1e30f, -1e30f}, l[4] = {0.f, 0.f, 0.f, 0.f};
  for (int st = 0; st < 32; ++st) {
    const int pb = st & 1;
    f32x4 S0 = {0.f, 0.f, 0.f, 0.f}, S1 = {0.f, 0.f, 0.f, 0.f};
    if (scorer) {
      const u16* kp = kh + ((size_t)bh * 1024 + st * 32 + w * 16 + t) * 384 + qd * 8;
#pragma unroll
      for (int ks = 0; ks < 12; ++ks) {
        short8 Bh = *(const short8*)(kp + ks * 32);
        S0 = MFMA_BF16(Ah[ks], Bh, S0);
        S1 = MFMA_BF16(R2[ks], Bh, S1);
      }
    } else {
      const u16* kp = kl + ((size_t)bh * 1024 + st * 32 + ss * 16 + t) * 384 + qd * 8;
#pragma unroll
      for (int ks = 0; ks < 12; ++ks) R2[ks] = *(const short8*)(kp + ks * 32);
#pragma unroll
      for (int ks = 0; ks < 12; ks += 2) {
        S0 = MFMA_BF16(Ah[ks], R2[ks], S0);
        S1 = MFMA_BF16(Ah[ks + 1], R2[ks + 1], S1);
      }
#pragma unroll
      for (int r = 0; r < 4; ++r) Sp[pb][ss][qd * 4 + r][t] = S0[r] + S1[r];
    }
    __syncthreads();  // Sp[pb] ready
    if (scorer) {
#pragma unroll
      for (int r = 0; r < 4; ++r) {
        float s = S0[r] + S1[r] + Sp[pb][w][qd * 4 + r][t];
        float mx = s;
#pragma unroll
        for (int mk = 1; mk < 16; mk <<= 1) mx = fmaxf(mx, __shfl_xor(mx, mk));
        float nm = fmaxf(m[r], mx);
        float e = __expf(s - nm);
#pragma unroll
        for (int mk = 1; mk < 16; mk <<= 1) e += __shfl_xor(e, mk);
        l[r] = l[r] * __expf(m[r] - nm) + e;
        m[r] = nm;
      }
    }
  }
  if (scorer && t == 0) {
#pragma unroll
    for (int r = 0; r < 4; ++r) comb[w][qd * 4 + r] = make_float2(m[r], l[r]);
  }
  __syncthreads();
  if (tid < 16) {
    float2 a = comb[0][tid], b = comb[1][tid];
    float nm = fmaxf(a.x, b.x);
    float ll = a.y * __expf(a.x - nm) + b.y * __expf(b.x - nm);
    stats[(size_t)bh * 1024 + o0 + tid] = make_float2(nm, 1.f / ll);
  }
}

// ---------------- att1 accumulate (split scores, standard attn direction).
// Direct-to-register; Sp and P double-buffered -> two barriers/iter. XCD-swizzled.
__global__ __launch_bounds__(256) void att1_accum(
    const u16* __restrict__ qh, const u16* __restrict__ ql,
    const u16* __restrict__ kh, const u16* __restrict__ kl,
    const u16* __restrict__ vt, const float2* __restrict__ stats,
    u16* __restrict__ xall) {
  __shared__ float Sp[2][2][16][17];
  __shared__ __align__(16) u16 P[2][16 * 40];
  const int tid = threadIdx.x, w = tid >> 6, lane = tid & 63;
  const int t = lane & 15, qd = lane >> 4;
  int bh, o0;
  xcd8(blockIdx.x, bh, o0);
  const int ss = w & 1;
  const bool scorer = (w < 2);
  short8 Ah[12], R2[12];
  float sm[4], sr[4];
  {
    const u16* qp = qh + ((size_t)bh * 1024 + o0 + t) * 384 + qd * 8;
#pragma unroll
    for (int ks = 0; ks < 12; ++ks) Ah[ks] = *(const short8*)(qp + ks * 32);
    if (scorer) {
      const u16* qp2 = ql + ((size_t)bh * 1024 + o0 + t) * 384 + qd * 8;
#pragma unroll
      for (int ks = 0; ks < 12; ++ks) R2[ks] = *(const short8*)(qp2 + ks * 32);
#pragma unroll
      for (int r = 0; r < 4; ++r) {
        float2 s2 = stats[(size_t)bh * 1024 + o0 + qd * 4 + r];
        sm[r] = s2.x; sr[r] = s2.y;
      }
    }
  }
  f32x4 acc[6];
#pragma unroll
  for (int i = 0; i < 6; ++i) acc[i] = (f32x4){0.f, 0.f, 0.f, 0.f};
  const u16* vbase = vt + ((size_t)bh * 384 + w * 96 + t) * 1024;
  for (int st = 0; st < 32; ++st) {
    const int pb = st & 1;
    f32x4 S0 = {0.f, 0.f, 0.f, 0.f}, S1 = {0.f, 0.f, 0.f, 0.f};
    if (scorer) {
      const u16* kp = kh + ((size_t)bh * 1024 + st * 32 + w * 16 + t) * 384 + qd * 8;
#pragma unroll
      for (int ks = 0; ks < 12; ++ks) {
        short8 Bh = *(const short8*)(kp + ks * 32);
        S0 = MFMA_BF16(Ah[ks], Bh, S0);
        S1 = MFMA_BF16(R2[ks], Bh, S1);
      }
    } else {
      const u16* kp = kl + ((size_t)bh * 1024 + st * 32 + ss * 16 + t) * 384 + qd * 8;
#pragma unroll
      for (int ks = 0; ks < 12; ++ks) R2[ks] = *(const short8*)(kp + ks * 32);
#pragma unroll
      for (int ks = 0; ks < 12; ks += 2) {
        S0 = MFMA_BF16(Ah[ks], R2[ks], S0);
        S1 = MFMA_BF16(Ah[ks + 1], R2[ks + 1], S1);
      }
#pragma unroll
      for (int r = 0; r < 4; ++r) Sp[pb][ss][qd * 4 + r][t] = S0[r] + S1[r];
    }
    short8 Vr[6];
#pragma unroll
    for (int nj = 0; nj < 6; ++nj)
      Vr[nj] = *(const short8*)(vbase + (size_t)nj * 16 * 1024 + st * 32 + qd * 8);
    __syncthreads();  // #1: Sp[pb] ready
    if (scorer) {
#pragma unroll
      for (int r = 0; r < 4; ++r) {
        float s = S0[r] + S1[r] + Sp[pb][w][qd * 4 + r][t];
        float p = __expf(s - sm[r]) * sr[r];
        P[pb][(qd * 4 + r) * 40 + w * 16 + t] = f2b(p);
      }
    }
    __syncthreads();  // #2: P[pb] ready
    short8 Pa = *(const short8*)&P[pb][t * 40 + qd * 8];
#pragma unroll
    for (int nj = 0; nj < 6; ++nj) acc[nj] = MFMA_BF16(Pa, Vr[nj], acc[nj]);
  }
#pragma unroll
  for (int nj = 0; nj < 6; ++nj)
#pragma unroll
    for (int r = 0; r < 4; ++r) {
      int row = o0 + qd * 4 + r;
      int d = w * 96 + nj * 16 + t;
      xall[((size_t)bh * 1024 + row) * 1536 + d] = f2b(acc[nj][r]);
    }
}

// ---------------- IWT: xall (B,1024,1536) -> y (B,4096,384)
__global__ __launch_bounds__(256) void iwt_y(const u16* __restrict__ xall, u16* __restrict__ y) {
  const int blk = blockIdx.x;
  const int b = blk >> 10, pos = blk & 1023;
  const int i = pos >> 5, j = pos & 31;
  const u16* xr = xall + (size_t)(b * 1024 + pos) * 1536;
  u16* yb = y + (size_t)b * 4096 * 384;
  const int p00 = (i * 2) * 64 + j * 2;
  for (int c = threadIdx.x; c < 384; c += 256) {
    float g1 = 0.5f * b2f(xr[c]);
    float g2 = 0.5f * b2f(xr[c + 384]);
    float g3 = 0.5f * b2f(xr[c + 768]);
    float g4 = 0.5f * b2f(xr[c + 1152]);
    yb[(size_t)p00 * 384 + c]        = f2b(g1 - g2 - g3 + g4);
    yb[(size_t)(p00 + 64) * 384 + c] = f2b(g1 - g2 + g3 - g4);
    yb[(size_t)(p00 + 1) * 384 + c]  = f2b(g1 + g2 - g3 - g4);
    yb[(size_t)(p00 + 65) * 384 + c] = f2b(g1 + g2 + g3 + g4);
  }
}

extern "C" void kernel_launch(void* const* d_in, const int* in_sizes, int n_in,
                              void* d_out, int out_size, void* d_ws, size_t ws_size,
                              hipStream_t stream) {
  (void)in_sizes; (void)n_in; (void)out_size; (void)ws_size;
  const float* sf      = (const float*)d_in[0];
  const float* wf      = (const float*)d_in[1];
  const float* q_w     = (const float*)d_in[2];
  const float* q_b     = (const float*)d_in[3];
  const float* q_ln_w  = (const float*)d_in[4];
  const float* q_ln_b  = (const float*)d_in[5];
  const float* kv_w    = (const float*)d_in[6];
  const float* kv_b    = (const float*)d_in[7];
  const float* kv_ln_w = (const float*)d_in[8];
  const float* kv_ln_b = (const float*)d_in[9];
  const float* out_w   = (const float*)d_in[10];
  const float* out_b   = (const float*)d_in[11];
  float* out = (float*)d_out;

  // ---- workspace layout, ~168 MiB peak with phase aliasing ----
  char* p = (char*)d_ws;
  float* A  = (float*)p; p += 50331648;   // t_sf f32; later k1h|k1l|v1|k2|v1t
  float* B1 = (float*)p; p += 50331648;   // t_wf lo f32; later xall
  u16*   B2 = (u16*)p;   p += 25165824;   // t_wf hi bf16; later v2t; later y
  u16* q1h = (u16*)p; p += 6291456;       // (8,1024,384) bf16 hi
  u16* q1l = (u16*)p; p += 6291456;       // lo
  u16* q2  = (u16*)p; p += 18874368;      // (24,1024,384) bf16
  u16* v2  = (u16*)p; p += 18874368;      // (24,1024,384) bf16 row-major
  float2* stats1 = (float2*)p; p += 65536;    // 8192 float2
  float2* stats2 = (float2*)p;                // 24576 float2
  // aliases inside A (t_sf dead after dwt_sf):
  u16* k1h = (u16*)A;
  u16* k1l = k1h + 3145728;
  u16* v1  = k1l + 3145728;
  u16* k2  = v1 + 3145728;
  u16* v1t = k2 + 9437184;            // (8,384,1024)
  u16* xall = (u16*)B1;               // (8,1024,1536)
  u16* v2t = B2;                      // (24,384,1024)
  u16* y   = B2;                      // (8,4096,384)

  // projections (MFMA) + LN; att1 score chain stays f32-precision via split
  gemm_mfma<1, float, float><<<dim3(3, 256), 256, 0, stream>>>(sf, q_w, q_b, A);
  ln_inplace<float><<<32768, 256, 0, stream>>>(A, q_ln_w, q_ln_b, 384);
  gemm_mfma<1, float, float><<<dim3(3, 256), 256, 0, stream>>>(wf, kv_w, kv_b, B1);
  gemm_mfma<0, float, u16><<<dim3(3, 256), 256, 0, stream>>>(wf, kv_w + 384 * 384, kv_b + 384, B2);
  ln_wf_split<<<32768, 256, 0, stream>>>(B1, B2, kv_ln_w, kv_ln_b);

  // DWT (dwt_sf must read A before k1/v1/k2/v1t overwrite it)
  dwt_sf<<<8192, 256, 0, stream>>>(A, q1h, q1l, q2);
  dwt_wf_split<<<8192, 256, 0, stream>>>(B1, B2, k1h, k1l, v1, k2, v2);

  // V transposes for MFMA B-operand layout
  transpose_rm<<<dim3(6, 16, 8), 256, 0, stream>>>(v1, v1t);
  transpose_rm<<<dim3(6, 16, 24), 256, 0, stream>>>(v2, v2t);  // overwrites dead t_wf-hi

  // attention (1D grids, XCD-swizzled inside the kernels)
  att1_stats<<<512, 256, 0, stream>>>(q1h, q1l, k1h, k1l, stats1);
  att2_stats<<<384, 256, 0, stream>>>(q2, k2, stats2, SCALE2);
  att1_accum<<<512, 256, 0, stream>>>(q1h, q1l, k1h, k1l, v1t, stats1, xall);
  att2_accum<<<384, 256, 0, stream>>>(k2, q2, v2t, stats2, xall, SCALE2);

  // IWT + output projection (MFMA)
  iwt_y<<<8192, 256, 0, stream>>>(xall, y);
  gemm_mfma<0, u16, float><<<dim3(3, 256), 256, 0, stream>>>(y, out_w, out_b, out);
}

// Round 4
// 811.404 us; speedup vs baseline: 1.3715x; 1.0603x over previous
//
#include <hip/hip_runtime.h>
#include <hip/hip_bf16.h>

typedef unsigned short u16;
typedef unsigned int u32;
typedef __attribute__((ext_vector_type(8))) short short8;   // 8 bf16 (4 VGPRs)
typedef __attribute__((ext_vector_type(4))) float f32x4;    // MFMA C/D

#define MFMA_BF16(A, B, C) __builtin_amdgcn_mfma_f32_16x16x32_bf16(A, B, C, 0, 0, 0)

#define SCALE2 0.08838834764831845f
#define LNEPS 1e-5f

__device__ __forceinline__ float b2f(u16 u) {
  return __uint_as_float(((u32)u) << 16);
}
__device__ __forceinline__ u16 f2b(float f) {
  u32 x = __float_as_uint(f);
  return (u16)((x + 0x7fffu + ((x >> 16) & 1u)) >> 16);  // RNE
}
__device__ __forceinline__ float ldf(const float* p) { return *p; }
__device__ __forceinline__ float ldf(const u16* p) { return b2f(*p); }
__device__ __forceinline__ void stf(float* p, float v) { *p = v; }
__device__ __forceinline__ void stf(u16* p, float v) { *p = f2b(v); }

// ---------------- MFMA GEMM: out[m][n] = sum_k X[m][k]*W[n][k] + bias[n]
// K=384, N=384. Block 128Mx128N, 4 waves (2x2 of 64x64). SPLIT: hi/lo bf16
// 3-product f32-precision (X must be float).
template <int SPLIT, typename TX, typename TO>
__global__ __launch_bounds__(256) void gemm_mfma(
    const TX* __restrict__ X, const float* __restrict__ W,
    const float* __restrict__ bias, TO* __restrict__ out) {
  __shared__ __align__(16) u16 AH[128 * 40];
  __shared__ __align__(16) u16 BH[128 * 40];
  __shared__ __align__(16) u16 AL[SPLIT ? 128 * 40 : 8];
  __shared__ __align__(16) u16 BL[SPLIT ? 128 * 40 : 8];
  const int tid = threadIdx.x;
  const int w = tid >> 6, lane = tid & 63;
  const int t = lane & 15, qd = lane >> 4;
  const int wm = w & 1, wn = w >> 1;
  const int m0 = blockIdx.y * 128, n0 = blockIdx.x * 128;
  f32x4 acc[4][4];
#pragma unroll
  for (int i = 0; i < 4; ++i)
#pragma unroll
    for (int j = 0; j < 4; ++j) acc[i][j] = (f32x4){0.f, 0.f, 0.f, 0.f};
  for (int kt = 0; kt < 384; kt += 32) {
    // stage A (128x32) and B (128x32) with f32->bf16 convert
#pragma unroll
    for (int rep = 0; rep < 4; ++rep) {
      int e = tid + rep * 256;
      int m = e >> 3, k4 = (e & 7) * 4;
      if constexpr (sizeof(TX) == 4) {
        float4 v = *(const float4*)(X + (size_t)(m0 + m) * 384 + kt + k4);
        u16 h0 = f2b(v.x), h1 = f2b(v.y), h2 = f2b(v.z), h3 = f2b(v.w);
        u32 hp0 = (u32)h0 | ((u32)h1 << 16), hp1 = (u32)h2 | ((u32)h3 << 16);
        *(uint2*)&AH[m * 40 + k4] = make_uint2(hp0, hp1);
        if (SPLIT) {
          u16 l0 = f2b(v.x - b2f(h0)), l1 = f2b(v.y - b2f(h1));
          u16 l2 = f2b(v.z - b2f(h2)), l3 = f2b(v.w - b2f(h3));
          *(uint2*)&AL[m * 40 + k4] =
              make_uint2((u32)l0 | ((u32)l1 << 16), (u32)l2 | ((u32)l3 << 16));
        }
      } else {
        uint2 raw = *(const uint2*)(X + (size_t)(m0 + m) * 384 + kt + k4);
        *(uint2*)&AH[m * 40 + k4] = raw;
      }
      float4 wv = *(const float4*)(W + (size_t)(n0 + m) * 384 + kt + k4);
      u16 wh0 = f2b(wv.x), wh1 = f2b(wv.y), wh2 = f2b(wv.z), wh3 = f2b(wv.w);
      *(uint2*)&BH[m * 40 + k4] =
          make_uint2((u32)wh0 | ((u32)wh1 << 16), (u32)wh2 | ((u32)wh3 << 16));
      if (SPLIT) {
        u16 wl0 = f2b(wv.x - b2f(wh0)), wl1 = f2b(wv.y - b2f(wh1));
        u16 wl2 = f2b(wv.z - b2f(wh2)), wl3 = f2b(wv.w - b2f(wh3));
        *(uint2*)&BL[m * 40 + k4] =
            make_uint2((u32)wl0 | ((u32)wl1 << 16), (u32)wl2 | ((u32)wl3 << 16));
      }
    }
    __syncthreads();
    short8 af[4], bf[4], al[4], bl[4];
#pragma unroll
    for (int mi = 0; mi < 4; ++mi) {
      af[mi] = *(const short8*)&AH[(wm * 64 + mi * 16 + t) * 40 + qd * 8];
      bf[mi] = *(const short8*)&BH[(wn * 64 + mi * 16 + t) * 40 + qd * 8];
      if (SPLIT) {
        al[mi] = *(const short8*)&AL[(wm * 64 + mi * 16 + t) * 40 + qd * 8];
        bl[mi] = *(const short8*)&BL[(wn * 64 + mi * 16 + t) * 40 + qd * 8];
      }
    }
#pragma unroll
    for (int mi = 0; mi < 4; ++mi)
#pragma unroll
      for (int ni = 0; ni < 4; ++ni) {
        acc[mi][ni] = MFMA_BF16(af[mi], bf[ni], acc[mi][ni]);
        if (SPLIT) {
          acc[mi][ni] = MFMA_BF16(al[mi], bf[ni], acc[mi][ni]);
          acc[mi][ni] = MFMA_BF16(af[mi], bl[ni], acc[mi][ni]);
        }
      }
    __syncthreads();
  }
#pragma unroll
  for (int ni = 0; ni < 4; ++ni) {
    int n = n0 + wn * 64 + ni * 16 + t;
    float bv = bias[n];
#pragma unroll
    for (int mi = 0; mi < 4; ++mi)
#pragma unroll
      for (int r = 0; r < 4; ++r) {
        int m = m0 + wm * 64 + mi * 16 + qd * 4 + r;
        stf(&out[(size_t)m * 384 + n], acc[mi][ni][r] + bv);
      }
  }
}

// ---------------- row LayerNorm, in place (templated storage)
template <typename T>
__global__ __launch_bounds__(256) void ln_inplace(
    T* __restrict__ Tb, const float* __restrict__ w, const float* __restrict__ b, int N) {
  const int row = blockIdx.x, tid = threadIdx.x;
  T* Tr = Tb + (size_t)row * N;
  float vals[3];
  float s = 0.f, ss = 0.f;
  int nv = 0;
  for (int i = tid; i < N; i += 256) {
    float v = ldf(&Tr[i]);
    vals[nv++] = v;
    s += v; ss += v * v;
  }
#pragma unroll
  for (int mk = 32; mk; mk >>= 1) { s += __shfl_xor(s, mk); ss += __shfl_xor(ss, mk); }
  __shared__ float red[8];
  if ((tid & 63) == 0) { red[tid >> 6] = s; red[4 + (tid >> 6)] = ss; }
  __syncthreads();
  s = red[0] + red[1] + red[2] + red[3];
  ss = red[4] + red[5] + red[6] + red[7];
  float inv = 1.f / (float)N;
  float mean = s * inv;
  float var = fmaxf(ss * inv - mean * mean, 0.f);
  float rstd = rsqrtf(var + LNEPS);
  nv = 0;
  for (int i = tid; i < N; i += 256) {
    float v = (vals[nv++] - mean) * rstd * w[i] + b[i];
    stf(&Tr[i], v);
  }
}

// ---------------- LN over split storage: lo = f32 chans 0..383, hi = bf16 chans 384..767
__global__ __launch_bounds__(256) void ln_wf_split(
    float* __restrict__ lo, u16* __restrict__ hi,
    const float* __restrict__ w, const float* __restrict__ b) {
  const int row = blockIdx.x, tid = threadIdx.x;
  float* L = lo + (size_t)row * 384;
  u16* H = hi + (size_t)row * 384;
  float vals[3];
  float s = 0.f, ss = 0.f;
  int nv = 0;
  for (int i = tid; i < 768; i += 256) {
    float v = (i < 384) ? L[i] : b2f(H[i - 384]);
    vals[nv++] = v;
    s += v; ss += v * v;
  }
#pragma unroll
  for (int mk = 32; mk; mk >>= 1) { s += __shfl_xor(s, mk); ss += __shfl_xor(ss, mk); }
  __shared__ float red[8];
  if ((tid & 63) == 0) { red[tid >> 6] = s; red[4 + (tid >> 6)] = ss; }
  __syncthreads();
  s = red[0] + red[1] + red[2] + red[3];
  ss = red[4] + red[5] + red[6] + red[7];
  float mean = s * (1.f / 768.f);
  float var = fmaxf(ss * (1.f / 768.f) - mean * mean, 0.f);
  float rstd = rsqrtf(var + LNEPS);
  nv = 0;
  for (int i = 0 + tid; i < 768; i += 256) {
    float v = (vals[nv++] - mean) * rstd * w[i] + b[i];
    if (i < 384) L[i] = v; else H[i - 384] = f2b(v);
  }
}

// ---------------- DWT sf: t_sf f32 -> q1 split-bf16 (hi+lo), q2 bf16 (3 heads)
__global__ __launch_bounds__(256) void dwt_sf(
    const float* __restrict__ T, u16* __restrict__ q1h, u16* __restrict__ q1l,
    u16* __restrict__ q2) {
  const int blk = blockIdx.x;
  const int b = blk >> 10, pos = blk & 1023;
  const int i = pos >> 5, j = pos & 31;
  const int p00 = (i * 2) * 64 + j * 2;
  const float* base = T + (size_t)b * 4096 * 384;
  for (int ch = threadIdx.x; ch < 384; ch += 256) {
    float a  = base[(size_t)p00 * 384 + ch];
    float cc = base[(size_t)(p00 + 1) * 384 + ch];
    float bb = base[(size_t)(p00 + 64) * 384 + ch];
    float dd = base[(size_t)(p00 + 65) * 384 + ch];
    float s0 = 0.5f * ( a + bb + cc + dd);
    float s1 = 0.5f * (-a - bb + cc + dd);
    float s2 = 0.5f * (-a + bb - cc + dd);
    float s3 = 0.5f * ( a - bb - cc + dd);
    size_t po = (size_t)(b * 1024 + pos) * 384 + ch;
    u16 h = f2b(s0);
    q1h[po] = h;
    q1l[po] = f2b(s0 - b2f(h));
    q2[(size_t)((b * 3 + 0) * 1024 + pos) * 384 + ch] = f2b(s1);
    q2[(size_t)((b * 3 + 1) * 1024 + pos) * 384 + ch] = f2b(s2);
    q2[(size_t)((b * 3 + 2) * 1024 + pos) * 384 + ch] = f2b(s3);
  }
}

// ---------------- DWT wf (split input): lo f32, hi bf16 -> k1 split-bf16, v1, k2, v2
__global__ __launch_bounds__(256) void dwt_wf_split(
    const float* __restrict__ lo, const u16* __restrict__ hi,
    u16* __restrict__ k1h, u16* __restrict__ k1l, u16* __restrict__ v1,
    u16* __restrict__ k2, u16* __restrict__ v2) {
  const int blk = blockIdx.x;
  const int b = blk >> 10, pos = blk & 1023;
  const int i = pos >> 5, j = pos & 31;
  const int p00 = (i * 2) * 64 + j * 2;
  for (int ch = threadIdx.x; ch < 768; ch += 256) {
    float a, bb, cc, dd;
    if (ch < 384) {
      const float* base = lo + (size_t)b * 4096 * 384;
      a  = base[(size_t)p00 * 384 + ch];
      cc = base[(size_t)(p00 + 1) * 384 + ch];
      bb = base[(size_t)(p00 + 64) * 384 + ch];
      dd = base[(size_t)(p00 + 65) * 384 + ch];
    } else {
      const u16* base = hi + (size_t)b * 4096 * 384;
      int c = ch - 384;
      a  = b2f(base[(size_t)p00 * 384 + c]);
      cc = b2f(base[(size_t)(p00 + 1) * 384 + c]);
      bb = b2f(base[(size_t)(p00 + 64) * 384 + c]);
      dd = b2f(base[(size_t)(p00 + 65) * 384 + c]);
    }
    float s0 = 0.5f * ( a + bb + cc + dd);
    float s1 = 0.5f * (-a - bb + cc + dd);
    float s2 = 0.5f * (-a + bb - cc + dd);
    float s3 = 0.5f * ( a - bb - cc + dd);
    if (ch < 384) {
      size_t po = (size_t)(b * 1024 + pos) * 384 + ch;
      u16 h = f2b(s0);
      k1h[po] = h;
      k1l[po] = f2b(s0 - b2f(h));
      v1[po] = f2b(s2);
      k2[(size_t)((b * 3 + 1) * 1024 + pos) * 384 + ch] = f2b(s1);
      v2[(size_t)((b * 3 + 1) * 1024 + pos) * 384 + ch] = f2b(s3);
    } else {
      int c = ch - 384;
      k2[(size_t)((b * 3 + 0) * 1024 + pos) * 384 + c] = f2b(s0);
      k2[(size_t)((b * 3 + 2) * 1024 + pos) * 384 + c] = f2b(s1);
      v2[(size_t)((b * 3 + 0) * 1024 + pos) * 384 + c] = f2b(s2);
      v2[(size_t)((b * 3 + 2) * 1024 + pos) * 384 + c] = f2b(s3);
    }
  }
}

// ---------------- transpose [bh][1024][384] -> [bh][384][1024]
__global__ __launch_bounds__(256) void transpose_rm(
    const u16* __restrict__ in, u16* __restrict__ out) {
  __shared__ u16 T[64][65];
  const int tid = threadIdx.x;
  const int bh = blockIdx.z, r0 = blockIdx.y * 64, c0 = blockIdx.x * 64;
  const u16* ip = in + ((size_t)bh * 1024 + r0) * 384 + c0;
  for (int i = tid; i < 2048; i += 256) {
    int r = i >> 5, c2 = i & 31;
    u32 v = *(const u32*)(ip + (size_t)r * 384 + c2 * 2);
    T[c2 * 2][r] = (u16)v;
    T[c2 * 2 + 1][r] = (u16)(v >> 16);
  }
  __syncthreads();
  u16* op = out + ((size_t)bh * 384 + c0) * 1024 + r0;
  for (int i = tid; i < 2048; i += 256) {
    int c = i >> 5, r2 = i & 31;
    u32 v = (u32)T[c][r2 * 2] | ((u32)T[c][r2 * 2 + 1] << 16);
    *(u32*)(op + (size_t)c * 1024 + r2 * 2) = v;
  }
}

// att2 (24 heads x 16 blocks of 64 own rows): XCD x gets heads {x, x+8, x+16}.
__device__ __forceinline__ void xcd24v2(int L, int& bh, int& o0) {
  int s = L >> 3;
  bh = (s >> 4) * 8 + (L & 7);
  o0 = (s & 15) * 64;
}

// ---------------- att2 stats v2: block owns 64 q-rows (wave w -> 16 rows).
// Stream k2 in 32-row tiles staged to LDS ONCE per block (4x cross-wave reuse
// vs direct loads); double-buffered, 1 barrier/iter. Stats complete per wave.
__global__ __launch_bounds__(256) void att2_stats(
    const u16* __restrict__ q, const u16* __restrict__ k,
    float2* __restrict__ stats, float scale) {
  __shared__ __align__(16) u16 S[2][12 * 32 * 40];  // 61440 B, stride-40 pad
  const int tid = threadIdx.x, w = tid >> 6, lane = tid & 63;
  const int t = lane & 15, qd = lane >> 4;
  int bh, o0;
  xcd24v2(blockIdx.x, bh, o0);
  short8 Ah[12];
  {
    const u16* qp = q + ((size_t)bh * 1024 + o0 + w * 16 + t) * 384 + qd * 8;
#pragma unroll
    for (int ks = 0; ks < 12; ++ks) Ah[ks] = *(const short8*)(qp + ks * 32);
  }
  float m[4] = {-1e30f, -1e30f, -1e30f, -1e30f}, l[4] = {0.f, 0.f, 0.f, 0.f};
  const u16* kb = k + (size_t)bh * 1024 * 384;
  int buf = 0;
  for (int st = 0; st < 32; ++st) {
    // stage stream rows st*32..+32: unit = 8 u16; [row][c8] -> S[ks][row][qq*8]
#pragma unroll
    for (int i = 0; i < 6; ++i) {
      int u = tid + i * 256;
      int r = u / 48, c8 = u % 48;
      int ks = c8 >> 2, qq = c8 & 3;
      uint4 v = *(const uint4*)(kb + (size_t)(st * 32 + r) * 384 + c8 * 8);
      *(uint4*)&S[buf][(ks * 32 + r) * 40 + qq * 8] = v;
    }
    __syncthreads();
    f32x4 Sa0 = {0.f,0.f,0.f,0.f}, Sb0 = {0.f,0.f,0.f,0.f};
    f32x4 Sa1 = {0.f,0.f,0.f,0.f}, Sb1 = {0.f,0.f,0.f,0.f};
#pragma unroll
    for (int ks = 0; ks < 12; ks += 2) {
      short8 B00 = *(const short8*)&S[buf][(ks * 32 + t) * 40 + qd * 8];
      short8 B01 = *(const short8*)&S[buf][((ks + 1) * 32 + t) * 40 + qd * 8];
      short8 B10 = *(const short8*)&S[buf][(ks * 32 + 16 + t) * 40 + qd * 8];
      short8 B11 = *(const short8*)&S[buf][((ks + 1) * 32 + 16 + t) * 40 + qd * 8];
      Sa0 = MFMA_BF16(Ah[ks], B00, Sa0);
      Sb0 = MFMA_BF16(Ah[ks + 1], B01, Sb0);
      Sa1 = MFMA_BF16(Ah[ks], B10, Sa1);
      Sb1 = MFMA_BF16(Ah[ks + 1], B11, Sb1);
    }
#pragma unroll
    for (int r = 0; r < 4; ++r) {
      float s0 = (Sa0[r] + Sb0[r]) * scale;
      float s1 = (Sa1[r] + Sb1[r]) * scale;
      float mx = fmaxf(s0, s1);
#pragma unroll
      for (int mk = 1; mk < 16; mk <<= 1) mx = fmaxf(mx, __shfl_xor(mx, mk));
      float nm = fmaxf(m[r], mx);
      float e = __expf(s0 - nm) + __expf(s1 - nm);
#pragma unroll
      for (int mk = 1; mk < 16; mk <<= 1) e += __shfl_xor(e, mk);
      l[r] = l[r] * __expf(m[r] - nm) + e;
      m[r] = nm;
    }
    buf ^= 1;
  }
  if (t == 0) {
#pragma unroll
    for (int r = 0; r < 4; ++r)
      stats[(size_t)bh * 1024 + o0 + w * 16 + qd * 4 + r] =
          make_float2(m[r], 1.f / l[r]);
  }
}

// ---------------- att2 accumulate v2 (transposed gather): block owns 64 k2
// rows (wave w -> 16 output rows x ALL 384 dims, acc[24]). Stream q2 tile (32
// rows) + V tile (384x32) staged to LDS once per block; single-buffer, two
// barriers/iter. P is wave-private LDS (no cross-wave barrier).
__global__ __launch_bounds__(256, 2) void att2_accum(
    const u16* __restrict__ own, const u16* __restrict__ str,
    const u16* __restrict__ vt, const float2* __restrict__ stats,
    u16* __restrict__ xall, float scale) {
  __shared__ __align__(16) u16 SQ[12 * 32 * 40];   // 30720 B
  __shared__ __align__(16) u16 SV[24 * 16 * 40];   // 30720 B
  __shared__ __align__(16) u16 P[4][16 * 40];      // 5120 B, wave-private
  const int tid = threadIdx.x, w = tid >> 6, lane = tid & 63;
  const int t = lane & 15, qd = lane >> 4;
  int bh, o0;
  xcd24v2(blockIdx.x, bh, o0);
  short8 Ah[12];
  {
    const u16* op = own + ((size_t)bh * 1024 + o0 + w * 16 + t) * 384 + qd * 8;
#pragma unroll
    for (int ks = 0; ks < 12; ++ks) Ah[ks] = *(const short8*)(op + ks * 32);
  }
  f32x4 acc[24];
#pragma unroll
  for (int i = 0; i < 24; ++i) acc[i] = (f32x4){0.f, 0.f, 0.f, 0.f};
  const u16* sb = str + (size_t)bh * 1024 * 384;
  const u16* vb = vt + (size_t)bh * 384 * 1024;
  u16* Pw = &P[w][0];
  for (int st = 0; st < 32; ++st) {
    __syncthreads();  // all waves done reading SQ/SV from previous iter
#pragma unroll
    for (int i = 0; i < 6; ++i) {
      int u = tid + i * 256;
      int r = u / 48, c8 = u % 48;
      int ks = c8 >> 2, qq = c8 & 3;
      uint4 v = *(const uint4*)(sb + (size_t)(st * 32 + r) * 384 + c8 * 8);
      *(uint4*)&SQ[(ks * 32 + r) * 40 + qq * 8] = v;
    }
#pragma unroll
    for (int i = 0; i < 6; ++i) {
      int u = tid + i * 256;
      int d = u >> 2, cq = u & 3;
      uint4 v = *(const uint4*)(vb + (size_t)d * 1024 + st * 32 + cq * 8);
      *(uint4*)&SV[d * 40 + cq * 8] = v;
    }
    float2 cs0 = stats[(size_t)bh * 1024 + st * 32 + t];
    float2 cs1 = stats[(size_t)bh * 1024 + st * 32 + 16 + t];
    __syncthreads();  // staging visible
    f32x4 Sa0 = {0.f,0.f,0.f,0.f}, Sb0 = {0.f,0.f,0.f,0.f};
    f32x4 Sa1 = {0.f,0.f,0.f,0.f}, Sb1 = {0.f,0.f,0.f,0.f};
#pragma unroll
    for (int ks = 0; ks < 12; ks += 2) {
      short8 B00 = *(const short8*)&SQ[(ks * 32 + t) * 40 + qd * 8];
      short8 B01 = *(const short8*)&SQ[((ks + 1) * 32 + t) * 40 + qd * 8];
      short8 B10 = *(const short8*)&SQ[(ks * 32 + 16 + t) * 40 + qd * 8];
      short8 B11 = *(const short8*)&SQ[((ks + 1) * 32 + 16 + t) * 40 + qd * 8];
      Sa0 = MFMA_BF16(Ah[ks], B00, Sa0);
      Sb0 = MFMA_BF16(Ah[ks + 1], B01, Sb0);
      Sa1 = MFMA_BF16(Ah[ks], B10, Sa1);
      Sb1 = MFMA_BF16(Ah[ks + 1], B11, Sb1);
    }
#pragma unroll
    for (int r = 0; r < 4; ++r) {
      float p0 = __expf((Sa0[r] + Sb0[r]) * scale - cs0.x) * cs0.y;
      float p1 = __expf((Sa1[r] + Sb1[r]) * scale - cs1.x) * cs1.y;
      Pw[(qd * 4 + r) * 40 + t] = f2b(p0);
      Pw[(qd * 4 + r) * 40 + 16 + t] = f2b(p1);
    }
    // wave-private P: compiler inserts lgkmcnt wait before the read
    short8 Pa = *(const short8*)&Pw[t * 40 + qd * 8];
#pragma unroll
    for (int nj = 0; nj < 24; ++nj) {
      short8 Vf = *(const short8*)&SV[(nj * 16 + t) * 40 + qd * 8];
      acc[nj] = MFMA_BF16(Pa, Vf, acc[nj]);
    }
  }
  const int b_out = bh / 3, off = (1 + bh % 3) * 384;
#pragma unroll
  for (int nj = 0; nj < 24; ++nj)
#pragma unroll
    for (int r = 0; r < 4; ++r) {
      int row = o0 + w * 16 + qd * 4 + r;
      int d = nj * 16 + t;
      xall[((size_t)b_out * 1024 + row) * 1536 + off + d] = f2b(acc[nj][r]);
    }
}

// ---------------- att1 fused flash (replaces att1_stats + att1_accum).
// Split hi/lo q,k; f32-precision scores (hh+lh+hl chains); scale=1.
// Grid 256 = 8 batches (XCD L&7) x 32 blocks x 32 own q-rows.
// Wave (wr,sh): scores for rows wr*16, stream half sh (no duplication);
// softmax merged across sh via comb LDS; PV over dims sh*192 (V in regs).
// Software-pipelined: stage(st+1) overlaps merge(st); 2 barriers/iter.
__global__ __launch_bounds__(256, 2) void att1_fused(
    const u16* __restrict__ qh, const u16* __restrict__ ql,
    const u16* __restrict__ kh, const u16* __restrict__ kl,
    const u16* __restrict__ vt, u16* __restrict__ xall) {
  __shared__ __align__(16) u16 KH[12 * 32 * 40];   // 30720 B
  __shared__ __align__(16) u16 KL[12 * 32 * 40];   // 30720 B
  __shared__ __align__(16) u16 P[2][16 * 40];      // 2560 B (per row-group)
  __shared__ float2 comb[2][2][16];                // 512 B  (wr, sh, row)
  const int tid = threadIdx.x, w = tid >> 6, lane = tid & 63;
  const int t = lane & 15, qd = lane >> 4;
  const int wr = w & 1, sh = w >> 1;
  const int bh = blockIdx.x & 7, o0 = (blockIdx.x >> 3) * 32;
  short8 Ah[12], Al[12];
  {
    const u16* qp  = qh + ((size_t)bh * 1024 + o0 + wr * 16 + t) * 384 + qd * 8;
    const u16* qp2 = ql + ((size_t)bh * 1024 + o0 + wr * 16 + t) * 384 + qd * 8;
#pragma unroll
    for (int ks = 0; ks < 12; ++ks) {
      Ah[ks] = *(const short8*)(qp + ks * 32);
      Al[ks] = *(const short8*)(qp2 + ks * 32);
    }
  }
  f32x4 acc[12];
#pragma unroll
  for (int i = 0; i < 12; ++i) acc[i] = (f32x4){0.f, 0.f, 0.f, 0.f};
  float m[4] = {-1e30f, -1e30f, -1e30f, -1e30f}, l[4] = {0.f, 0.f, 0.f, 0.f};
  const u16* khb = kh + (size_t)bh * 1024 * 384;
  const u16* klb = kl + (size_t)bh * 1024 * 384;
  const u16* vbase = vt + ((size_t)bh * 384 + sh * 192 + t) * 1024;
  // prologue: stage stream tile 0 (32 rows of kh and kl)
#pragma unroll
  for (int i = 0; i < 6; ++i) {
    int u = tid + i * 256;
    int r = u / 48, c8 = u % 48;
    int ks = c8 >> 2, j8 = c8 & 3;
    *(uint4*)&KH[(ks * 32 + r) * 40 + j8 * 8] =
        *(const uint4*)(khb + (size_t)r * 384 + c8 * 8);
    *(uint4*)&KL[(ks * 32 + r) * 40 + j8 * 8] =
        *(const uint4*)(klb + (size_t)r * 384 + c8 * 8);
  }
  __syncthreads();
  for (int st = 0; st < 32; ++st) {
    // V fragments for this tile (global; issued early to overlap scores)
    short8 Vr[12];
#pragma unroll
    for (int nj = 0; nj < 12; ++nj)
      Vr[nj] = *(const short8*)(vbase + (size_t)nj * 16 * 1024 + st * 32 + qd * 8);
    // scores: own rows (group wr) x stream half sh; 3 independent f32 chains
    f32x4 Shh = {0.f,0.f,0.f,0.f}, Slh = {0.f,0.f,0.f,0.f}, Shl = {0.f,0.f,0.f,0.f};
#pragma unroll
    for (int ks = 0; ks < 12; ++ks) {
      short8 Bh = *(const short8*)&KH[(ks * 32 + sh * 16 + t) * 40 + qd * 8];
      short8 Bl = *(const short8*)&KL[(ks * 32 + sh * 16 + t) * 40 + qd * 8];
      Shh = MFMA_BF16(Ah[ks], Bh, Shh);
      Slh = MFMA_BF16(Al[ks], Bh, Slh);
      Shl = MFMA_BF16(Ah[ks], Bl, Shl);
    }
    float s[4], mx[4], e[4];
#pragma unroll
    for (int r = 0; r < 4; ++r) {
      s[r] = Shh[r] + Slh[r] + Shl[r];
      float v = s[r];
#pragma unroll
      for (int mk = 1; mk < 16; mk <<= 1) v = fmaxf(v, __shfl_xor(v, mk));
      mx[r] = v;
      float ee = __expf(s[r] - v);
#pragma unroll
      for (int mk = 1; mk < 16; mk <<= 1) ee += __shfl_xor(ee, mk);
      e[r] = ee;
    }
    if (t == 0) {
#pragma unroll
      for (int r = 0; r < 4; ++r)
        comb[wr][sh][qd * 4 + r] = make_float2(mx[r], e[r]);
    }
    __syncthreads();  // B2: comb visible; all KH/KL frag reads retired
    // stage NEXT tile (overlaps the merge VALU below; visible after B3)
    if (st < 31) {
#pragma unroll
      for (int i = 0; i < 6; ++i) {
        int u = tid + i * 256;
        int r = u / 48, c8 = u % 48;
        int ks = c8 >> 2, j8 = c8 & 3;
        *(uint4*)&KH[(ks * 32 + r) * 40 + j8 * 8] =
            *(const uint4*)(khb + (size_t)((st + 1) * 32 + r) * 384 + c8 * 8);
        *(uint4*)&KL[(ks * 32 + r) * 40 + j8 * 8] =
            *(const uint4*)(klb + (size_t)((st + 1) * 32 + r) * 384 + c8 * 8);
      }
    }
    // merge softmax state across the sh pair; rescale acc; emit P half
#pragma unroll
    for (int r = 0; r < 4; ++r) {
      float2 c0 = comb[wr][0][qd * 4 + r];
      float2 c1 = comb[wr][1][qd * 4 + r];
      float nm = fmaxf(m[r], fmaxf(c0.x, c1.x));
      float sc = __expf(m[r] - nm);
      l[r] = l[r] * sc + c0.y * __expf(c0.x - nm) + c1.y * __expf(c1.x - nm);
      m[r] = nm;
#pragma unroll
      for (int nj = 0; nj < 12; ++nj) acc[nj][r] *= sc;
      P[wr][(qd * 4 + r) * 40 + sh * 16 + t] = f2b(__expf(s[r] - nm));
    }
    __syncthreads();  // B3: P + next-tile staging visible
    short8 Pa = *(const short8*)&P[wr][t * 40 + qd * 8];
#pragma unroll
    for (int nj = 0; nj < 12; ++nj) acc[nj] = MFMA_BF16(Pa, Vr[nj], acc[nj]);
  }
#pragma unroll
  for (int r = 0; r < 4; ++r) {
    float inv = 1.f / l[r];
    int row = o0 + wr * 16 + qd * 4 + r;
#pragma unroll
    for (int nj = 0; nj < 12; ++nj) {
      int d = sh * 192 + nj * 16 + t;
      xall[((size_t)bh * 1024 + row) * 1536 + d] = f2b(acc[nj][r] * inv);
    }
  }
}

// ---------------- IWT: xall (B,1024,1536) -> y (B,4096,384)
__global__ __launch_bounds__(256) void iwt_y(const u16* __restrict__ xall, u16* __restrict__ y) {
  const int blk = blockIdx.x;
  const int b = blk >> 10, pos = blk & 1023;
  const int i = pos >> 5, j = pos & 31;
  const u16* xr = xall + (size_t)(b * 1024 + pos) * 1536;
  u16* yb = y + (size_t)b * 4096 * 384;
  const int p00 = (i * 2) * 64 + j * 2;
  for (int c = threadIdx.x; c < 384; c += 256) {
    float g1 = 0.5f * b2f(xr[c]);
    float g2 = 0.5f * b2f(xr[c + 384]);
    float g3 = 0.5f * b2f(xr[c + 768]);
    float g4 = 0.5f * b2f(xr[c + 1152]);
    yb[(size_t)p00 * 384 + c]        = f2b(g1 - g2 - g3 + g4);
    yb[(size_t)(p00 + 64) * 384 + c] = f2b(g1 - g2 + g3 - g4);
    yb[(size_t)(p00 + 1) * 384 + c]  = f2b(g1 + g2 - g3 - g4);
    yb[(size_t)(p00 + 65) * 384 + c] = f2b(g1 + g2 + g3 + g4);
  }
}

extern "C" void kernel_launch(void* const* d_in, const int* in_sizes, int n_in,
                              void* d_out, int out_size, void* d_ws, size_t ws_size,
                              hipStream_t stream) {
  (void)in_sizes; (void)n_in; (void)out_size; (void)ws_size;
  const float* sf      = (const float*)d_in[0];
  const float* wf      = (const float*)d_in[1];
  const float* q_w     = (const float*)d_in[2];
  const float* q_b     = (const float*)d_in[3];
  const float* q_ln_w  = (const float*)d_in[4];
  const float* q_ln_b  = (const float*)d_in[5];
  const float* kv_w    = (const float*)d_in[6];
  const float* kv_b    = (const float*)d_in[7];
  const float* kv_ln_w = (const float*)d_in[8];
  const float* kv_ln_b = (const float*)d_in[9];
  const float* out_w   = (const float*)d_in[10];
  const float* out_b   = (const float*)d_in[11];
  float* out = (float*)d_out;

  // ---- workspace layout, ~168 MiB peak with phase aliasing ----
  char* p = (char*)d_ws;
  float* A  = (float*)p; p += 50331648;   // t_sf f32; later k1h|k1l|v1|k2|v1t
  float* B1 = (float*)p; p += 50331648;   // t_wf lo f32; later xall
  u16*   B2 = (u16*)p;   p += 25165824;   // t_wf hi bf16; later v2t; later y
  u16* q1h = (u16*)p; p += 6291456;       // (8,1024,384) bf16 hi
  u16* q1l = (u16*)p; p += 6291456;       // lo
  u16* q2  = (u16*)p; p += 18874368;      // (24,1024,384) bf16
  u16* v2  = (u16*)p; p += 18874368;      // (24,1024,384) bf16 row-major
  float2* stats1 = (float2*)p; p += 65536;    // 8192 float2 (unused now)
  float2* stats2 = (float2*)p;                // 24576 float2
  (void)stats1;
  // aliases inside A (t_sf dead after dwt_sf):
  u16* k1h = (u16*)A;
  u16* k1l = k1h + 3145728;
  u16* v1  = k1l + 3145728;
  u16* k2  = v1 + 3145728;
  u16* v1t = k2 + 9437184;            // (8,384,1024)
  u16* xall = (u16*)B1;               // (8,1024,1536)
  u16* v2t = B2;                      // (24,384,1024)
  u16* y   = B2;                      // (8,4096,384)

  // projections (MFMA) + LN; att1 score chain stays f32-precision via split
  gemm_mfma<1, float, float><<<dim3(3, 256), 256, 0, stream>>>(sf, q_w, q_b, A);
  ln_inplace<float><<<32768, 256, 0, stream>>>(A, q_ln_w, q_ln_b, 384);
  gemm_mfma<1, float, float><<<dim3(3, 256), 256, 0, stream>>>(wf, kv_w, kv_b, B1);
  gemm_mfma<0, float, u16><<<dim3(3, 256), 256, 0, stream>>>(wf, kv_w + 384 * 384, kv_b + 384, B2);
  ln_wf_split<<<32768, 256, 0, stream>>>(B1, B2, kv_ln_w, kv_ln_b);

  // DWT (dwt_sf must read A before k1/v1/k2/v1t overwrite it)
  dwt_sf<<<8192, 256, 0, stream>>>(A, q1h, q1l, q2);
  dwt_wf_split<<<8192, 256, 0, stream>>>(B1, B2, k1h, k1l, v1, k2, v2);

  // V transposes for MFMA B-operand layout
  transpose_rm<<<dim3(6, 16, 8), 256, 0, stream>>>(v1, v1t);
  transpose_rm<<<dim3(6, 16, 24), 256, 0, stream>>>(v2, v2t);  // overwrites dead t_wf-hi

  // attention (1D grids, XCD-swizzled inside the kernels)
  att2_stats<<<384, 256, 0, stream>>>(q2, k2, stats2, SCALE2);
  att1_fused<<<256, 256, 0, stream>>>(q1h, q1l, k1h, k1l, v1t, xall);
  att2_accum<<<384, 256, 0, stream>>>(k2, q2, v2t, stats2, xall, SCALE2);

  // IWT + output projection (MFMA)
  iwt_y<<<8192, 256, 0, stream>>>(xall, y);
  gemm_mfma<0, u16, float><<<dim3(3, 256), 256, 0, stream>>>(y, out_w, out_b, out);
}

// Round 5
// 762.235 us; speedup vs baseline: 1.4600x; 1.0645x over previous
//
#include <hip/hip_runtime.h>
#include <hip/hip_bf16.h>

typedef unsigned short u16;
typedef unsigned int u32;
typedef __attribute__((ext_vector_type(8))) short short8;   // 8 bf16 (4 VGPRs)
typedef __attribute__((ext_vector_type(4))) float f32x4;    // MFMA C/D

#define MFMA_BF16(A, B, C) __builtin_amdgcn_mfma_f32_16x16x32_bf16(A, B, C, 0, 0, 0)

#define SCALE2 0.08838834764831845f
#define LNEPS 1e-5f

__device__ __forceinline__ float b2f(u16 u) {
  return __uint_as_float(((u32)u) << 16);
}
__device__ __forceinline__ u16 f2b(float f) {
  u32 x = __float_as_uint(f);
  return (u16)((x + 0x7fffu + ((x >> 16) & 1u)) >> 16);  // RNE
}
__device__ __forceinline__ float ldf(const float* p) { return *p; }
__device__ __forceinline__ float ldf(const u16* p) { return b2f(*p); }
__device__ __forceinline__ void stf(float* p, float v) { *p = v; }
__device__ __forceinline__ void stf(u16* p, float v) { *p = f2b(v); }

// ---------------- MFMA GEMM: out[m][n] = sum_k X[m][k]*W[n][k] + bias[n]
// K=384, N=384. Block 128Mx128N, 4 waves (2x2 of 64x64). SPLIT: hi/lo bf16
// 3-product f32-precision (X must be float).
template <int SPLIT, typename TX, typename TO>
__global__ __launch_bounds__(256) void gemm_mfma(
    const TX* __restrict__ X, const float* __restrict__ W,
    const float* __restrict__ bias, TO* __restrict__ out) {
  __shared__ __align__(16) u16 AH[128 * 40];
  __shared__ __align__(16) u16 BH[128 * 40];
  __shared__ __align__(16) u16 AL[SPLIT ? 128 * 40 : 8];
  __shared__ __align__(16) u16 BL[SPLIT ? 128 * 40 : 8];
  const int tid = threadIdx.x;
  const int w = tid >> 6, lane = tid & 63;
  const int t = lane & 15, qd = lane >> 4;
  const int wm = w & 1, wn = w >> 1;
  const int m0 = blockIdx.y * 128, n0 = blockIdx.x * 128;
  f32x4 acc[4][4];
#pragma unroll
  for (int i = 0; i < 4; ++i)
#pragma unroll
    for (int j = 0; j < 4; ++j) acc[i][j] = (f32x4){0.f, 0.f, 0.f, 0.f};
  for (int kt = 0; kt < 384; kt += 32) {
    // stage A (128x32) and B (128x32) with f32->bf16 convert
#pragma unroll
    for (int rep = 0; rep < 4; ++rep) {
      int e = tid + rep * 256;
      int m = e >> 3, k4 = (e & 7) * 4;
      if constexpr (sizeof(TX) == 4) {
        float4 v = *(const float4*)(X + (size_t)(m0 + m) * 384 + kt + k4);
        u16 h0 = f2b(v.x), h1 = f2b(v.y), h2 = f2b(v.z), h3 = f2b(v.w);
        u32 hp0 = (u32)h0 | ((u32)h1 << 16), hp1 = (u32)h2 | ((u32)h3 << 16);
        *(uint2*)&AH[m * 40 + k4] = make_uint2(hp0, hp1);
        if (SPLIT) {
          u16 l0 = f2b(v.x - b2f(h0)), l1 = f2b(v.y - b2f(h1));
          u16 l2 = f2b(v.z - b2f(h2)), l3 = f2b(v.w - b2f(h3));
          *(uint2*)&AL[m * 40 + k4] =
              make_uint2((u32)l0 | ((u32)l1 << 16), (u32)l2 | ((u32)l3 << 16));
        }
      } else {
        uint2 raw = *(const uint2*)(X + (size_t)(m0 + m) * 384 + kt + k4);
        *(uint2*)&AH[m * 40 + k4] = raw;
      }
      float4 wv = *(const float4*)(W + (size_t)(n0 + m) * 384 + kt + k4);
      u16 wh0 = f2b(wv.x), wh1 = f2b(wv.y), wh2 = f2b(wv.z), wh3 = f2b(wv.w);
      *(uint2*)&BH[m * 40 + k4] =
          make_uint2((u32)wh0 | ((u32)wh1 << 16), (u32)wh2 | ((u32)wh3 << 16));
      if (SPLIT) {
        u16 wl0 = f2b(wv.x - b2f(wh0)), wl1 = f2b(wv.y - b2f(wh1));
        u16 wl2 = f2b(wv.z - b2f(wh2)), wl3 = f2b(wv.w - b2f(wh3));
        *(uint2*)&BL[m * 40 + k4] =
            make_uint2((u32)wl0 | ((u32)wl1 << 16), (u32)wl2 | ((u32)wl3 << 16));
      }
    }
    __syncthreads();
    short8 af[4], bf[4], al[4], bl[4];
#pragma unroll
    for (int mi = 0; mi < 4; ++mi) {
      af[mi] = *(const short8*)&AH[(wm * 64 + mi * 16 + t) * 40 + qd * 8];
      bf[mi] = *(const short8*)&BH[(wn * 64 + mi * 16 + t) * 40 + qd * 8];
      if (SPLIT) {
        al[mi] = *(const short8*)&AL[(wm * 64 + mi * 16 + t) * 40 + qd * 8];
        bl[mi] = *(const short8*)&BL[(wn * 64 + mi * 16 + t) * 40 + qd * 8];
      }
    }
#pragma unroll
    for (int mi = 0; mi < 4; ++mi)
#pragma unroll
      for (int ni = 0; ni < 4; ++ni) {
        acc[mi][ni] = MFMA_BF16(af[mi], bf[ni], acc[mi][ni]);
        if (SPLIT) {
          acc[mi][ni] = MFMA_BF16(al[mi], bf[ni], acc[mi][ni]);
          acc[mi][ni] = MFMA_BF16(af[mi], bl[ni], acc[mi][ni]);
        }
      }
    __syncthreads();
  }
#pragma unroll
  for (int ni = 0; ni < 4; ++ni) {
    int n = n0 + wn * 64 + ni * 16 + t;
    float bv = bias[n];
#pragma unroll
    for (int mi = 0; mi < 4; ++mi)
#pragma unroll
      for (int r = 0; r < 4; ++r) {
        int m = m0 + wm * 64 + mi * 16 + qd * 4 + r;
        stf(&out[(size_t)m * 384 + n], acc[mi][ni][r] + bv);
      }
  }
}

// ---------------- row LayerNorm, in place (templated storage)
template <typename T>
__global__ __launch_bounds__(256) void ln_inplace(
    T* __restrict__ Tb, const float* __restrict__ w, const float* __restrict__ b, int N) {
  const int row = blockIdx.x, tid = threadIdx.x;
  T* Tr = Tb + (size_t)row * N;
  float vals[3];
  float s = 0.f, ss = 0.f;
  int nv = 0;
  for (int i = tid; i < N; i += 256) {
    float v = ldf(&Tr[i]);
    vals[nv++] = v;
    s += v; ss += v * v;
  }
#pragma unroll
  for (int mk = 32; mk; mk >>= 1) { s += __shfl_xor(s, mk); ss += __shfl_xor(ss, mk); }
  __shared__ float red[8];
  if ((tid & 63) == 0) { red[tid >> 6] = s; red[4 + (tid >> 6)] = ss; }
  __syncthreads();
  s = red[0] + red[1] + red[2] + red[3];
  ss = red[4] + red[5] + red[6] + red[7];
  float inv = 1.f / (float)N;
  float mean = s * inv;
  float var = fmaxf(ss * inv - mean * mean, 0.f);
  float rstd = rsqrtf(var + LNEPS);
  nv = 0;
  for (int i = tid; i < N; i += 256) {
    float v = (vals[nv++] - mean) * rstd * w[i] + b[i];
    stf(&Tr[i], v);
  }
}

// ---------------- LN over split storage: lo = f32 chans 0..383, hi = bf16 chans 384..767
__global__ __launch_bounds__(256) void ln_wf_split(
    float* __restrict__ lo, u16* __restrict__ hi,
    const float* __restrict__ w, const float* __restrict__ b) {
  const int row = blockIdx.x, tid = threadIdx.x;
  float* L = lo + (size_t)row * 384;
  u16* H = hi + (size_t)row * 384;
  float vals[3];
  float s = 0.f, ss = 0.f;
  int nv = 0;
  for (int i = tid; i < 768; i += 256) {
    float v = (i < 384) ? L[i] : b2f(H[i - 384]);
    vals[nv++] = v;
    s += v; ss += v * v;
  }
#pragma unroll
  for (int mk = 32; mk; mk >>= 1) { s += __shfl_xor(s, mk); ss += __shfl_xor(ss, mk); }
  __shared__ float red[8];
  if ((tid & 63) == 0) { red[tid >> 6] = s; red[4 + (tid >> 6)] = ss; }
  __syncthreads();
  s = red[0] + red[1] + red[2] + red[3];
  ss = red[4] + red[5] + red[6] + red[7];
  float mean = s * (1.f / 768.f);
  float var = fmaxf(ss * (1.f / 768.f) - mean * mean, 0.f);
  float rstd = rsqrtf(var + LNEPS);
  nv = 0;
  for (int i = 0 + tid; i < 768; i += 256) {
    float v = (vals[nv++] - mean) * rstd * w[i] + b[i];
    if (i < 384) L[i] = v; else H[i - 384] = f2b(v);
  }
}

// ---------------- DWT sf: t_sf f32 -> q1 split-bf16 (hi+lo), q2 bf16 (3 heads)
__global__ __launch_bounds__(256) void dwt_sf(
    const float* __restrict__ T, u16* __restrict__ q1h, u16* __restrict__ q1l,
    u16* __restrict__ q2) {
  const int blk = blockIdx.x;
  const int b = blk >> 10, pos = blk & 1023;
  const int i = pos >> 5, j = pos & 31;
  const int p00 = (i * 2) * 64 + j * 2;
  const float* base = T + (size_t)b * 4096 * 384;
  for (int ch = threadIdx.x; ch < 384; ch += 256) {
    float a  = base[(size_t)p00 * 384 + ch];
    float cc = base[(size_t)(p00 + 1) * 384 + ch];
    float bb = base[(size_t)(p00 + 64) * 384 + ch];
    float dd = base[(size_t)(p00 + 65) * 384 + ch];
    float s0 = 0.5f * ( a + bb + cc + dd);
    float s1 = 0.5f * (-a - bb + cc + dd);
    float s2 = 0.5f * (-a + bb - cc + dd);
    float s3 = 0.5f * ( a - bb - cc + dd);
    size_t po = (size_t)(b * 1024 + pos) * 384 + ch;
    u16 h = f2b(s0);
    q1h[po] = h;
    q1l[po] = f2b(s0 - b2f(h));
    q2[(size_t)((b * 3 + 0) * 1024 + pos) * 384 + ch] = f2b(s1);
    q2[(size_t)((b * 3 + 1) * 1024 + pos) * 384 + ch] = f2b(s2);
    q2[(size_t)((b * 3 + 2) * 1024 + pos) * 384 + ch] = f2b(s3);
  }
}

// ---------------- DWT wf (split input): lo f32, hi bf16 -> k1 split-bf16, v1, k2, v2
__global__ __launch_bounds__(256) void dwt_wf_split(
    const float* __restrict__ lo, const u16* __restrict__ hi,
    u16* __restrict__ k1h, u16* __restrict__ k1l, u16* __restrict__ v1,
    u16* __restrict__ k2, u16* __restrict__ v2) {
  const int blk = blockIdx.x;
  const int b = blk >> 10, pos = blk & 1023;
  const int i = pos >> 5, j = pos & 31;
  const int p00 = (i * 2) * 64 + j * 2;
  for (int ch = threadIdx.x; ch < 768; ch += 256) {
    float a, bb, cc, dd;
    if (ch < 384) {
      const float* base = lo + (size_t)b * 4096 * 384;
      a  = base[(size_t)p00 * 384 + ch];
      cc = base[(size_t)(p00 + 1) * 384 + ch];
      bb = base[(size_t)(p00 + 64) * 384 + ch];
      dd = base[(size_t)(p00 + 65) * 384 + ch];
    } else {
      const u16* base = hi + (size_t)b * 4096 * 384;
      int c = ch - 384;
      a  = b2f(base[(size_t)p00 * 384 + c]);
      cc = b2f(base[(size_t)(p00 + 1) * 384 + c]);
      bb = b2f(base[(size_t)(p00 + 64) * 384 + c]);
      dd = b2f(base[(size_t)(p00 + 65) * 384 + c]);
    }
    float s0 = 0.5f * ( a + bb + cc + dd);
    float s1 = 0.5f * (-a - bb + cc + dd);
    float s2 = 0.5f * (-a + bb - cc + dd);
    float s3 = 0.5f * ( a - bb - cc + dd);
    if (ch < 384) {
      size_t po = (size_t)(b * 1024 + pos) * 384 + ch;
      u16 h = f2b(s0);
      k1h[po] = h;
      k1l[po] = f2b(s0 - b2f(h));
      v1[po] = f2b(s2);
      k2[(size_t)((b * 3 + 1) * 1024 + pos) * 384 + ch] = f2b(s1);
      v2[(size_t)((b * 3 + 1) * 1024 + pos) * 384 + ch] = f2b(s3);
    } else {
      int c = ch - 384;
      k2[(size_t)((b * 3 + 0) * 1024 + pos) * 384 + c] = f2b(s0);
      k2[(size_t)((b * 3 + 2) * 1024 + pos) * 384 + c] = f2b(s1);
      v2[(size_t)((b * 3 + 0) * 1024 + pos) * 384 + c] = f2b(s2);
      v2[(size_t)((b * 3 + 2) * 1024 + pos) * 384 + c] = f2b(s3);
    }
  }
}

// ---------------- transpose [bh][1024][384] -> [bh][384][1024]
__global__ __launch_bounds__(256) void transpose_rm(
    const u16* __restrict__ in, u16* __restrict__ out) {
  __shared__ u16 T[64][65];
  const int tid = threadIdx.x;
  const int bh = blockIdx.z, r0 = blockIdx.y * 64, c0 = blockIdx.x * 64;
  const u16* ip = in + ((size_t)bh * 1024 + r0) * 384 + c0;
  for (int i = tid; i < 2048; i += 256) {
    int r = i >> 5, c2 = i & 31;
    u32 v = *(const u32*)(ip + (size_t)r * 384 + c2 * 2);
    T[c2 * 2][r] = (u16)v;
    T[c2 * 2 + 1][r] = (u16)(v >> 16);
  }
  __syncthreads();
  u16* op = out + ((size_t)bh * 384 + c0) * 1024 + r0;
  for (int i = tid; i < 2048; i += 256) {
    int c = i >> 5, r2 = i & 31;
    u32 v = (u32)T[c][r2 * 2] | ((u32)T[c][r2 * 2 + 1] << 16);
    *(u32*)(op + (size_t)c * 1024 + r2 * 2) = v;
  }
}

// att2 (24 heads x 16 blocks of 64 own rows): XCD x gets heads {x, x+8, x+16}.
__device__ __forceinline__ void xcd24v2(int L, int& bh, int& o0) {
  int s = L >> 3;
  bh = (s >> 4) * 8 + (L & 7);
  o0 = (s & 15) * 64;
}

// ---------------- att2 stats v2: block owns 64 q-rows (wave w -> 16 rows).
// Stream k2 in 32-row tiles staged to LDS ONCE per block (4x cross-wave reuse
// vs direct loads); double-buffered, 1 barrier/iter. Stats complete per wave.
__global__ __launch_bounds__(256) void att2_stats(
    const u16* __restrict__ q, const u16* __restrict__ k,
    float2* __restrict__ stats, float scale) {
  __shared__ __align__(16) u16 S[2][12 * 32 * 40];  // 61440 B, stride-40 pad
  const int tid = threadIdx.x, w = tid >> 6, lane = tid & 63;
  const int t = lane & 15, qd = lane >> 4;
  int bh, o0;
  xcd24v2(blockIdx.x, bh, o0);
  short8 Ah[12];
  {
    const u16* qp = q + ((size_t)bh * 1024 + o0 + w * 16 + t) * 384 + qd * 8;
#pragma unroll
    for (int ks = 0; ks < 12; ++ks) Ah[ks] = *(const short8*)(qp + ks * 32);
  }
  float m[4] = {-1e30f, -1e30f, -1e30f, -1e30f}, l[4] = {0.f, 0.f, 0.f, 0.f};
  const u16* kb = k + (size_t)bh * 1024 * 384;
  int buf = 0;
  for (int st = 0; st < 32; ++st) {
    // stage stream rows st*32..+32: unit = 8 u16; [row][c8] -> S[ks][row][qq*8]
#pragma unroll
    for (int i = 0; i < 6; ++i) {
      int u = tid + i * 256;
      int r = u / 48, c8 = u % 48;
      int ks = c8 >> 2, qq = c8 & 3;
      uint4 v = *(const uint4*)(kb + (size_t)(st * 32 + r) * 384 + c8 * 8);
      *(uint4*)&S[buf][(ks * 32 + r) * 40 + qq * 8] = v;
    }
    __syncthreads();
    f32x4 Sa0 = {0.f,0.f,0.f,0.f}, Sb0 = {0.f,0.f,0.f,0.f};
    f32x4 Sa1 = {0.f,0.f,0.f,0.f}, Sb1 = {0.f,0.f,0.f,0.f};
#pragma unroll
    for (int ks = 0; ks < 12; ks += 2) {
      short8 B00 = *(const short8*)&S[buf][(ks * 32 + t) * 40 + qd * 8];
      short8 B01 = *(const short8*)&S[buf][((ks + 1) * 32 + t) * 40 + qd * 8];
      short8 B10 = *(const short8*)&S[buf][(ks * 32 + 16 + t) * 40 + qd * 8];
      short8 B11 = *(const short8*)&S[buf][((ks + 1) * 32 + 16 + t) * 40 + qd * 8];
      Sa0 = MFMA_BF16(Ah[ks], B00, Sa0);
      Sb0 = MFMA_BF16(Ah[ks + 1], B01, Sb0);
      Sa1 = MFMA_BF16(Ah[ks], B10, Sa1);
      Sb1 = MFMA_BF16(Ah[ks + 1], B11, Sb1);
    }
#pragma unroll
    for (int r = 0; r < 4; ++r) {
      float s0 = (Sa0[r] + Sb0[r]) * scale;
      float s1 = (Sa1[r] + Sb1[r]) * scale;
      float mx = fmaxf(s0, s1);
#pragma unroll
      for (int mk = 1; mk < 16; mk <<= 1) mx = fmaxf(mx, __shfl_xor(mx, mk));
      float nm = fmaxf(m[r], mx);
      float e = __expf(s0 - nm) + __expf(s1 - nm);
#pragma unroll
      for (int mk = 1; mk < 16; mk <<= 1) e += __shfl_xor(e, mk);
      l[r] = l[r] * __expf(m[r] - nm) + e;
      m[r] = nm;
    }
    buf ^= 1;
  }
  if (t == 0) {
#pragma unroll
    for (int r = 0; r < 4; ++r)
      stats[(size_t)bh * 1024 + o0 + w * 16 + qd * 4 + r] =
          make_float2(m[r], 1.f / l[r]);
  }
}

// ---------------- att2 accumulate v2 (transposed gather): block owns 64 k2
// rows (wave w -> 16 output rows x ALL 384 dims, acc[24]). Stream q2 tile (32
// rows) + V tile (384x32) staged to LDS once per block; single-buffer, two
// barriers/iter. P is wave-private LDS (no cross-wave barrier).
__global__ __launch_bounds__(256, 2) void att2_accum(
    const u16* __restrict__ own, const u16* __restrict__ str,
    const u16* __restrict__ vt, const float2* __restrict__ stats,
    u16* __restrict__ xall, float scale) {
  __shared__ __align__(16) u16 SQ[12 * 32 * 40];   // 30720 B
  __shared__ __align__(16) u16 SV[24 * 16 * 40];   // 30720 B
  __shared__ __align__(16) u16 P[4][16 * 40];      // 5120 B, wave-private
  const int tid = threadIdx.x, w = tid >> 6, lane = tid & 63;
  const int t = lane & 15, qd = lane >> 4;
  int bh, o0;
  xcd24v2(blockIdx.x, bh, o0);
  short8 Ah[12];
  {
    const u16* op = own + ((size_t)bh * 1024 + o0 + w * 16 + t) * 384 + qd * 8;
#pragma unroll
    for (int ks = 0; ks < 12; ++ks) Ah[ks] = *(const short8*)(op + ks * 32);
  }
  f32x4 acc[24];
#pragma unroll
  for (int i = 0; i < 24; ++i) acc[i] = (f32x4){0.f, 0.f, 0.f, 0.f};
  const u16* sb = str + (size_t)bh * 1024 * 384;
  const u16* vb = vt + (size_t)bh * 384 * 1024;
  u16* Pw = &P[w][0];
  for (int st = 0; st < 32; ++st) {
    __syncthreads();  // all waves done reading SQ/SV from previous iter
#pragma unroll
    for (int i = 0; i < 6; ++i) {
      int u = tid + i * 256;
      int r = u / 48, c8 = u % 48;
      int ks = c8 >> 2, qq = c8 & 3;
      uint4 v = *(const uint4*)(sb + (size_t)(st * 32 + r) * 384 + c8 * 8);
      *(uint4*)&SQ[(ks * 32 + r) * 40 + qq * 8] = v;
    }
#pragma unroll
    for (int i = 0; i < 6; ++i) {
      int u = tid + i * 256;
      int d = u >> 2, cq = u & 3;
      uint4 v = *(const uint4*)(vb + (size_t)d * 1024 + st * 32 + cq * 8);
      *(uint4*)&SV[d * 40 + cq * 8] = v;
    }
    float2 cs0 = stats[(size_t)bh * 1024 + st * 32 + t];
    float2 cs1 = stats[(size_t)bh * 1024 + st * 32 + 16 + t];
    __syncthreads();  // staging visible
    f32x4 Sa0 = {0.f,0.f,0.f,0.f}, Sb0 = {0.f,0.f,0.f,0.f};
    f32x4 Sa1 = {0.f,0.f,0.f,0.f}, Sb1 = {0.f,0.f,0.f,0.f};
#pragma unroll
    for (int ks = 0; ks < 12; ks += 2) {
      short8 B00 = *(const short8*)&SQ[(ks * 32 + t) * 40 + qd * 8];
      short8 B01 = *(const short8*)&SQ[((ks + 1) * 32 + t) * 40 + qd * 8];
      short8 B10 = *(const short8*)&SQ[(ks * 32 + 16 + t) * 40 + qd * 8];
      short8 B11 = *(const short8*)&SQ[((ks + 1) * 32 + 16 + t) * 40 + qd * 8];
      Sa0 = MFMA_BF16(Ah[ks], B00, Sa0);
      Sb0 = MFMA_BF16(Ah[ks + 1], B01, Sb0);
      Sa1 = MFMA_BF16(Ah[ks], B10, Sa1);
      Sb1 = MFMA_BF16(Ah[ks + 1], B11, Sb1);
    }
#pragma unroll
    for (int r = 0; r < 4; ++r) {
      float p0 = __expf((Sa0[r] + Sb0[r]) * scale - cs0.x) * cs0.y;
      float p1 = __expf((Sa1[r] + Sb1[r]) * scale - cs1.x) * cs1.y;
      Pw[(qd * 4 + r) * 40 + t] = f2b(p0);
      Pw[(qd * 4 + r) * 40 + 16 + t] = f2b(p1);
    }
    // wave-private P: compiler inserts lgkmcnt wait before the read
    short8 Pa = *(const short8*)&Pw[t * 40 + qd * 8];
#pragma unroll
    for (int nj = 0; nj < 24; ++nj) {
      short8 Vf = *(const short8*)&SV[(nj * 16 + t) * 40 + qd * 8];
      acc[nj] = MFMA_BF16(Pa, Vf, acc[nj]);
    }
  }
  const int b_out = bh / 3, off = (1 + bh % 3) * 384;
#pragma unroll
  for (int nj = 0; nj < 24; ++nj)
#pragma unroll
    for (int r = 0; r < 4; ++r) {
      int row = o0 + w * 16 + qd * 4 + r;
      int d = nj * 16 + t;
      xall[((size_t)b_out * 1024 + row) * 1536 + off + d] = f2b(acc[nj][r]);
    }
}

// ---------------- att1 fused flash, split-K over the stream dimension.
// Grid 512 = (sseg 0/1) x 32 row-blocks x 8 heads; 2 blocks/CU. Block owns 32
// q-rows, processes stream rows sseg*512..+512 (16 iters of 32). Emits
// UNNORMALIZED f32 partial (32x384) + per-row (m,l); att1_merge combines.
// Wave (wr,sh): scores for rows wr*16, stream half sh; softmax merged across
// sh via comb; PV over dims sh*192. ks-blocks padded (stride 1288 u16) so
// staging writes spread across all 8 bank granules (was 12-way conflict).
__global__ __launch_bounds__(256, 2) void att1_fused(
    const u16* __restrict__ qh, const u16* __restrict__ ql,
    const u16* __restrict__ kh, const u16* __restrict__ kl,
    const u16* __restrict__ vt, float* __restrict__ part,
    float2* __restrict__ ml) {
  __shared__ __align__(16) u16 KH[12 * 1288];      // 30912 B
  __shared__ __align__(16) u16 KL[12 * 1288];      // 30912 B
  __shared__ __align__(16) u16 P[2][16 * 40];      // 2560 B (per row-group)
  __shared__ float2 comb[2][2][16];                // 512 B  (wr, sh, row)
  const int tid = threadIdx.x, w = tid >> 6, lane = tid & 63;
  const int t = lane & 15, qd = lane >> 4;
  const int wr = w & 1, sh = w >> 1;
  const int bh = blockIdx.x & 7;
  const int q = blockIdx.x >> 3;
  const int o0 = (q & 31) * 32;
  const int sseg = q >> 5;
  const int sbase = sseg * 512;
  short8 Ah[12], Al[12];
  {
    const u16* qp  = qh + ((size_t)bh * 1024 + o0 + wr * 16 + t) * 384 + qd * 8;
    const u16* qp2 = ql + ((size_t)bh * 1024 + o0 + wr * 16 + t) * 384 + qd * 8;
#pragma unroll
    for (int ks = 0; ks < 12; ++ks) {
      Ah[ks] = *(const short8*)(qp + ks * 32);
      Al[ks] = *(const short8*)(qp2 + ks * 32);
    }
  }
  f32x4 acc[12];
#pragma unroll
  for (int i = 0; i < 12; ++i) acc[i] = (f32x4){0.f, 0.f, 0.f, 0.f};
  float m[4] = {-1e30f, -1e30f, -1e30f, -1e30f}, l[4] = {0.f, 0.f, 0.f, 0.f};
  const u16* khb = kh + (size_t)bh * 1024 * 384;
  const u16* klb = kl + (size_t)bh * 1024 * 384;
  const u16* vbase = vt + ((size_t)bh * 384 + sh * 192 + t) * 1024 + sbase;
  // prologue: stage stream tile 0
#pragma unroll
  for (int i = 0; i < 6; ++i) {
    int u = tid + i * 256;
    int r = u / 48, c8 = u % 48;
    int ks = c8 >> 2, j8 = c8 & 3;
    *(uint4*)&KH[ks * 1288 + r * 40 + j8 * 8] =
        *(const uint4*)(khb + (size_t)(sbase + r) * 384 + c8 * 8);
    *(uint4*)&KL[ks * 1288 + r * 40 + j8 * 8] =
        *(const uint4*)(klb + (size_t)(sbase + r) * 384 + c8 * 8);
  }
  __syncthreads();
  for (int st = 0; st < 16; ++st) {
    // V fragments for this tile (global; issued early to overlap scores)
    short8 Vr[12];
#pragma unroll
    for (int nj = 0; nj < 12; ++nj)
      Vr[nj] = *(const short8*)(vbase + (size_t)nj * 16 * 1024 + st * 32 + qd * 8);
    // scores: own rows (group wr) x stream half sh; 3 independent f32 chains
    f32x4 Shh = {0.f,0.f,0.f,0.f}, Slh = {0.f,0.f,0.f,0.f}, Shl = {0.f,0.f,0.f,0.f};
#pragma unroll
    for (int ks = 0; ks < 12; ++ks) {
      short8 Bh = *(const short8*)&KH[ks * 1288 + (sh * 16 + t) * 40 + qd * 8];
      short8 Bl = *(const short8*)&KL[ks * 1288 + (sh * 16 + t) * 40 + qd * 8];
      Shh = MFMA_BF16(Ah[ks], Bh, Shh);
      Slh = MFMA_BF16(Al[ks], Bh, Slh);
      Shl = MFMA_BF16(Ah[ks], Bl, Shl);
    }
    float s[4], mx[4], e[4];
#pragma unroll
    for (int r = 0; r < 4; ++r) {
      s[r] = Shh[r] + Slh[r] + Shl[r];
      float v = s[r];
#pragma unroll
      for (int mk = 1; mk < 16; mk <<= 1) v = fmaxf(v, __shfl_xor(v, mk));
      mx[r] = v;
      float ee = __expf(s[r] - v);
#pragma unroll
      for (int mk = 1; mk < 16; mk <<= 1) ee += __shfl_xor(ee, mk);
      e[r] = ee;
    }
    if (t == 0) {
#pragma unroll
      for (int r = 0; r < 4; ++r)
        comb[wr][sh][qd * 4 + r] = make_float2(mx[r], e[r]);
    }
    __syncthreads();  // B2: comb visible; all KH/KL frag reads retired
    // stage NEXT tile (overlaps the merge VALU below; visible after B3)
    if (st < 15) {
#pragma unroll
      for (int i = 0; i < 6; ++i) {
        int u = tid + i * 256;
        int r = u / 48, c8 = u % 48;
        int ks = c8 >> 2, j8 = c8 & 3;
        *(uint4*)&KH[ks * 1288 + r * 40 + j8 * 8] =
            *(const uint4*)(khb + (size_t)(sbase + (st + 1) * 32 + r) * 384 + c8 * 8);
        *(uint4*)&KL[ks * 1288 + r * 40 + j8 * 8] =
            *(const uint4*)(klb + (size_t)(sbase + (st + 1) * 32 + r) * 384 + c8 * 8);
      }
    }
    // merge softmax state across the sh pair; rescale acc; emit P half
#pragma unroll
    for (int r = 0; r < 4; ++r) {
      float2 c0 = comb[wr][0][qd * 4 + r];
      float2 c1 = comb[wr][1][qd * 4 + r];
      float nm = fmaxf(m[r], fmaxf(c0.x, c1.x));
      float sc = __expf(m[r] - nm);
      l[r] = l[r] * sc + c0.y * __expf(c0.x - nm) + c1.y * __expf(c1.x - nm);
      m[r] = nm;
#pragma unroll
      for (int nj = 0; nj < 12; ++nj) acc[nj][r] *= sc;
      P[wr][(qd * 4 + r) * 40 + sh * 16 + t] = f2b(__expf(s[r] - nm));
    }
    __syncthreads();  // B3: P + next-tile staging visible
    short8 Pa = *(const short8*)&P[wr][t * 40 + qd * 8];
#pragma unroll
    for (int nj = 0; nj < 12; ++nj) acc[nj] = MFMA_BF16(Pa, Vr[nj], acc[nj]);
  }
  // store unnormalized f32 partial + per-row (m,l) for the merge kernel
  float* pb = part + ((size_t)(sseg * 8 + bh) * 1024 + o0 + wr * 16) * 384;
#pragma unroll
  for (int r = 0; r < 4; ++r) {
    int row = qd * 4 + r;
#pragma unroll
    for (int nj = 0; nj < 12; ++nj)
      pb[(size_t)row * 384 + sh * 192 + nj * 16 + t] = acc[nj][r];
  }
  if (sh == 0 && t == 0) {
#pragma unroll
    for (int r = 0; r < 4; ++r)
      ml[sseg * 8192 + bh * 1024 + o0 + wr * 16 + qd * 4 + r] =
          make_float2(m[r], l[r]);
  }
}

// ---------------- att1 merge: combine the two stream-segment partials.
// out[row][d] = (p0*e^(m0-M) + p1*e^(m1-M)) / (l0*e^(m0-M) + l1*e^(m1-M))
__global__ __launch_bounds__(192) void att1_merge(
    const float* __restrict__ part, const float2* __restrict__ ml,
    u16* __restrict__ xall) {
  const int rb = blockIdx.x;  // bh*1024 + row, 0..8191
  float2 a = ml[rb];
  float2 b = ml[8192 + rb];
  float M = fmaxf(a.x, b.x);
  float e0 = __expf(a.x - M), e1 = __expf(b.x - M);
  float inv = 1.f / (a.y * e0 + b.y * e1);
  const float* p0 = part + (size_t)rb * 384;
  const float* p1 = part + (size_t)(8192 + rb) * 384;
  u16* xr = xall + (size_t)rb * 1536;
  for (int ch = threadIdx.x; ch < 384; ch += 192)
    xr[ch] = f2b((p0[ch] * e0 + p1[ch] * e1) * inv);
}

// ---------------- IWT: xall (B,1024,1536) -> y (B,4096,384)
__global__ __launch_bounds__(256) void iwt_y(const u16* __restrict__ xall, u16* __restrict__ y) {
  const int blk = blockIdx.x;
  const int b = blk >> 10, pos = blk & 1023;
  const int i = pos >> 5, j = pos & 31;
  const u16* xr = xall + (size_t)(b * 1024 + pos) * 1536;
  u16* yb = y + (size_t)b * 4096 * 384;
  const int p00 = (i * 2) * 64 + j * 2;
  for (int c = threadIdx.x; c < 384; c += 256) {
    float g1 = 0.5f * b2f(xr[c]);
    float g2 = 0.5f * b2f(xr[c + 384]);
    float g3 = 0.5f * b2f(xr[c + 768]);
    float g4 = 0.5f * b2f(xr[c + 1152]);
    yb[(size_t)p00 * 384 + c]        = f2b(g1 - g2 - g3 + g4);
    yb[(size_t)(p00 + 64) * 384 + c] = f2b(g1 - g2 + g3 - g4);
    yb[(size_t)(p00 + 1) * 384 + c]  = f2b(g1 + g2 - g3 - g4);
    yb[(size_t)(p00 + 65) * 384 + c] = f2b(g1 + g2 + g3 + g4);
  }
}

extern "C" void kernel_launch(void* const* d_in, const int* in_sizes, int n_in,
                              void* d_out, int out_size, void* d_ws, size_t ws_size,
                              hipStream_t stream) {
  (void)in_sizes; (void)n_in; (void)out_size; (void)ws_size;
  const float* sf      = (const float*)d_in[0];
  const float* wf      = (const float*)d_in[1];
  const float* q_w     = (const float*)d_in[2];
  const float* q_b     = (const float*)d_in[3];
  const float* q_ln_w  = (const float*)d_in[4];
  const float* q_ln_b  = (const float*)d_in[5];
  const float* kv_w    = (const float*)d_in[6];
  const float* kv_b    = (const float*)d_in[7];
  const float* kv_ln_w = (const float*)d_in[8];
  const float* kv_ln_b = (const float*)d_in[9];
  const float* out_w   = (const float*)d_in[10];
  const float* out_b   = (const float*)d_in[11];
  float* out = (float*)d_out;

  // ---- workspace layout, ~168 MiB peak with phase aliasing ----
  char* p = (char*)d_ws;
  float* A  = (float*)p; p += 50331648;   // t_sf f32; later k1h|k1l|v1|k2|v1t|ml1
  float* B1 = (float*)p; p += 50331648;   // t_wf lo f32; later xall | att1 partials
  u16*   B2 = (u16*)p;   p += 25165824;   // t_wf hi bf16; later v2t; later y
  u16* q1h = (u16*)p; p += 6291456;       // (8,1024,384) bf16 hi
  u16* q1l = (u16*)p; p += 6291456;       // lo
  u16* q2  = (u16*)p; p += 18874368;      // (24,1024,384) bf16
  u16* v2  = (u16*)p; p += 18874368;      // (24,1024,384) bf16 row-major
  float2* stats1 = (float2*)p; p += 65536;    // 8192 float2 (unused now)
  float2* stats2 = (float2*)p;                // 24576 float2
  (void)stats1;
  // aliases inside A (t_sf dead after dwt_sf):
  u16* k1h = (u16*)A;
  u16* k1l = k1h + 3145728;
  u16* v1  = k1l + 3145728;
  u16* k2  = v1 + 3145728;
  u16* v1t = k2 + 9437184;            // (8,384,1024), ends at byte 44040192
  float2* ml1 = (float2*)((char*)A + 44040192);  // 2 x 8192 float2 = 128 KB (fits tail)
  u16* xall = (u16*)B1;               // (8,1024,1536) = 25165824 B
  float* part1 = (float*)((char*)B1 + 25165824);  // 2 x (8,1024,384) f32 = 25165824 B
  u16* v2t = B2;                      // (24,384,1024)
  u16* y   = B2;                      // (8,4096,384)

  // projections (MFMA) + LN; att1 score chain stays f32-precision via split
  gemm_mfma<1, float, float><<<dim3(3, 256), 256, 0, stream>>>(sf, q_w, q_b, A);
  ln_inplace<float><<<32768, 256, 0, stream>>>(A, q_ln_w, q_ln_b, 384);
  gemm_mfma<1, float, float><<<dim3(3, 256), 256, 0, stream>>>(wf, kv_w, kv_b, B1);
  gemm_mfma<0, float, u16><<<dim3(3, 256), 256, 0, stream>>>(wf, kv_w + 384 * 384, kv_b + 384, B2);
  ln_wf_split<<<32768, 256, 0, stream>>>(B1, B2, kv_ln_w, kv_ln_b);

  // DWT (dwt_sf must read A before k1/v1/k2/v1t overwrite it)
  dwt_sf<<<8192, 256, 0, stream>>>(A, q1h, q1l, q2);
  dwt_wf_split<<<8192, 256, 0, stream>>>(B1, B2, k1h, k1l, v1, k2, v2);

  // V transposes for MFMA B-operand layout
  transpose_rm<<<dim3(6, 16, 8), 256, 0, stream>>>(v1, v1t);
  transpose_rm<<<dim3(6, 16, 24), 256, 0, stream>>>(v2, v2t);  // overwrites dead t_wf-hi

  // attention (1D grids, XCD-swizzled inside the kernels)
  att2_stats<<<384, 256, 0, stream>>>(q2, k2, stats2, SCALE2);
  att1_fused<<<512, 256, 0, stream>>>(q1h, q1l, k1h, k1l, v1t, part1, ml1);
  att1_merge<<<8192, 192, 0, stream>>>(part1, ml1, xall);
  att2_accum<<<384, 256, 0, stream>>>(k2, q2, v2t, stats2, xall, SCALE2);

  // IWT + output projection (MFMA)
  iwt_y<<<8192, 256, 0, stream>>>(xall, y);
  gemm_mfma<0, u16, float><<<dim3(3, 256), 256, 0, stream>>>(y, out_w, out_b, out);
}

// Round 6
// 738.588 us; speedup vs baseline: 1.5067x; 1.0320x over previous
//
#include <hip/hip_runtime.h>
#include <hip/hip_bf16.h>

typedef unsigned short u16;
typedef unsigned int u32;
typedef __attribute__((ext_vector_type(8))) short short8;   // 8 bf16 (4 VGPRs)
typedef __attribute__((ext_vector_type(4))) float f32x4;    // MFMA C/D

#define MFMA_BF16(A, B, C) __builtin_amdgcn_mfma_f32_16x16x32_bf16(A, B, C, 0, 0, 0)

#define SCALE2 0.08838834764831845f
#define LNEPS 1e-5f

__device__ __forceinline__ float b2f(u16 u) {
  return __uint_as_float(((u32)u) << 16);
}
__device__ __forceinline__ u16 f2b(float f) {
  u32 x = __float_as_uint(f);
  return (u16)((x + 0x7fffu + ((x >> 16) & 1u)) >> 16);  // RNE
}
__device__ __forceinline__ float ldf(const float* p) { return *p; }
__device__ __forceinline__ float ldf(const u16* p) { return b2f(*p); }
__device__ __forceinline__ void stf(float* p, float v) { *p = v; }
__device__ __forceinline__ void stf(u16* p, float v) { *p = f2b(v); }

// ---------------- MFMA GEMM: out[m][n] = sum_k X[m][k]*W[n][k] + bias[n]
// K=384, N=384. Block 128Mx128N, 4 waves (2x2 of 64x64). SPLIT: hi/lo bf16
// 3-product f32-precision (X must be float).
template <int SPLIT, typename TX, typename TO>
__global__ __launch_bounds__(256) void gemm_mfma(
    const TX* __restrict__ X, const float* __restrict__ W,
    const float* __restrict__ bias, TO* __restrict__ out) {
  __shared__ __align__(16) u16 AH[128 * 40];
  __shared__ __align__(16) u16 BH[128 * 40];
  __shared__ __align__(16) u16 AL[SPLIT ? 128 * 40 : 8];
  __shared__ __align__(16) u16 BL[SPLIT ? 128 * 40 : 8];
  const int tid = threadIdx.x;
  const int w = tid >> 6, lane = tid & 63;
  const int t = lane & 15, qd = lane >> 4;
  const int wm = w & 1, wn = w >> 1;
  const int m0 = blockIdx.y * 128, n0 = blockIdx.x * 128;
  f32x4 acc[4][4];
#pragma unroll
  for (int i = 0; i < 4; ++i)
#pragma unroll
    for (int j = 0; j < 4; ++j) acc[i][j] = (f32x4){0.f, 0.f, 0.f, 0.f};
  for (int kt = 0; kt < 384; kt += 32) {
    // stage A (128x32) and B (128x32) with f32->bf16 convert
#pragma unroll
    for (int rep = 0; rep < 4; ++rep) {
      int e = tid + rep * 256;
      int m = e >> 3, k4 = (e & 7) * 4;
      if constexpr (sizeof(TX) == 4) {
        float4 v = *(const float4*)(X + (size_t)(m0 + m) * 384 + kt + k4);
        u16 h0 = f2b(v.x), h1 = f2b(v.y), h2 = f2b(v.z), h3 = f2b(v.w);
        u32 hp0 = (u32)h0 | ((u32)h1 << 16), hp1 = (u32)h2 | ((u32)h3 << 16);
        *(uint2*)&AH[m * 40 + k4] = make_uint2(hp0, hp1);
        if (SPLIT) {
          u16 l0 = f2b(v.x - b2f(h0)), l1 = f2b(v.y - b2f(h1));
          u16 l2 = f2b(v.z - b2f(h2)), l3 = f2b(v.w - b2f(h3));
          *(uint2*)&AL[m * 40 + k4] =
              make_uint2((u32)l0 | ((u32)l1 << 16), (u32)l2 | ((u32)l3 << 16));
        }
      } else {
        uint2 raw = *(const uint2*)(X + (size_t)(m0 + m) * 384 + kt + k4);
        *(uint2*)&AH[m * 40 + k4] = raw;
      }
      float4 wv = *(const float4*)(W + (size_t)(n0 + m) * 384 + kt + k4);
      u16 wh0 = f2b(wv.x), wh1 = f2b(wv.y), wh2 = f2b(wv.z), wh3 = f2b(wv.w);
      *(uint2*)&BH[m * 40 + k4] =
          make_uint2((u32)wh0 | ((u32)wh1 << 16), (u32)wh2 | ((u32)wh3 << 16));
      if (SPLIT) {
        u16 wl0 = f2b(wv.x - b2f(wh0)), wl1 = f2b(wv.y - b2f(wh1));
        u16 wl2 = f2b(wv.z - b2f(wh2)), wl3 = f2b(wv.w - b2f(wh3));
        *(uint2*)&BL[m * 40 + k4] =
            make_uint2((u32)wl0 | ((u32)wl1 << 16), (u32)wl2 | ((u32)wl3 << 16));
      }
    }
    __syncthreads();
    short8 af[4], bf[4], al[4], bl[4];
#pragma unroll
    for (int mi = 0; mi < 4; ++mi) {
      af[mi] = *(const short8*)&AH[(wm * 64 + mi * 16 + t) * 40 + qd * 8];
      bf[mi] = *(const short8*)&BH[(wn * 64 + mi * 16 + t) * 40 + qd * 8];
      if (SPLIT) {
        al[mi] = *(const short8*)&AL[(wm * 64 + mi * 16 + t) * 40 + qd * 8];
        bl[mi] = *(const short8*)&BL[(wn * 64 + mi * 16 + t) * 40 + qd * 8];
      }
    }
#pragma unroll
    for (int mi = 0; mi < 4; ++mi)
#pragma unroll
      for (int ni = 0; ni < 4; ++ni) {
        acc[mi][ni] = MFMA_BF16(af[mi], bf[ni], acc[mi][ni]);
        if (SPLIT) {
          acc[mi][ni] = MFMA_BF16(al[mi], bf[ni], acc[mi][ni]);
          acc[mi][ni] = MFMA_BF16(af[mi], bl[ni], acc[mi][ni]);
        }
      }
    __syncthreads();
  }
#pragma unroll
  for (int ni = 0; ni < 4; ++ni) {
    int n = n0 + wn * 64 + ni * 16 + t;
    float bv = bias[n];
#pragma unroll
    for (int mi = 0; mi < 4; ++mi)
#pragma unroll
      for (int r = 0; r < 4; ++r) {
        int m = m0 + wm * 64 + mi * 16 + qd * 4 + r;
        stf(&out[(size_t)m * 384 + n], acc[mi][ni][r] + bv);
      }
  }
}

// ---------------- row LayerNorm, in place (templated storage)
template <typename T>
__global__ __launch_bounds__(256) void ln_inplace(
    T* __restrict__ Tb, const float* __restrict__ w, const float* __restrict__ b, int N) {
  const int row = blockIdx.x, tid = threadIdx.x;
  T* Tr = Tb + (size_t)row * N;
  float vals[3];
  float s = 0.f, ss = 0.f;
  int nv = 0;
  for (int i = tid; i < N; i += 256) {
    float v = ldf(&Tr[i]);
    vals[nv++] = v;
    s += v; ss += v * v;
  }
#pragma unroll
  for (int mk = 32; mk; mk >>= 1) { s += __shfl_xor(s, mk); ss += __shfl_xor(ss, mk); }
  __shared__ float red[8];
  if ((tid & 63) == 0) { red[tid >> 6] = s; red[4 + (tid >> 6)] = ss; }
  __syncthreads();
  s = red[0] + red[1] + red[2] + red[3];
  ss = red[4] + red[5] + red[6] + red[7];
  float inv = 1.f / (float)N;
  float mean = s * inv;
  float var = fmaxf(ss * inv - mean * mean, 0.f);
  float rstd = rsqrtf(var + LNEPS);
  nv = 0;
  for (int i = tid; i < N; i += 256) {
    float v = (vals[nv++] - mean) * rstd * w[i] + b[i];
    stf(&Tr[i], v);
  }
}

// ---------------- LN over split storage: lo = f32 chans 0..383, hi = bf16 chans 384..767
__global__ __launch_bounds__(256) void ln_wf_split(
    float* __restrict__ lo, u16* __restrict__ hi,
    const float* __restrict__ w, const float* __restrict__ b) {
  const int row = blockIdx.x, tid = threadIdx.x;
  float* L = lo + (size_t)row * 384;
  u16* H = hi + (size_t)row * 384;
  float vals[3];
  float s = 0.f, ss = 0.f;
  int nv = 0;
  for (int i = tid; i < 768; i += 256) {
    float v = (i < 384) ? L[i] : b2f(H[i - 384]);
    vals[nv++] = v;
    s += v; ss += v * v;
  }
#pragma unroll
  for (int mk = 32; mk; mk >>= 1) { s += __shfl_xor(s, mk); ss += __shfl_xor(ss, mk); }
  __shared__ float red[8];
  if ((tid & 63) == 0) { red[tid >> 6] = s; red[4 + (tid >> 6)] = ss; }
  __syncthreads();
  s = red[0] + red[1] + red[2] + red[3];
  ss = red[4] + red[5] + red[6] + red[7];
  float mean = s * (1.f / 768.f);
  float var = fmaxf(ss * (1.f / 768.f) - mean * mean, 0.f);
  float rstd = rsqrtf(var + LNEPS);
  nv = 0;
  for (int i = 0 + tid; i < 768; i += 256) {
    float v = (vals[nv++] - mean) * rstd * w[i] + b[i];
    if (i < 384) L[i] = v; else H[i - 384] = f2b(v);
  }
}

// ---------------- DWT sf: t_sf f32 -> q1 split-bf16 (hi+lo), q2 bf16 (3 heads)
__global__ __launch_bounds__(256) void dwt_sf(
    const float* __restrict__ T, u16* __restrict__ q1h, u16* __restrict__ q1l,
    u16* __restrict__ q2) {
  const int blk = blockIdx.x;
  const int b = blk >> 10, pos = blk & 1023;
  const int i = pos >> 5, j = pos & 31;
  const int p00 = (i * 2) * 64 + j * 2;
  const float* base = T + (size_t)b * 4096 * 384;
  for (int ch = threadIdx.x; ch < 384; ch += 256) {
    float a  = base[(size_t)p00 * 384 + ch];
    float cc = base[(size_t)(p00 + 1) * 384 + ch];
    float bb = base[(size_t)(p00 + 64) * 384 + ch];
    float dd = base[(size_t)(p00 + 65) * 384 + ch];
    float s0 = 0.5f * ( a + bb + cc + dd);
    float s1 = 0.5f * (-a - bb + cc + dd);
    float s2 = 0.5f * (-a + bb - cc + dd);
    float s3 = 0.5f * ( a - bb - cc + dd);
    size_t po = (size_t)(b * 1024 + pos) * 384 + ch;
    u16 h = f2b(s0);
    q1h[po] = h;
    q1l[po] = f2b(s0 - b2f(h));
    q2[(size_t)((b * 3 + 0) * 1024 + pos) * 384 + ch] = f2b(s1);
    q2[(size_t)((b * 3 + 1) * 1024 + pos) * 384 + ch] = f2b(s2);
    q2[(size_t)((b * 3 + 2) * 1024 + pos) * 384 + ch] = f2b(s3);
  }
}

// ---------------- DWT wf (split input): lo f32, hi bf16 -> k1 split-bf16, v1, k2, v2
__global__ __launch_bounds__(256) void dwt_wf_split(
    const float* __restrict__ lo, const u16* __restrict__ hi,
    u16* __restrict__ k1h, u16* __restrict__ k1l, u16* __restrict__ v1,
    u16* __restrict__ k2, u16* __restrict__ v2) {
  const int blk = blockIdx.x;
  const int b = blk >> 10, pos = blk & 1023;
  const int i = pos >> 5, j = pos & 31;
  const int p00 = (i * 2) * 64 + j * 2;
  for (int ch = threadIdx.x; ch < 768; ch += 256) {
    float a, bb, cc, dd;
    if (ch < 384) {
      const float* base = lo + (size_t)b * 4096 * 384;
      a  = base[(size_t)p00 * 384 + ch];
      cc = base[(size_t)(p00 + 1) * 384 + ch];
      bb = base[(size_t)(p00 + 64) * 384 + ch];
      dd = base[(size_t)(p00 + 65) * 384 + ch];
    } else {
      const u16* base = hi + (size_t)b * 4096 * 384;
      int c = ch - 384;
      a  = b2f(base[(size_t)p00 * 384 + c]);
      cc = b2f(base[(size_t)(p00 + 1) * 384 + c]);
      bb = b2f(base[(size_t)(p00 + 64) * 384 + c]);
      dd = b2f(base[(size_t)(p00 + 65) * 384 + c]);
    }
    float s0 = 0.5f * ( a + bb + cc + dd);
    float s1 = 0.5f * (-a - bb + cc + dd);
    float s2 = 0.5f * (-a + bb - cc + dd);
    float s3 = 0.5f * ( a - bb - cc + dd);
    if (ch < 384) {
      size_t po = (size_t)(b * 1024 + pos) * 384 + ch;
      u16 h = f2b(s0);
      k1h[po] = h;
      k1l[po] = f2b(s0 - b2f(h));
      v1[po] = f2b(s2);
      k2[(size_t)((b * 3 + 1) * 1024 + pos) * 384 + ch] = f2b(s1);
      v2[(size_t)((b * 3 + 1) * 1024 + pos) * 384 + ch] = f2b(s3);
    } else {
      int c = ch - 384;
      k2[(size_t)((b * 3 + 0) * 1024 + pos) * 384 + c] = f2b(s0);
      k2[(size_t)((b * 3 + 2) * 1024 + pos) * 384 + c] = f2b(s1);
      v2[(size_t)((b * 3 + 0) * 1024 + pos) * 384 + c] = f2b(s2);
      v2[(size_t)((b * 3 + 2) * 1024 + pos) * 384 + c] = f2b(s3);
    }
  }
}

// ---------------- transpose [bh][1024][384] -> [bh][384][1024]
__global__ __launch_bounds__(256) void transpose_rm(
    const u16* __restrict__ in, u16* __restrict__ out) {
  __shared__ u16 T[64][65];
  const int tid = threadIdx.x;
  const int bh = blockIdx.z, r0 = blockIdx.y * 64, c0 = blockIdx.x * 64;
  const u16* ip = in + ((size_t)bh * 1024 + r0) * 384 + c0;
  for (int i = tid; i < 2048; i += 256) {
    int r = i >> 5, c2 = i & 31;
    u32 v = *(const u32*)(ip + (size_t)r * 384 + c2 * 2);
    T[c2 * 2][r] = (u16)v;
    T[c2 * 2 + 1][r] = (u16)(v >> 16);
  }
  __syncthreads();
  u16* op = out + ((size_t)bh * 384 + c0) * 1024 + r0;
  for (int i = tid; i < 2048; i += 256) {
    int c = i >> 5, r2 = i & 31;
    u32 v = (u32)T[c][r2 * 2] | ((u32)T[c][r2 * 2 + 1] << 16);
    *(u32*)(op + (size_t)c * 1024 + r2 * 2) = v;
  }
}

// att2 (24 heads x 16 blocks of 64 own rows): XCD x gets heads {x, x+8, x+16}.
__device__ __forceinline__ void xcd24v2(int L, int& bh, int& o0) {
  int s = L >> 3;
  bh = (s >> 4) * 8 + (L & 7);
  o0 = (s & 15) * 64;
}

// ---------------- att2 stats v3: block owns 64 q-rows (wave w -> 16 rows).
// Stream k2 staged to LDS (dbuf, 1 barrier/iter). SWAPPED scores: S^T =
// mfma(K_frag, Q_frag) puts the stream axis in-register (r) and qd-lanes, so
// the softmax reduce is 7 in-lane fmax + 2 shfl_xor instead of 4-step 16-lane
// chains. State (m,l) is per own-row t, fully in-lane.
__global__ __launch_bounds__(256) void att2_stats(
    const u16* __restrict__ q, const u16* __restrict__ k,
    float2* __restrict__ stats, float scale) {
  __shared__ __align__(16) u16 S[2][12 * 32 * 40];  // 61440 B, stride-40 pad
  const int tid = threadIdx.x, w = tid >> 6, lane = tid & 63;
  const int t = lane & 15, qd = lane >> 4;
  int bh, o0;
  xcd24v2(blockIdx.x, bh, o0);
  short8 Ah[12];
  {
    const u16* qp = q + ((size_t)bh * 1024 + o0 + w * 16 + t) * 384 + qd * 8;
#pragma unroll
    for (int ks = 0; ks < 12; ++ks) Ah[ks] = *(const short8*)(qp + ks * 32);
  }
  float m = -1e30f, l = 0.f;
  const u16* kb = k + (size_t)bh * 1024 * 384;
  int buf = 0;
  for (int st = 0; st < 32; ++st) {
    // stage stream rows st*32..+32: unit = 8 u16; [row][c8] -> S[ks][row][qq*8]
#pragma unroll
    for (int i = 0; i < 6; ++i) {
      int u = tid + i * 256;
      int r = u / 48, c8 = u % 48;
      int ks = c8 >> 2, qq = c8 & 3;
      uint4 v = *(const uint4*)(kb + (size_t)(st * 32 + r) * 384 + c8 * 8);
      *(uint4*)&S[buf][(ks * 32 + r) * 40 + qq * 8] = v;
    }
    __syncthreads();
    // swapped: A = stream frags (rows t and 16+t), B = own Q regs
    f32x4 Sg0 = {0.f,0.f,0.f,0.f}, Sg1 = {0.f,0.f,0.f,0.f};
#pragma unroll
    for (int ks = 0; ks < 12; ++ks) {
      short8 A0 = *(const short8*)&S[buf][(ks * 32 + t) * 40 + qd * 8];
      short8 A1 = *(const short8*)&S[buf][(ks * 32 + 16 + t) * 40 + qd * 8];
      Sg0 = MFMA_BF16(A0, Ah[ks], Sg0);
      Sg1 = MFMA_BF16(A1, Ah[ks], Sg1);
    }
    // lane (t,qd): Sg0[r] = S^T[stream qd*4+r][own t], Sg1: stream 16+qd*4+r
    float s0 = Sg0[0]*scale, s1 = Sg0[1]*scale, s2 = Sg0[2]*scale, s3 = Sg0[3]*scale;
    float s4 = Sg1[0]*scale, s5 = Sg1[1]*scale, s6 = Sg1[2]*scale, s7 = Sg1[3]*scale;
    float mx = fmaxf(fmaxf(fmaxf(s0,s1),fmaxf(s2,s3)),fmaxf(fmaxf(s4,s5),fmaxf(s6,s7)));
    mx = fmaxf(mx, __shfl_xor(mx, 16));
    mx = fmaxf(mx, __shfl_xor(mx, 32));
    float nm = fmaxf(m, mx);
    float e = __expf(s0-nm)+__expf(s1-nm)+__expf(s2-nm)+__expf(s3-nm)
            + __expf(s4-nm)+__expf(s5-nm)+__expf(s6-nm)+__expf(s7-nm);
    e += __shfl_xor(e, 16);
    e += __shfl_xor(e, 32);
    l = l * __expf(m - nm) + e;
    m = nm;
    buf ^= 1;
  }
  if (qd == 0)
    stats[(size_t)bh * 1024 + o0 + w * 16 + t] = make_float2(m, 1.f / l);
}

// ---------------- att2 accumulate v2 (transposed gather): block owns 64 k2
// rows (wave w -> 16 output rows x ALL 384 dims, acc[24]). Stream q2 tile (32
// rows) + V tile (384x32) staged to LDS once per block; single-buffer, two
// barriers/iter. P is wave-private LDS (no cross-wave barrier).
__global__ __launch_bounds__(256, 2) void att2_accum(
    const u16* __restrict__ own, const u16* __restrict__ str,
    const u16* __restrict__ vt, const float2* __restrict__ stats,
    u16* __restrict__ xall, float scale) {
  __shared__ __align__(16) u16 SQ[12 * 32 * 40];   // 30720 B
  __shared__ __align__(16) u16 SV[24 * 16 * 40];   // 30720 B
  __shared__ __align__(16) u16 P[4][16 * 40];      // 5120 B, wave-private
  const int tid = threadIdx.x, w = tid >> 6, lane = tid & 63;
  const int t = lane & 15, qd = lane >> 4;
  int bh, o0;
  xcd24v2(blockIdx.x, bh, o0);
  short8 Ah[12];
  {
    const u16* op = own + ((size_t)bh * 1024 + o0 + w * 16 + t) * 384 + qd * 8;
#pragma unroll
    for (int ks = 0; ks < 12; ++ks) Ah[ks] = *(const short8*)(op + ks * 32);
  }
  f32x4 acc[24];
#pragma unroll
  for (int i = 0; i < 24; ++i) acc[i] = (f32x4){0.f, 0.f, 0.f, 0.f};
  const u16* sb = str + (size_t)bh * 1024 * 384;
  const u16* vb = vt + (size_t)bh * 384 * 1024;
  u16* Pw = &P[w][0];
  for (int st = 0; st < 32; ++st) {
    __syncthreads();  // all waves done reading SQ/SV from previous iter
#pragma unroll
    for (int i = 0; i < 6; ++i) {
      int u = tid + i * 256;
      int r = u / 48, c8 = u % 48;
      int ks = c8 >> 2, qq = c8 & 3;
      uint4 v = *(const uint4*)(sb + (size_t)(st * 32 + r) * 384 + c8 * 8);
      *(uint4*)&SQ[(ks * 32 + r) * 40 + qq * 8] = v;
    }
#pragma unroll
    for (int i = 0; i < 6; ++i) {
      int u = tid + i * 256;
      int d = u >> 2, cq = u & 3;
      uint4 v = *(const uint4*)(vb + (size_t)d * 1024 + st * 32 + cq * 8);
      *(uint4*)&SV[d * 40 + cq * 8] = v;
    }
    float2 cs0 = stats[(size_t)bh * 1024 + st * 32 + t];
    float2 cs1 = stats[(size_t)bh * 1024 + st * 32 + 16 + t];
    __syncthreads();  // staging visible
    f32x4 Sa0 = {0.f,0.f,0.f,0.f}, Sb0 = {0.f,0.f,0.f,0.f};
    f32x4 Sa1 = {0.f,0.f,0.f,0.f}, Sb1 = {0.f,0.f,0.f,0.f};
#pragma unroll
    for (int ks = 0; ks < 12; ks += 2) {
      short8 B00 = *(const short8*)&SQ[(ks * 32 + t) * 40 + qd * 8];
      short8 B01 = *(const short8*)&SQ[((ks + 1) * 32 + t) * 40 + qd * 8];
      short8 B10 = *(const short8*)&SQ[(ks * 32 + 16 + t) * 40 + qd * 8];
      short8 B11 = *(const short8*)&SQ[((ks + 1) * 32 + 16 + t) * 40 + qd * 8];
      Sa0 = MFMA_BF16(Ah[ks], B00, Sa0);
      Sb0 = MFMA_BF16(Ah[ks + 1], B01, Sb0);
      Sa1 = MFMA_BF16(Ah[ks], B10, Sa1);
      Sb1 = MFMA_BF16(Ah[ks + 1], B11, Sb1);
    }
#pragma unroll
    for (int r = 0; r < 4; ++r) {
      float p0 = __expf((Sa0[r] + Sb0[r]) * scale - cs0.x) * cs0.y;
      float p1 = __expf((Sa1[r] + Sb1[r]) * scale - cs1.x) * cs1.y;
      Pw[(qd * 4 + r) * 40 + t] = f2b(p0);
      Pw[(qd * 4 + r) * 40 + 16 + t] = f2b(p1);
    }
    // wave-private P: compiler inserts lgkmcnt wait before the read
    short8 Pa = *(const short8*)&Pw[t * 40 + qd * 8];
#pragma unroll
    for (int nj = 0; nj < 24; ++nj) {
      short8 Vf = *(const short8*)&SV[(nj * 16 + t) * 40 + qd * 8];
      acc[nj] = MFMA_BF16(Pa, Vf, acc[nj]);
    }
  }
  const int b_out = bh / 3, off = (1 + bh % 3) * 384;
#pragma unroll
  for (int nj = 0; nj < 24; ++nj)
#pragma unroll
    for (int r = 0; r < 4; ++r) {
      int row = o0 + w * 16 + qd * 4 + r;
      int d = nj * 16 + t;
      xall[((size_t)b_out * 1024 + row) * 1536 + off + d] = f2b(acc[nj][r]);
    }
}

// ---------------- att1 fused flash v2 (split-K over stream; swapped QK^T).
// Grid 512 = (sseg 0/1) x 32 row-blocks x 8 heads; 2 blocks/CU. Block owns 32
// q-rows; waves = (row-group wr x dim-half dh). Each wave computes the FULL
// softmax for its 16 rows (redundant across the dh pair -> NO cross-wave
// exchange, wave-private P). Stream in 16-row tiles, K double-buffered in LDS
// -> ONE barrier/iter. Swapped scores S^T = mfma(K,Q): stream axis lands
// in-register; reduce = 3 fmax + 2 shfl_xor. PV every 2 tiles (K=32) with
// pair-deferred max; acc/l rescaled at each PV boundary. Emits unnormalized
// f32 partial + (m,l); att1_merge combines segments.
__global__ __launch_bounds__(256, 2) void att1_fused(
    const u16* __restrict__ qh, const u16* __restrict__ ql,
    const u16* __restrict__ kh, const u16* __restrict__ kl,
    const u16* __restrict__ vt, float* __restrict__ part,
    float2* __restrict__ ml) {
  __shared__ __align__(16) u16 KH[2][12 * 640];   // 30720 B
  __shared__ __align__(16) u16 KL[2][12 * 640];   // 30720 B
  __shared__ __align__(16) u16 P[4][16 * 32];     // 4096 B, wave-private
  const int tid = threadIdx.x, w = tid >> 6, lane = tid & 63;
  const int t = lane & 15, qd = lane >> 4;
  const int wr = w & 1, dh = w >> 1;
  const int bh = blockIdx.x & 7;
  const int q = blockIdx.x >> 3;
  const int o0 = (q & 31) * 32;
  const int sseg = q >> 5;
  const int sbase = sseg * 512;
  // own Q fragments (MFMA B-operand): row o0+wr*16+t, chans ks*32+qd*8
  short8 Ah[12], Al[12];
  {
    const u16* qp  = qh + ((size_t)bh * 1024 + o0 + wr * 16 + t) * 384 + qd * 8;
    const u16* qp2 = ql + ((size_t)bh * 1024 + o0 + wr * 16 + t) * 384 + qd * 8;
#pragma unroll
    for (int ks = 0; ks < 12; ++ks) {
      Ah[ks] = *(const short8*)(qp + ks * 32);
      Al[ks] = *(const short8*)(qp2 + ks * 32);
    }
  }
  f32x4 acc[12];
#pragma unroll
  for (int i = 0; i < 12; ++i) acc[i] = (f32x4){0.f, 0.f, 0.f, 0.f};
  float m = 0.f, l = 0.f, mxp = -1e30f;  // m initialized from tile 0
  const u16* khb = kh + ((size_t)bh * 1024 + sbase) * 384;
  const u16* klb = kl + ((size_t)bh * 1024 + sbase) * 384;
  u16* Pw = &P[w][0];
  // prologue: stage stream tile 0 (16 rows) into buf 0
#pragma unroll
  for (int i = 0; i < 3; ++i) {
    int u = tid + i * 256;
    int r = u / 48, c8 = u % 48;
    int ks = c8 >> 2, j8 = c8 & 3;
    *(uint4*)&KH[0][ks * 640 + r * 40 + j8 * 8] =
        *(const uint4*)(khb + (size_t)r * 384 + c8 * 8);
    *(uint4*)&KL[0][ks * 640 + r * 40 + j8 * 8] =
        *(const uint4*)(klb + (size_t)r * 384 + c8 * 8);
  }
  __syncthreads();
  short8 Vr[12];
  for (int st = 0; st < 32; ++st) {
    const int buf = st & 1;
    if (!(st & 1)) {
      // V fragments for this tile PAIR (stream rows st*16 .. +32), 2 iters early
#pragma unroll
      for (int nj = 0; nj < 12; ++nj)
        Vr[nj] = *(const short8*)(vt +
            ((size_t)bh * 384 + dh * 192 + nj * 16 + t) * 1024 +
            sbase + st * 16 + qd * 8);
    }
    if (st < 31) {
      // stage next tile into the other buffer (visible after this iter's barrier)
      const int nb = buf ^ 1;
      const u16* kh2 = khb + (size_t)(st + 1) * 16 * 384;
      const u16* kl2 = klb + (size_t)(st + 1) * 16 * 384;
#pragma unroll
      for (int i = 0; i < 3; ++i) {
        int u = tid + i * 256;
        int r = u / 48, c8 = u % 48;
        int ks = c8 >> 2, j8 = c8 & 3;
        *(uint4*)&KH[nb][ks * 640 + r * 40 + j8 * 8] =
            *(const uint4*)(kh2 + (size_t)r * 384 + c8 * 8);
        *(uint4*)&KL[nb][ks * 640 + r * 40 + j8 * 8] =
            *(const uint4*)(kl2 + (size_t)r * 384 + c8 * 8);
      }
    }
    // swapped scores: A = stream K frag (LDS), B = own Q regs; 3 f32 chains
    f32x4 Shh = {0.f,0.f,0.f,0.f}, Slh = {0.f,0.f,0.f,0.f}, Shl = {0.f,0.f,0.f,0.f};
#pragma unroll
    for (int ks = 0; ks < 12; ++ks) {
      short8 Bh = *(const short8*)&KH[buf][ks * 640 + t * 40 + qd * 8];
      short8 Bl = *(const short8*)&KL[buf][ks * 640 + t * 40 + qd * 8];
      Shh = MFMA_BF16(Bh, Ah[ks], Shh);
      Slh = MFMA_BF16(Bh, Al[ks], Slh);
      Shl = MFMA_BF16(Bl, Ah[ks], Shl);
    }
    // lane (t,qd): s[r] = S^T[stream qd*4+r][own t]
    float s0 = Shh[0] + Slh[0] + Shl[0];
    float s1 = Shh[1] + Slh[1] + Shl[1];
    float s2 = Shh[2] + Slh[2] + Shl[2];
    float s3 = Shh[3] + Slh[3] + Shl[3];
    float mx = fmaxf(fmaxf(s0, s1), fmaxf(s2, s3));
    mx = fmaxf(mx, __shfl_xor(mx, 16));
    mx = fmaxf(mx, __shfl_xor(mx, 32));
    if (st == 0) m = mx;
    mxp = fmaxf(mxp, mx);
    // deferred max: P = exp(s - m_boundary); bounded by exp(pair growth)
    float p0 = __expf(s0 - m), p1 = __expf(s1 - m);
    float p2 = __expf(s2 - m), p3 = __expf(s3 - m);
    float e = p0 + p1 + p2 + p3;
    e += __shfl_xor(e, 16);
    e += __shfl_xor(e, 32);
    l += e;
    Pw[t * 32 + buf * 16 + qd * 4 + 0] = f2b(p0);
    Pw[t * 32 + buf * 16 + qd * 4 + 1] = f2b(p1);
    Pw[t * 32 + buf * 16 + qd * 4 + 2] = f2b(p2);
    Pw[t * 32 + buf * 16 + qd * 4 + 3] = f2b(p3);
    if (st & 1) {
      // PV over the pair (old-m units); wave-private P, lgkm auto-wait
      short8 Pa = *(const short8*)&Pw[t * 32 + qd * 8];
#pragma unroll
      for (int nj = 0; nj < 12; ++nj) acc[nj] = MFMA_BF16(Pa, Vr[nj], acc[nj]);
      // boundary: fold pair max into running max; rescale l and acc
      float mnew = fmaxf(m, mxp);
      float sc = __expf(m - mnew);
      l *= sc; m = mnew; mxp = -1e30f;
      float f0 = __shfl(sc, qd * 4 + 0);
      float f1 = __shfl(sc, qd * 4 + 1);
      float f2v = __shfl(sc, qd * 4 + 2);
      float f3 = __shfl(sc, qd * 4 + 3);
#pragma unroll
      for (int nj = 0; nj < 12; ++nj) {
        acc[nj][0] *= f0; acc[nj][1] *= f1;
        acc[nj][2] *= f2v; acc[nj][3] *= f3;
      }
    }
    __syncthreads();
  }
  // store unnormalized f32 partial + per-row (m,l) for the merge kernel
  float* pb = part + ((size_t)(sseg * 8 + bh) * 1024 + o0 + wr * 16) * 384;
#pragma unroll
  for (int r = 0; r < 4; ++r) {
    int row = qd * 4 + r;
#pragma unroll
    for (int nj = 0; nj < 12; ++nj)
      pb[(size_t)row * 384 + dh * 192 + nj * 16 + t] = acc[nj][r];
  }
  if (dh == 0 && qd == 0)
    ml[sseg * 8192 + bh * 1024 + o0 + wr * 16 + t] = make_float2(m, l);
}

// ---------------- att1 merge: combine the two stream-segment partials.
// out[row][d] = (p0*e^(m0-M) + p1*e^(m1-M)) / (l0*e^(m0-M) + l1*e^(m1-M))
__global__ __launch_bounds__(192) void att1_merge(
    const float* __restrict__ part, const float2* __restrict__ ml,
    u16* __restrict__ xall) {
  const int rb = blockIdx.x;  // bh*1024 + row, 0..8191
  float2 a = ml[rb];
  float2 b = ml[8192 + rb];
  float M = fmaxf(a.x, b.x);
  float e0 = __expf(a.x - M), e1 = __expf(b.x - M);
  float inv = 1.f / (a.y * e0 + b.y * e1);
  const float* p0 = part + (size_t)rb * 384;
  const float* p1 = part + (size_t)(8192 + rb) * 384;
  u16* xr = xall + (size_t)rb * 1536;
  for (int ch = threadIdx.x; ch < 384; ch += 192)
    xr[ch] = f2b((p0[ch] * e0 + p1[ch] * e1) * inv);
}

// ---------------- IWT: xall (B,1024,1536) -> y (B,4096,384)
__global__ __launch_bounds__(256) void iwt_y(const u16* __restrict__ xall, u16* __restrict__ y) {
  const int blk = blockIdx.x;
  const int b = blk >> 10, pos = blk & 1023;
  const int i = pos >> 5, j = pos & 31;
  const u16* xr = xall + (size_t)(b * 1024 + pos) * 1536;
  u16* yb = y + (size_t)b * 4096 * 384;
  const int p00 = (i * 2) * 64 + j * 2;
  for (int c = threadIdx.x; c < 384; c += 256) {
    float g1 = 0.5f * b2f(xr[c]);
    float g2 = 0.5f * b2f(xr[c + 384]);
    float g3 = 0.5f * b2f(xr[c + 768]);
    float g4 = 0.5f * b2f(xr[c + 1152]);
    yb[(size_t)p00 * 384 + c]        = f2b(g1 - g2 - g3 + g4);
    yb[(size_t)(p00 + 64) * 384 + c] = f2b(g1 - g2 + g3 - g4);
    yb[(size_t)(p00 + 1) * 384 + c]  = f2b(g1 + g2 - g3 - g4);
    yb[(size_t)(p00 + 65) * 384 + c] = f2b(g1 + g2 + g3 + g4);
  }
}

extern "C" void kernel_launch(void* const* d_in, const int* in_sizes, int n_in,
                              void* d_out, int out_size, void* d_ws, size_t ws_size,
                              hipStream_t stream) {
  (void)in_sizes; (void)n_in; (void)out_size; (void)ws_size;
  const float* sf      = (const float*)d_in[0];
  const float* wf      = (const float*)d_in[1];
  const float* q_w     = (const float*)d_in[2];
  const float* q_b     = (const float*)d_in[3];
  const float* q_ln_w  = (const float*)d_in[4];
  const float* q_ln_b  = (const float*)d_in[5];
  const float* kv_w    = (const float*)d_in[6];
  const float* kv_b    = (const float*)d_in[7];
  const float* kv_ln_w = (const float*)d_in[8];
  const float* kv_ln_b = (const float*)d_in[9];
  const float* out_w   = (const float*)d_in[10];
  const float* out_b   = (const float*)d_in[11];
  float* out = (float*)d_out;

  // ---- workspace layout, ~168 MiB peak with phase aliasing ----
  char* p = (char*)d_ws;
  float* A  = (float*)p; p += 50331648;   // t_sf f32; later k1h|k1l|v1|k2|v1t|ml1
  float* B1 = (float*)p; p += 50331648;   // t_wf lo f32; later xall | att1 partials
  u16*   B2 = (u16*)p;   p += 25165824;   // t_wf hi bf16; later v2t; later y
  u16* q1h = (u16*)p; p += 6291456;       // (8,1024,384) bf16 hi
  u16* q1l = (u16*)p; p += 6291456;       // lo
  u16* q2  = (u16*)p; p += 18874368;      // (24,1024,384) bf16
  u16* v2  = (u16*)p; p += 18874368;      // (24,1024,384) bf16 row-major
  float2* stats1 = (float2*)p; p += 65536;    // 8192 float2 (unused now)
  float2* stats2 = (float2*)p;                // 24576 float2
  (void)stats1;
  // aliases inside A (t_sf dead after dwt_sf):
  u16* k1h = (u16*)A;
  u16* k1l = k1h + 3145728;
  u16* v1  = k1l + 3145728;
  u16* k2  = v1 + 3145728;
  u16* v1t = k2 + 9437184;            // (8,384,1024), ends at byte 44040192
  float2* ml1 = (float2*)((char*)A + 44040192);  // 2 x 8192 float2 = 128 KB (fits tail)
  u16* xall = (u16*)B1;               // (8,1024,1536) = 25165824 B
  float* part1 = (float*)((char*)B1 + 25165824);  // 2 x (8,1024,384) f32 = 25165824 B
  u16* v2t = B2;                      // (24,384,1024)
  u16* y   = B2;                      // (8,4096,384)

  // projections (MFMA) + LN; att1 score chain stays f32-precision via split
  gemm_mfma<1, float, float><<<dim3(3, 256), 256, 0, stream>>>(sf, q_w, q_b, A);
  ln_inplace<float><<<32768, 256, 0, stream>>>(A, q_ln_w, q_ln_b, 384);
  gemm_mfma<1, float, float><<<dim3(3, 256), 256, 0, stream>>>(wf, kv_w, kv_b, B1);
  gemm_mfma<0, float, u16><<<dim3(3, 256), 256, 0, stream>>>(wf, kv_w + 384 * 384, kv_b + 384, B2);
  ln_wf_split<<<32768, 256, 0, stream>>>(B1, B2, kv_ln_w, kv_ln_b);

  // DWT (dwt_sf must read A before k1/v1/k2/v1t overwrite it)
  dwt_sf<<<8192, 256, 0, stream>>>(A, q1h, q1l, q2);
  dwt_wf_split<<<8192, 256, 0, stream>>>(B1, B2, k1h, k1l, v1, k2, v2);

  // V transposes for MFMA B-operand layout
  transpose_rm<<<dim3(6, 16, 8), 256, 0, stream>>>(v1, v1t);
  transpose_rm<<<dim3(6, 16, 24), 256, 0, stream>>>(v2, v2t);  // overwrites dead t_wf-hi

  // attention (1D grids, XCD-swizzled inside the kernels)
  att2_stats<<<384, 256, 0, stream>>>(q2, k2, stats2, SCALE2);
  att1_fused<<<512, 256, 0, stream>>>(q1h, q1l, k1h, k1l, v1t, part1, ml1);
  att1_merge<<<8192, 192, 0, stream>>>(part1, ml1, xall);
  att2_accum<<<384, 256, 0, stream>>>(k2, q2, v2t, stats2, xall, SCALE2);

  // IWT + output projection (MFMA)
  iwt_y<<<8192, 256, 0, stream>>>(xall, y);
  gemm_mfma<0, u16, float><<<dim3(3, 256), 256, 0, stream>>>(y, out_w, out_b, out);
}

// Round 7
// 731.410 us; speedup vs baseline: 1.5215x; 1.0098x over previous
//
#include <hip/hip_runtime.h>
#include <hip/hip_bf16.h>

typedef unsigned short u16;
typedef unsigned int u32;
typedef __attribute__((ext_vector_type(8))) short short8;   // 8 bf16 (4 VGPRs)
typedef __attribute__((ext_vector_type(4))) float f32x4;    // MFMA C/D

#define MFMA_BF16(A, B, C) __builtin_amdgcn_mfma_f32_16x16x32_bf16(A, B, C, 0, 0, 0)

#define SCALE2 0.08838834764831845f
#define LNEPS 1e-5f

__device__ __forceinline__ float b2f(u16 u) {
  return __uint_as_float(((u32)u) << 16);
}
__device__ __forceinline__ u16 f2b(float f) {
  u32 x = __float_as_uint(f);
  return (u16)((x + 0x7fffu + ((x >> 16) & 1u)) >> 16);  // RNE
}
__device__ __forceinline__ float ldf(const float* p) { return *p; }
__device__ __forceinline__ float ldf(const u16* p) { return b2f(*p); }
__device__ __forceinline__ void stf(float* p, float v) { *p = v; }
__device__ __forceinline__ void stf(u16* p, float v) { *p = f2b(v); }

// ---------------- MFMA GEMM: out[m][n] = sum_k X[m][k]*W[n][k] + bias[n]
// K=384, N=384. Block 128Mx128N, 4 waves (2x2 of 64x64). SPLIT: hi/lo bf16
// 3-product f32-precision (X must be float).
template <int SPLIT, typename TX, typename TO>
__global__ __launch_bounds__(256) void gemm_mfma(
    const TX* __restrict__ X, const float* __restrict__ W,
    const float* __restrict__ bias, TO* __restrict__ out) {
  __shared__ __align__(16) u16 AH[128 * 40];
  __shared__ __align__(16) u16 BH[128 * 40];
  __shared__ __align__(16) u16 AL[SPLIT ? 128 * 40 : 8];
  __shared__ __align__(16) u16 BL[SPLIT ? 128 * 40 : 8];
  const int tid = threadIdx.x;
  const int w = tid >> 6, lane = tid & 63;
  const int t = lane & 15, qd = lane >> 4;
  const int wm = w & 1, wn = w >> 1;
  const int m0 = blockIdx.y * 128, n0 = blockIdx.x * 128;
  f32x4 acc[4][4];
#pragma unroll
  for (int i = 0; i < 4; ++i)
#pragma unroll
    for (int j = 0; j < 4; ++j) acc[i][j] = (f32x4){0.f, 0.f, 0.f, 0.f};
  for (int kt = 0; kt < 384; kt += 32) {
    // stage A (128x32) and B (128x32) with f32->bf16 convert
#pragma unroll
    for (int rep = 0; rep < 4; ++rep) {
      int e = tid + rep * 256;
      int m = e >> 3, k4 = (e & 7) * 4;
      if constexpr (sizeof(TX) == 4) {
        float4 v = *(const float4*)(X + (size_t)(m0 + m) * 384 + kt + k4);
        u16 h0 = f2b(v.x), h1 = f2b(v.y), h2 = f2b(v.z), h3 = f2b(v.w);
        u32 hp0 = (u32)h0 | ((u32)h1 << 16), hp1 = (u32)h2 | ((u32)h3 << 16);
        *(uint2*)&AH[m * 40 + k4] = make_uint2(hp0, hp1);
        if (SPLIT) {
          u16 l0 = f2b(v.x - b2f(h0)), l1 = f2b(v.y - b2f(h1));
          u16 l2 = f2b(v.z - b2f(h2)), l3 = f2b(v.w - b2f(h3));
          *(uint2*)&AL[m * 40 + k4] =
              make_uint2((u32)l0 | ((u32)l1 << 16), (u32)l2 | ((u32)l3 << 16));
        }
      } else {
        uint2 raw = *(const uint2*)(X + (size_t)(m0 + m) * 384 + kt + k4);
        *(uint2*)&AH[m * 40 + k4] = raw;
      }
      float4 wv = *(const float4*)(W + (size_t)(n0 + m) * 384 + kt + k4);
      u16 wh0 = f2b(wv.x), wh1 = f2b(wv.y), wh2 = f2b(wv.z), wh3 = f2b(wv.w);
      *(uint2*)&BH[m * 40 + k4] =
          make_uint2((u32)wh0 | ((u32)wh1 << 16), (u32)wh2 | ((u32)wh3 << 16));
      if (SPLIT) {
        u16 wl0 = f2b(wv.x - b2f(wh0)), wl1 = f2b(wv.y - b2f(wh1));
        u16 wl2 = f2b(wv.z - b2f(wh2)), wl3 = f2b(wv.w - b2f(wh3));
        *(uint2*)&BL[m * 40 + k4] =
            make_uint2((u32)wl0 | ((u32)wl1 << 16), (u32)wl2 | ((u32)wl3 << 16));
      }
    }
    __syncthreads();
    short8 af[4], bf[4], al[4], bl[4];
#pragma unroll
    for (int mi = 0; mi < 4; ++mi) {
      af[mi] = *(const short8*)&AH[(wm * 64 + mi * 16 + t) * 40 + qd * 8];
      bf[mi] = *(const short8*)&BH[(wn * 64 + mi * 16 + t) * 40 + qd * 8];
      if (SPLIT) {
        al[mi] = *(const short8*)&AL[(wm * 64 + mi * 16 + t) * 40 + qd * 8];
        bl[mi] = *(const short8*)&BL[(wn * 64 + mi * 16 + t) * 40 + qd * 8];
      }
    }
#pragma unroll
    for (int mi = 0; mi < 4; ++mi)
#pragma unroll
      for (int ni = 0; ni < 4; ++ni) {
        acc[mi][ni] = MFMA_BF16(af[mi], bf[ni], acc[mi][ni]);
        if (SPLIT) {
          acc[mi][ni] = MFMA_BF16(al[mi], bf[ni], acc[mi][ni]);
          acc[mi][ni] = MFMA_BF16(af[mi], bl[ni], acc[mi][ni]);
        }
      }
    __syncthreads();
  }
#pragma unroll
  for (int ni = 0; ni < 4; ++ni) {
    int n = n0 + wn * 64 + ni * 16 + t;
    float bv = bias[n];
#pragma unroll
    for (int mi = 0; mi < 4; ++mi)
#pragma unroll
      for (int r = 0; r < 4; ++r) {
        int m = m0 + wm * 64 + mi * 16 + qd * 4 + r;
        stf(&out[(size_t)m * 384 + n], acc[mi][ni][r] + bv);
      }
  }
}

// ---------------- row LayerNorm, in place (templated storage)
template <typename T>
__global__ __launch_bounds__(256) void ln_inplace(
    T* __restrict__ Tb, const float* __restrict__ w, const float* __restrict__ b, int N) {
  const int row = blockIdx.x, tid = threadIdx.x;
  T* Tr = Tb + (size_t)row * N;
  float vals[3];
  float s = 0.f, ss = 0.f;
  int nv = 0;
  for (int i = tid; i < N; i += 256) {
    float v = ldf(&Tr[i]);
    vals[nv++] = v;
    s += v; ss += v * v;
  }
#pragma unroll
  for (int mk = 32; mk; mk >>= 1) { s += __shfl_xor(s, mk); ss += __shfl_xor(ss, mk); }
  __shared__ float red[8];
  if ((tid & 63) == 0) { red[tid >> 6] = s; red[4 + (tid >> 6)] = ss; }
  __syncthreads();
  s = red[0] + red[1] + red[2] + red[3];
  ss = red[4] + red[5] + red[6] + red[7];
  float inv = 1.f / (float)N;
  float mean = s * inv;
  float var = fmaxf(ss * inv - mean * mean, 0.f);
  float rstd = rsqrtf(var + LNEPS);
  nv = 0;
  for (int i = tid; i < N; i += 256) {
    float v = (vals[nv++] - mean) * rstd * w[i] + b[i];
    stf(&Tr[i], v);
  }
}

// ---------------- LN over split storage: lo = f32 chans 0..383, hi = bf16 chans 384..767
__global__ __launch_bounds__(256) void ln_wf_split(
    float* __restrict__ lo, u16* __restrict__ hi,
    const float* __restrict__ w, const float* __restrict__ b) {
  const int row = blockIdx.x, tid = threadIdx.x;
  float* L = lo + (size_t)row * 384;
  u16* H = hi + (size_t)row * 384;
  float vals[3];
  float s = 0.f, ss = 0.f;
  int nv = 0;
  for (int i = tid; i < 768; i += 256) {
    float v = (i < 384) ? L[i] : b2f(H[i - 384]);
    vals[nv++] = v;
    s += v; ss += v * v;
  }
#pragma unroll
  for (int mk = 32; mk; mk >>= 1) { s += __shfl_xor(s, mk); ss += __shfl_xor(ss, mk); }
  __shared__ float red[8];
  if ((tid & 63) == 0) { red[tid >> 6] = s; red[4 + (tid >> 6)] = ss; }
  __syncthreads();
  s = red[0] + red[1] + red[2] + red[3];
  ss = red[4] + red[5] + red[6] + red[7];
  float mean = s * (1.f / 768.f);
  float var = fmaxf(ss * (1.f / 768.f) - mean * mean, 0.f);
  float rstd = rsqrtf(var + LNEPS);
  nv = 0;
  for (int i = 0 + tid; i < 768; i += 256) {
    float v = (vals[nv++] - mean) * rstd * w[i] + b[i];
    if (i < 384) L[i] = v; else H[i - 384] = f2b(v);
  }
}

// ---------------- DWT sf: t_sf f32 -> q1 split-bf16 (hi+lo), q2 bf16 (3 heads)
__global__ __launch_bounds__(256) void dwt_sf(
    const float* __restrict__ T, u16* __restrict__ q1h, u16* __restrict__ q1l,
    u16* __restrict__ q2) {
  const int blk = blockIdx.x;
  const int b = blk >> 10, pos = blk & 1023;
  const int i = pos >> 5, j = pos & 31;
  const int p00 = (i * 2) * 64 + j * 2;
  const float* base = T + (size_t)b * 4096 * 384;
  for (int ch = threadIdx.x; ch < 384; ch += 256) {
    float a  = base[(size_t)p00 * 384 + ch];
    float cc = base[(size_t)(p00 + 1) * 384 + ch];
    float bb = base[(size_t)(p00 + 64) * 384 + ch];
    float dd = base[(size_t)(p00 + 65) * 384 + ch];
    float s0 = 0.5f * ( a + bb + cc + dd);
    float s1 = 0.5f * (-a - bb + cc + dd);
    float s2 = 0.5f * (-a + bb - cc + dd);
    float s3 = 0.5f * ( a - bb - cc + dd);
    size_t po = (size_t)(b * 1024 + pos) * 384 + ch;
    u16 h = f2b(s0);
    q1h[po] = h;
    q1l[po] = f2b(s0 - b2f(h));
    q2[(size_t)((b * 3 + 0) * 1024 + pos) * 384 + ch] = f2b(s1);
    q2[(size_t)((b * 3 + 1) * 1024 + pos) * 384 + ch] = f2b(s2);
    q2[(size_t)((b * 3 + 2) * 1024 + pos) * 384 + ch] = f2b(s3);
  }
}

// ---------------- DWT wf (split input): lo f32, hi bf16 -> k1 split-bf16, v1, k2, v2
__global__ __launch_bounds__(256) void dwt_wf_split(
    const float* __restrict__ lo, const u16* __restrict__ hi,
    u16* __restrict__ k1h, u16* __restrict__ k1l, u16* __restrict__ v1,
    u16* __restrict__ k2, u16* __restrict__ v2) {
  const int blk = blockIdx.x;
  const int b = blk >> 10, pos = blk & 1023;
  const int i = pos >> 5, j = pos & 31;
  const int p00 = (i * 2) * 64 + j * 2;
  for (int ch = threadIdx.x; ch < 768; ch += 256) {
    float a, bb, cc, dd;
    if (ch < 384) {
      const float* base = lo + (size_t)b * 4096 * 384;
      a  = base[(size_t)p00 * 384 + ch];
      cc = base[(size_t)(p00 + 1) * 384 + ch];
      bb = base[(size_t)(p00 + 64) * 384 + ch];
      dd = base[(size_t)(p00 + 65) * 384 + ch];
    } else {
      const u16* base = hi + (size_t)b * 4096 * 384;
      int c = ch - 384;
      a  = b2f(base[(size_t)p00 * 384 + c]);
      cc = b2f(base[(size_t)(p00 + 1) * 384 + c]);
      bb = b2f(base[(size_t)(p00 + 64) * 384 + c]);
      dd = b2f(base[(size_t)(p00 + 65) * 384 + c]);
    }
    float s0 = 0.5f * ( a + bb + cc + dd);
    float s1 = 0.5f * (-a - bb + cc + dd);
    float s2 = 0.5f * (-a + bb - cc + dd);
    float s3 = 0.5f * ( a - bb - cc + dd);
    if (ch < 384) {
      size_t po = (size_t)(b * 1024 + pos) * 384 + ch;
      u16 h = f2b(s0);
      k1h[po] = h;
      k1l[po] = f2b(s0 - b2f(h));
      v1[po] = f2b(s2);
      k2[(size_t)((b * 3 + 1) * 1024 + pos) * 384 + ch] = f2b(s1);
      v2[(size_t)((b * 3 + 1) * 1024 + pos) * 384 + ch] = f2b(s3);
    } else {
      int c = ch - 384;
      k2[(size_t)((b * 3 + 0) * 1024 + pos) * 384 + c] = f2b(s0);
      k2[(size_t)((b * 3 + 2) * 1024 + pos) * 384 + c] = f2b(s1);
      v2[(size_t)((b * 3 + 0) * 1024 + pos) * 384 + c] = f2b(s2);
      v2[(size_t)((b * 3 + 2) * 1024 + pos) * 384 + c] = f2b(s3);
    }
  }
}

// ---------------- transpose [bh][1024][384] -> [bh][384][1024]
__global__ __launch_bounds__(256) void transpose_rm(
    const u16* __restrict__ in, u16* __restrict__ out) {
  __shared__ u16 T[64][65];
  const int tid = threadIdx.x;
  const int bh = blockIdx.z, r0 = blockIdx.y * 64, c0 = blockIdx.x * 64;
  const u16* ip = in + ((size_t)bh * 1024 + r0) * 384 + c0;
  for (int i = tid; i < 2048; i += 256) {
    int r = i >> 5, c2 = i & 31;
    u32 v = *(const u32*)(ip + (size_t)r * 384 + c2 * 2);
    T[c2 * 2][r] = (u16)v;
    T[c2 * 2 + 1][r] = (u16)(v >> 16);
  }
  __syncthreads();
  u16* op = out + ((size_t)bh * 384 + c0) * 1024 + r0;
  for (int i = tid; i < 2048; i += 256) {
    int c = i >> 5, r2 = i & 31;
    u32 v = (u32)T[c][r2 * 2] | ((u32)T[c][r2 * 2 + 1] << 16);
    *(u32*)(op + (size_t)c * 1024 + r2 * 2) = v;
  }
}

// att2 (24 heads x 16 blocks of 64 own rows): XCD x gets heads {x, x+8, x+16}.
__device__ __forceinline__ void xcd24v2(int L, int& bh, int& o0) {
  int s = L >> 3;
  bh = (s >> 4) * 8 + (L & 7);
  o0 = (s & 15) * 64;
}

// ---------------- att2 stats v4: block owns 64 q-rows (wave w -> 16 rows).
// Stream k2 staged to LDS in ROW-MAJOR [32][392] (write banks uniform: the
// old [ks*32+r][40] layout put all 12 ks-lanes in one 4-bank window, 12-way
// write conflict). Swapped scores (stream axis in-register), in-lane reduce.
__global__ __launch_bounds__(256) void att2_stats(
    const u16* __restrict__ q, const u16* __restrict__ k,
    float2* __restrict__ stats, float scale) {
  __shared__ __align__(16) u16 S[2][32 * 392];  // 50176 B, row-major +8 pad
  const int tid = threadIdx.x, w = tid >> 6, lane = tid & 63;
  const int t = lane & 15, qd = lane >> 4;
  int bh, o0;
  xcd24v2(blockIdx.x, bh, o0);
  short8 Ah[12];
  {
    const u16* qp = q + ((size_t)bh * 1024 + o0 + w * 16 + t) * 384 + qd * 8;
#pragma unroll
    for (int ks = 0; ks < 12; ++ks) Ah[ks] = *(const short8*)(qp + ks * 32);
  }
  float m = -1e30f, l = 0.f;
  const u16* kb = k + (size_t)bh * 1024 * 384;
  int buf = 0;
  for (int st = 0; st < 32; ++st) {
    // stage stream rows st*32..+32, row-major
#pragma unroll
    for (int i = 0; i < 6; ++i) {
      int u = tid + i * 256;
      int r = u / 48, c8 = u % 48;
      *(uint4*)&S[buf][r * 392 + c8 * 8] =
          *(const uint4*)(kb + (size_t)(st * 32 + r) * 384 + c8 * 8);
    }
    __syncthreads();
    // swapped: A = stream frags (rows t and 16+t), B = own Q regs
    f32x4 Sg0 = {0.f,0.f,0.f,0.f}, Sg1 = {0.f,0.f,0.f,0.f};
#pragma unroll
    for (int ks = 0; ks < 12; ++ks) {
      short8 A0 = *(const short8*)&S[buf][t * 392 + ks * 32 + qd * 8];
      short8 A1 = *(const short8*)&S[buf][(16 + t) * 392 + ks * 32 + qd * 8];
      Sg0 = MFMA_BF16(A0, Ah[ks], Sg0);
      Sg1 = MFMA_BF16(A1, Ah[ks], Sg1);
    }
    float s0 = Sg0[0]*scale, s1 = Sg0[1]*scale, s2 = Sg0[2]*scale, s3 = Sg0[3]*scale;
    float s4 = Sg1[0]*scale, s5 = Sg1[1]*scale, s6 = Sg1[2]*scale, s7 = Sg1[3]*scale;
    float mx = fmaxf(fmaxf(fmaxf(s0,s1),fmaxf(s2,s3)),fmaxf(fmaxf(s4,s5),fmaxf(s6,s7)));
    mx = fmaxf(mx, __shfl_xor(mx, 16));
    mx = fmaxf(mx, __shfl_xor(mx, 32));
    float nm = fmaxf(m, mx);
    float e = __expf(s0-nm)+__expf(s1-nm)+__expf(s2-nm)+__expf(s3-nm)
            + __expf(s4-nm)+__expf(s5-nm)+__expf(s6-nm)+__expf(s7-nm);
    e += __shfl_xor(e, 16);
    e += __shfl_xor(e, 32);
    l = l * __expf(m - nm) + e;
    m = nm;
    buf ^= 1;
  }
  if (qd == 0)
    stats[(size_t)bh * 1024 + o0 + w * 16 + t] = make_float2(m, 1.f / l);
}

// ---------------- att2 accumulate v3 (transposed gather): block owns 64 k2
// rows (wave w -> 16 output rows x ALL 384 dims, acc[24]). SQ staged ROW-MAJOR
// [32][392] (conflict-free writes); SV/P unchanged. Two barriers/iter.
__global__ __launch_bounds__(256, 2) void att2_accum(
    const u16* __restrict__ own, const u16* __restrict__ str,
    const u16* __restrict__ vt, const float2* __restrict__ stats,
    u16* __restrict__ xall, float scale) {
  __shared__ __align__(16) u16 SQ[32 * 392];       // 25088 B row-major
  __shared__ __align__(16) u16 SV[24 * 16 * 40];   // 30720 B
  __shared__ __align__(16) u16 P[4][16 * 40];      // 5120 B, wave-private
  const int tid = threadIdx.x, w = tid >> 6, lane = tid & 63;
  const int t = lane & 15, qd = lane >> 4;
  int bh, o0;
  xcd24v2(blockIdx.x, bh, o0);
  short8 Ah[12];
  {
    const u16* op = own + ((size_t)bh * 1024 + o0 + w * 16 + t) * 384 + qd * 8;
#pragma unroll
    for (int ks = 0; ks < 12; ++ks) Ah[ks] = *(const short8*)(op + ks * 32);
  }
  f32x4 acc[24];
#pragma unroll
  for (int i = 0; i < 24; ++i) acc[i] = (f32x4){0.f, 0.f, 0.f, 0.f};
  const u16* sb = str + (size_t)bh * 1024 * 384;
  const u16* vb = vt + (size_t)bh * 384 * 1024;
  u16* Pw = &P[w][0];
  for (int st = 0; st < 32; ++st) {
    __syncthreads();  // all waves done reading SQ/SV from previous iter
#pragma unroll
    for (int i = 0; i < 6; ++i) {
      int u = tid + i * 256;
      int r = u / 48, c8 = u % 48;
      *(uint4*)&SQ[r * 392 + c8 * 8] =
          *(const uint4*)(sb + (size_t)(st * 32 + r) * 384 + c8 * 8);
    }
#pragma unroll
    for (int i = 0; i < 6; ++i) {
      int u = tid + i * 256;
      int d = u >> 2, cq = u & 3;
      uint4 v = *(const uint4*)(vb + (size_t)d * 1024 + st * 32 + cq * 8);
      *(uint4*)&SV[d * 40 + cq * 8] = v;
    }
    float2 cs0 = stats[(size_t)bh * 1024 + st * 32 + t];
    float2 cs1 = stats[(size_t)bh * 1024 + st * 32 + 16 + t];
    __syncthreads();  // staging visible
    f32x4 Sa0 = {0.f,0.f,0.f,0.f}, Sb0 = {0.f,0.f,0.f,0.f};
    f32x4 Sa1 = {0.f,0.f,0.f,0.f}, Sb1 = {0.f,0.f,0.f,0.f};
#pragma unroll
    for (int ks = 0; ks < 12; ks += 2) {
      short8 B00 = *(const short8*)&SQ[t * 392 + ks * 32 + qd * 8];
      short8 B01 = *(const short8*)&SQ[t * 392 + (ks + 1) * 32 + qd * 8];
      short8 B10 = *(const short8*)&SQ[(16 + t) * 392 + ks * 32 + qd * 8];
      short8 B11 = *(const short8*)&SQ[(16 + t) * 392 + (ks + 1) * 32 + qd * 8];
      Sa0 = MFMA_BF16(Ah[ks], B00, Sa0);
      Sb0 = MFMA_BF16(Ah[ks + 1], B01, Sb0);
      Sa1 = MFMA_BF16(Ah[ks], B10, Sa1);
      Sb1 = MFMA_BF16(Ah[ks + 1], B11, Sb1);
    }
#pragma unroll
    for (int r = 0; r < 4; ++r) {
      float p0 = __expf((Sa0[r] + Sb0[r]) * scale - cs0.x) * cs0.y;
      float p1 = __expf((Sa1[r] + Sb1[r]) * scale - cs1.x) * cs1.y;
      Pw[(qd * 4 + r) * 40 + t] = f2b(p0);
      Pw[(qd * 4 + r) * 40 + 16 + t] = f2b(p1);
    }
    // wave-private P: compiler inserts lgkmcnt wait before the read
    short8 Pa = *(const short8*)&Pw[t * 40 + qd * 8];
#pragma unroll
    for (int nj = 0; nj < 24; ++nj) {
      short8 Vf = *(const short8*)&SV[(nj * 16 + t) * 40 + qd * 8];
      acc[nj] = MFMA_BF16(Pa, Vf, acc[nj]);
    }
  }
  const int b_out = bh / 3, off = (1 + bh % 3) * 384;
#pragma unroll
  for (int nj = 0; nj < 24; ++nj)
#pragma unroll
    for (int r = 0; r < 4; ++r) {
      int row = o0 + w * 16 + qd * 4 + r;
      int d = nj * 16 + t;
      xall[((size_t)b_out * 1024 + row) * 1536 + off + d] = f2b(acc[nj][r]);
    }
}

// ---------------- att1 fused flash v3 (split-K over stream; swapped QK^T;
// conflict-free LDS). Grid 512 = (sseg 0/1) x 32 row-blocks x 8 heads;
// 2 blocks/CU. K tiles ROW-MAJOR [16][392] (uniform staging-write banks);
// P rows padded to 40 u16 and written as ONE packed ds_write_b64 (the old
// stride-32 layout + 4 scalar writes were 8-way conflicts). Otherwise
// identical to v2: wave = (wr,dh), wave-private softmax, 1 barrier/iter,
// PV every 2 tiles with pair-deferred max. Emits unnormalized partial +
// (m,l); att1_merge combines.
__global__ __launch_bounds__(256, 2) void att1_fused(
    const u16* __restrict__ qh, const u16* __restrict__ ql,
    const u16* __restrict__ kh, const u16* __restrict__ kl,
    const u16* __restrict__ vt, float* __restrict__ part,
    float2* __restrict__ ml) {
  __shared__ __align__(16) u16 KH[2][16 * 392];   // 25088 B
  __shared__ __align__(16) u16 KL[2][16 * 392];   // 25088 B
  __shared__ __align__(16) u16 P[4][16 * 40];     // 5120 B, wave-private
  const int tid = threadIdx.x, w = tid >> 6, lane = tid & 63;
  const int t = lane & 15, qd = lane >> 4;
  const int wr = w & 1, dh = w >> 1;
  const int bh = blockIdx.x & 7;
  const int q = blockIdx.x >> 3;
  const int o0 = (q & 31) * 32;
  const int sseg = q >> 5;
  const int sbase = sseg * 512;
  // own Q fragments (MFMA B-operand): row o0+wr*16+t, chans ks*32+qd*8
  short8 Ah[12], Al[12];
  {
    const u16* qp  = qh + ((size_t)bh * 1024 + o0 + wr * 16 + t) * 384 + qd * 8;
    const u16* qp2 = ql + ((size_t)bh * 1024 + o0 + wr * 16 + t) * 384 + qd * 8;
#pragma unroll
    for (int ks = 0; ks < 12; ++ks) {
      Ah[ks] = *(const short8*)(qp + ks * 32);
      Al[ks] = *(const short8*)(qp2 + ks * 32);
    }
  }
  f32x4 acc[12];
#pragma unroll
  for (int i = 0; i < 12; ++i) acc[i] = (f32x4){0.f, 0.f, 0.f, 0.f};
  float m = 0.f, l = 0.f, mxp = -1e30f;  // m initialized from tile 0
  const u16* khb = kh + ((size_t)bh * 1024 + sbase) * 384;
  const u16* klb = kl + ((size_t)bh * 1024 + sbase) * 384;
  u16* Pw = &P[w][0];
  // prologue: stage stream tile 0 (16 rows) into buf 0, row-major
#pragma unroll
  for (int i = 0; i < 3; ++i) {
    int u = tid + i * 256;
    int r = u / 48, c8 = u % 48;
    *(uint4*)&KH[0][r * 392 + c8 * 8] =
        *(const uint4*)(khb + (size_t)r * 384 + c8 * 8);
    *(uint4*)&KL[0][r * 392 + c8 * 8] =
        *(const uint4*)(klb + (size_t)r * 384 + c8 * 8);
  }
  __syncthreads();
  short8 Vr[12];
  for (int st = 0; st < 32; ++st) {
    const int buf = st & 1;
    if (!(st & 1)) {
      // V fragments for this tile PAIR (stream rows st*16 .. +32), 2 iters early
#pragma unroll
      for (int nj = 0; nj < 12; ++nj)
        Vr[nj] = *(const short8*)(vt +
            ((size_t)bh * 384 + dh * 192 + nj * 16 + t) * 1024 +
            sbase + st * 16 + qd * 8);
    }
    if (st < 31) {
      // stage next tile into the other buffer (visible after this iter's barrier)
      const int nb = buf ^ 1;
      const u16* kh2 = khb + (size_t)(st + 1) * 16 * 384;
      const u16* kl2 = klb + (size_t)(st + 1) * 16 * 384;
#pragma unroll
      for (int i = 0; i < 3; ++i) {
        int u = tid + i * 256;
        int r = u / 48, c8 = u % 48;
        *(uint4*)&KH[nb][r * 392 + c8 * 8] =
            *(const uint4*)(kh2 + (size_t)r * 384 + c8 * 8);
        *(uint4*)&KL[nb][r * 392 + c8 * 8] =
            *(const uint4*)(kl2 + (size_t)r * 384 + c8 * 8);
      }
    }
    // swapped scores: A = stream K frag (LDS row t), B = own Q regs; 3 chains
    f32x4 Shh = {0.f,0.f,0.f,0.f}, Slh = {0.f,0.f,0.f,0.f}, Shl = {0.f,0.f,0.f,0.f};
#pragma unroll
    for (int ks = 0; ks < 12; ++ks) {
      short8 Bh = *(const short8*)&KH[buf][t * 392 + ks * 32 + qd * 8];
      short8 Bl = *(const short8*)&KL[buf][t * 392 + ks * 32 + qd * 8];
      Shh = MFMA_BF16(Bh, Ah[ks], Shh);
      Slh = MFMA_BF16(Bh, Al[ks], Slh);
      Shl = MFMA_BF16(Bl, Ah[ks], Shl);
    }
    // lane (t,qd): s[r] = S^T[stream qd*4+r][own t]
    float s0 = Shh[0] + Slh[0] + Shl[0];
    float s1 = Shh[1] + Slh[1] + Shl[1];
    float s2 = Shh[2] + Slh[2] + Shl[2];
    float s3 = Shh[3] + Slh[3] + Shl[3];
    float mx = fmaxf(fmaxf(s0, s1), fmaxf(s2, s3));
    mx = fmaxf(mx, __shfl_xor(mx, 16));
    mx = fmaxf(mx, __shfl_xor(mx, 32));
    if (st == 0) m = mx;
    mxp = fmaxf(mxp, mx);
    // deferred max: P = exp(s - m_boundary); bounded by exp(pair growth)
    float p0 = __expf(s0 - m), p1 = __expf(s1 - m);
    float p2 = __expf(s2 - m), p3 = __expf(s3 - m);
    float e = p0 + p1 + p2 + p3;
    e += __shfl_xor(e, 16);
    e += __shfl_xor(e, 32);
    l += e;
    u32 plo = (u32)f2b(p0) | ((u32)f2b(p1) << 16);
    u32 phi = (u32)f2b(p2) | ((u32)f2b(p3) << 16);
    *(uint2*)&Pw[t * 40 + buf * 16 + qd * 4] = make_uint2(plo, phi);
    if (st & 1) {
      // PV over the pair (old-m units); wave-private P, lgkm auto-wait
      short8 Pa = *(const short8*)&Pw[t * 40 + qd * 8];
#pragma unroll
      for (int nj = 0; nj < 12; ++nj) acc[nj] = MFMA_BF16(Pa, Vr[nj], acc[nj]);
      // boundary: fold pair max into running max; rescale l and acc
      float mnew = fmaxf(m, mxp);
      float sc = __expf(m - mnew);
      l *= sc; m = mnew; mxp = -1e30f;
      float f0 = __shfl(sc, qd * 4 + 0);
      float f1 = __shfl(sc, qd * 4 + 1);
      float f2v = __shfl(sc, qd * 4 + 2);
      float f3 = __shfl(sc, qd * 4 + 3);
#pragma unroll
      for (int nj = 0; nj < 12; ++nj) {
        acc[nj][0] *= f0; acc[nj][1] *= f1;
        acc[nj][2] *= f2v; acc[nj][3] *= f3;
      }
    }
    __syncthreads();
  }
  // store unnormalized f32 partial + per-row (m,l) for the merge kernel
  float* pb = part + ((size_t)(sseg * 8 + bh) * 1024 + o0 + wr * 16) * 384;
#pragma unroll
  for (int r = 0; r < 4; ++r) {
    int row = qd * 4 + r;
#pragma unroll
    for (int nj = 0; nj < 12; ++nj)
      pb[(size_t)row * 384 + dh * 192 + nj * 16 + t] = acc[nj][r];
  }
  if (dh == 0 && qd == 0)
    ml[sseg * 8192 + bh * 1024 + o0 + wr * 16 + t] = make_float2(m, l);
}

// ---------------- att1 merge: combine the two stream-segment partials.
// out[row][d] = (p0*e^(m0-M) + p1*e^(m1-M)) / (l0*e^(m0-M) + l1*e^(m1-M))
__global__ __launch_bounds__(192) void att1_merge(
    const float* __restrict__ part, const float2* __restrict__ ml,
    u16* __restrict__ xall) {
  const int rb = blockIdx.x;  // bh*1024 + row, 0..8191
  float2 a = ml[rb];
  float2 b = ml[8192 + rb];
  float M = fmaxf(a.x, b.x);
  float e0 = __expf(a.x - M), e1 = __expf(b.x - M);
  float inv = 1.f / (a.y * e0 + b.y * e1);
  const float* p0 = part + (size_t)rb * 384;
  const float* p1 = part + (size_t)(8192 + rb) * 384;
  u16* xr = xall + (size_t)rb * 1536;
  for (int ch = threadIdx.x; ch < 384; ch += 192)
    xr[ch] = f2b((p0[ch] * e0 + p1[ch] * e1) * inv);
}

// ---------------- IWT: xall (B,1024,1536) -> y (B,4096,384)
__global__ __launch_bounds__(256) void iwt_y(const u16* __restrict__ xall, u16* __restrict__ y) {
  const int blk = blockIdx.x;
  const int b = blk >> 10, pos = blk & 1023;
  const int i = pos >> 5, j = pos & 31;
  const u16* xr = xall + (size_t)(b * 1024 + pos) * 1536;
  u16* yb = y + (size_t)b * 4096 * 384;
  const int p00 = (i * 2) * 64 + j * 2;
  for (int c = threadIdx.x; c < 384; c += 256) {
    float g1 = 0.5f * b2f(xr[c]);
    float g2 = 0.5f * b2f(xr[c + 384]);
    float g3 = 0.5f * b2f(xr[c + 768]);
    float g4 = 0.5f * b2f(xr[c + 1152]);
    yb[(size_t)p00 * 384 + c]        = f2b(g1 - g2 - g3 + g4);
    yb[(size_t)(p00 + 64) * 384 + c] = f2b(g1 - g2 + g3 - g4);
    yb[(size_t)(p00 + 1) * 384 + c]  = f2b(g1 + g2 - g3 - g4);
    yb[(size_t)(p00 + 65) * 384 + c] = f2b(g1 + g2 + g3 + g4);
  }
}

extern "C" void kernel_launch(void* const* d_in, const int* in_sizes, int n_in,
                              void* d_out, int out_size, void* d_ws, size_t ws_size,
                              hipStream_t stream) {
  (void)in_sizes; (void)n_in; (void)out_size; (void)ws_size;
  const float* sf      = (const float*)d_in[0];
  const float* wf      = (const float*)d_in[1];
  const float* q_w     = (const float*)d_in[2];
  const float* q_b     = (const float*)d_in[3];
  const float* q_ln_w  = (const float*)d_in[4];
  const float* q_ln_b  = (const float*)d_in[5];
  const float* kv_w    = (const float*)d_in[6];
  const float* kv_b    = (const float*)d_in[7];
  const float* kv_ln_w = (const float*)d_in[8];
  const float* kv_ln_b = (const float*)d_in[9];
  const float* out_w   = (const float*)d_in[10];
  const float* out_b   = (const float*)d_in[11];
  float* out = (float*)d_out;

  // ---- workspace layout, ~168 MiB peak with phase aliasing ----
  char* p = (char*)d_ws;
  float* A  = (float*)p; p += 50331648;   // t_sf f32; later k1h|k1l|v1|k2|v1t|ml1
  float* B1 = (float*)p; p += 50331648;   // t_wf lo f32; later xall | att1 partials
  u16*   B2 = (u16*)p;   p += 25165824;   // t_wf hi bf16; later v2t; later y
  u16* q1h = (u16*)p; p += 6291456;       // (8,1024,384) bf16 hi
  u16* q1l = (u16*)p; p += 6291456;       // lo
  u16* q2  = (u16*)p; p += 18874368;      // (24,1024,384) bf16
  u16* v2  = (u16*)p; p += 18874368;      // (24,1024,384) bf16 row-major
  float2* stats1 = (float2*)p; p += 65536;    // 8192 float2 (unused now)
  float2* stats2 = (float2*)p;                // 24576 float2
  (void)stats1;
  // aliases inside A (t_sf dead after dwt_sf):
  u16* k1h = (u16*)A;
  u16* k1l = k1h + 3145728;
  u16* v1  = k1l + 3145728;
  u16* k2  = v1 + 3145728;
  u16* v1t = k2 + 9437184;            // (8,384,1024), ends at byte 44040192
  float2* ml1 = (float2*)((char*)A + 44040192);  // 2 x 8192 float2 = 128 KB (fits tail)
  u16* xall = (u16*)B1;               // (8,1024,1536) = 25165824 B
  float* part1 = (float*)((char*)B1 + 25165824);  // 2 x (8,1024,384) f32 = 25165824 B
  u16* v2t = B2;                      // (24,384,1024)
  u16* y   = B2;                      // (8,4096,384)

  // projections (MFMA) + LN; att1 score chain stays f32-precision via split
  gemm_mfma<1, float, float><<<dim3(3, 256), 256, 0, stream>>>(sf, q_w, q_b, A);
  ln_inplace<float><<<32768, 256, 0, stream>>>(A, q_ln_w, q_ln_b, 384);
  gemm_mfma<1, float, float><<<dim3(3, 256), 256, 0, stream>>>(wf, kv_w, kv_b, B1);
  gemm_mfma<0, float, u16><<<dim3(3, 256), 256, 0, stream>>>(wf, kv_w + 384 * 384, kv_b + 384, B2);
  ln_wf_split<<<32768, 256, 0, stream>>>(B1, B2, kv_ln_w, kv_ln_b);

  // DWT (dwt_sf must read A before k1/v1/k2/v1t overwrite it)
  dwt_sf<<<8192, 256, 0, stream>>>(A, q1h, q1l, q2);
  dwt_wf_split<<<8192, 256, 0, stream>>>(B1, B2, k1h, k1l, v1, k2, v2);

  // V transposes for MFMA B-operand layout
  transpose_rm<<<dim3(6, 16, 8), 256, 0, stream>>>(v1, v1t);
  transpose_rm<<<dim3(6, 16, 24), 256, 0, stream>>>(v2, v2t);  // overwrites dead t_wf-hi

  // attention (1D grids, XCD-swizzled inside the kernels)
  att2_stats<<<384, 256, 0, stream>>>(q2, k2, stats2, SCALE2);
  att1_fused<<<512, 256, 0, stream>>>(q1h, q1l, k1h, k1l, v1t, part1, ml1);
  att1_merge<<<8192, 192, 0, stream>>>(part1, ml1, xall);
  att2_accum<<<384, 256, 0, stream>>>(k2, q2, v2t, stats2, xall, SCALE2);

  // IWT + output projection (MFMA)
  iwt_y<<<8192, 256, 0, stream>>>(xall, y);
  gemm_mfma<0, u16, float><<<dim3(3, 256), 256, 0, stream>>>(y, out_w, out_b, out);
}